// Round 4
// baseline (1216.613 us; speedup 1.0000x reference)
//
#include <hip/hip_runtime.h>
#include <math.h>

// Problem constants (fixed by the reference)
#define NN 1024   // nodes
#define BB 32     // mols
#define EE 8192   // edges
#define DD 64     // DIM
#define ID 66     // IN_DIM
#define FT 63     // feats dim
#define CAP 128   // max nnz per adj column
#define ECAP 64   // max in-edges per node (data: Poisson(8), P(>64)~0)
#define MAXM 64   // max nodes per mol (s2s)
#define GM 40     // max nodes per mol (gru)

// ---- workspace layout (float offsets) ----
enum : int {
  OFF_SMIP  = 0,                        // N*66 pre-BN smi
  OFF_OUT   = OFF_SMIP + NN*ID,         // N*66 h == out
  OFF_STATS = OFF_OUT + NN*ID,          // 144 mean/rstd
  OFF_M     = OFF_STATS + 144,          // N*66 m buffer
  OFF_CM    = OFF_M + NN*ID,            // N*132 cm
  OFF_QSTAR = OFF_CM + NN*132,          // 32*132
  OFF_CVAL  = OFF_QSTAR + BB*132,       // N*CAP csc values
  OFF_A     = OFF_CVAL + NN*CAP,        // 1024*256 A = feats@W1a^T + e1b
  OFF_B     = OFF_A + 1024*256,         // 1024*256 B = feats@W1b^T
  OFF_EDGE  = OFF_B + 1024*256,         // 8192*68: [0..62]=mij, [64..66]=cw*rel
  OFF_T     = OFF_EDGE + EE*68,         // 1024*726 T[n][t*66+o]
  OFF_QAUG  = OFF_T + NN*726,           // 726*68 Qaug[(t*66+o)][i]
  OFF_W1A   = OFF_QAUG + 726*68,        // 256*64
  OFF_W1B   = OFF_W1A + 16384,          // 256*64
  OFF_WR    = OFF_W1B + 16384,          // 256
  OFF_W2P   = OFF_WR + 256,             // 64*256 padded e2w
  OFF_C1P   = OFF_W2P + 16384,          // 256*64 padded c1w
  OFF_C1R   = OFF_C1P + 16384,          // 3*1024*192 conv1_w reorg [it][b][o*3+k]
  OFF_GIH   = OFF_C1R + 3*1024*192,     // 198*132
  OFF_GHH   = OFF_GIH + 198*132,        // 198*68
  OFF_F1    = OFF_GHH + 198*68,         // 32*512
  OFF_F2    = OFF_F1 + BB*512,          // 32*256
  OFF_FEND  = OFF_F2 + BB*256
};
enum : int {  // int region at ws + OFF_FEND
  IOFF_CNT   = 0,                 // N   csc col counts
  IOFF_CIDX  = NN,                // N*CAP
  IOFF_ECNT  = NN + NN*CAP,       // N   in-degree
  IOFF_ELIST = NN + NN*CAP + NN,  // N*ECAP edge ids sorted by dst
  IOFF_END   = NN + NN*CAP + NN + NN*ECAP
};

__device__ __forceinline__ float sgm(float x){ return 1.0f/(1.0f+expf(-x)); }
__device__ __forceinline__ float silu_(float x){ return x/(1.0f+expf(-x)); }
__device__ __forceinline__ float nan0(float v){ return (v!=v) ? 0.0f : v; }
__device__ __forceinline__ float hsum4(float4 v){ return v.x+v.y+v.z+v.w; }
#define FMA4(A,X,W) {A.x += (X).x*(W).x; A.y += (X).y*(W).y; A.z += (X).z*(W).z; A.w += (X).w*(W).w;}
#define Z4 {0.f,0.f,0.f,0.f}

// ---- zero the atomic counters ----
__global__ void k_zero0(int* __restrict__ iw){
  int i = blockIdx.x*256 + threadIdx.x;
  if (i < NN){ iw[IOFF_CNT + i] = 0; iw[IOFF_ECNT + i] = 0; }
}

// ---- one-shot setup: csc(adj), edge sort by dst, weight reorg/pad ----
__global__ void k_setup(const float* __restrict__ adj, const int* __restrict__ eidx,
                        const float* __restrict__ e1w, const float* __restrict__ e2w,
                        const float* __restrict__ c1w,
                        const float* __restrict__ nnw, const float* __restrict__ nnb,
                        const float* __restrict__ cv1w,
                        const float* __restrict__ gwih, const float* __restrict__ gwhh,
                        float* __restrict__ ws, int* __restrict__ iw){
  long long idx = (long long)blockIdx.x*256 + threadIdx.x;
  if (idx < (long long)NN*NN){
    float v = adj[idx];
    if (v != 0.0f){
      int a = (int)(idx & 1023), b = (int)(idx >> 10);
      int p = atomicAdd(iw + IOFF_CNT + a, 1);
      if (p < CAP){ iw[IOFF_CIDX + a*CAP + p] = b; ws[OFF_CVAL + a*CAP + p] = v; }
    }
    return;
  }
  idx -= (long long)NN*NN;
  if (idx < EE){
    int e = (int)idx, d = eidx[EE + e];
    int p = atomicAdd(iw + IOFF_ECNT + d, 1);
    if (p < ECAP) iw[IOFF_ELIST + d*ECAP + p] = e;
    return;
  }
  idx -= EE;
  if (idx < 16384){ int u=(int)idx>>6, j=(int)idx&63;
    ws[OFF_W1A+idx] = (u<254 && j<63)? e1w[u*127+j]      : 0.f;
    ws[OFF_W1B+idx] = (u<254 && j<63)? e1w[u*127+63+j]   : 0.f;
    if (j==0) ws[OFF_WR+u] = (u<254)? e1w[u*127+126] : 0.f;
    return; }
  idx -= 16384;
  if (idx < 16384){ int u=(int)idx>>8, j=(int)idx&255; ws[OFF_W2P+idx] = (u<63 && j<254)? e2w[u*254+j] : 0.f; return; }
  idx -= 16384;
  if (idx < 16384){ int u=(int)idx>>6, j=(int)idx&63; ws[OFF_C1P+idx] = (u<252 && j<63)? c1w[u*63+j] : 0.f; return; }
  idx -= 16384;
  if (idx < 726*68){ int to=(int)idx/68, i=(int)idx%68; int t=to/66, o=to%66;
    float v = 0.f;
    if (i < 66) v = (t<10)? nnw[(i*66+o)*10+t] : nnb[i*66+o];
    ws[OFF_QAUG+idx] = v; return; }
  idx -= 726*68;
  if (idx < 3*1024*192){ int it=(int)(idx/196608); int r=(int)(idx%196608); int b=r/192; int z=r%192; int o=z/3, k=z%3;
    ws[OFF_C1R+idx] = cv1w[((it*64+o)*1024+b)*3+k]; return; }
  idx -= 3*1024*192;
  if (idx < 198*132){ int u=(int)idx/132, j=(int)idx%132; ws[OFF_GIH+idx] = (j<130)? gwih[u*130+j] : 0.f; return; }
  idx -= 198*132;
  if (idx < 198*68){ int u=(int)idx/68, j=(int)idx%68; ws[OFF_GHH+idx] = (j<66)? gwhh[u*66+j] : 0.f; return; }
}

// ---- A/B build: A[n][u] = e1b[u] + feats[n]·W1a[u], B[n][u] = feats[n]·W1b[u] ----
__global__ __launch_bounds__(256) void k_ab(const float* __restrict__ mnc,
                                            const float* __restrict__ e1b,
                                            float* __restrict__ ws){
  __shared__ float xf[32][68];
  int tid = threadIdx.x;
  int n0 = blockIdx.x*32;
  for (int idx=tid; idx<32*64; idx+=256){ int n=idx>>6, j=idx&63;
    xf[n][j] = (j<63)? mnc[(n0+n)*ID + 3 + j] : 0.f; }
  __syncthreads();
  int eg = tid&7, ug = tid>>3;
  for (int pass=0; pass<8; pass++){
    int u = pass*32 + ug;
    const float4* wa = (const float4*)(ws + OFF_W1A + u*64);
    const float4* wb = (const float4*)(ws + OFF_W1B + u*64);
    float4 a0=Z4,a1=Z4,a2=Z4,a3=Z4,b0=Z4,b1=Z4,b2=Z4,b3=Z4;
    for (int jj=0;jj<16;jj++){
      float4 w1 = wa[jj], w2 = wb[jj];
      float4 x0 = *(const float4*)&xf[eg   ][jj*4];
      float4 x1 = *(const float4*)&xf[eg+ 8][jj*4];
      float4 x2 = *(const float4*)&xf[eg+16][jj*4];
      float4 x3 = *(const float4*)&xf[eg+24][jj*4];
      FMA4(a0,x0,w1) FMA4(a1,x1,w1) FMA4(a2,x2,w1) FMA4(a3,x3,w1)
      FMA4(b0,x0,w2) FMA4(b1,x1,w2) FMA4(b2,x2,w2) FMA4(b3,x3,w2)
    }
    if (u < 254){
      float bv = e1b[u];
      float va[4]={hsum4(a0),hsum4(a1),hsum4(a2),hsum4(a3)};
      float vb[4]={hsum4(b0),hsum4(b1),hsum4(b2),hsum4(b3)};
      #pragma unroll
      for (int i=0;i<4;i++){
        int n = n0 + eg + 8*i;
        ws[OFF_A + n*256 + u] = bv + va[i];
        ws[OFF_B + n*256 + u] = vb[i];
      }
    }
  }
}

// ---- per-edge chain: eh (from A/B) -> mij -> ch -> cw; writes EDGE buffer ----
#define EB 32
__global__ __launch_bounds__(256) void k_edge(
    const float* __restrict__ mnc, const int* __restrict__ eidx,
    const float* __restrict__ e2b, const float* __restrict__ c1b,
    const float* __restrict__ c2w, const float* __restrict__ c2b,
    float* __restrict__ ws)
{
  __shared__ float eh [EB][260];   // L1 out; later ch
  __shared__ float mij[EB][68];
  __shared__ float wst[64][68];    // weight chunk staging
  __shared__ float srel[EB][4];
  __shared__ int ssrc[EB], sdst[EB];
  int tid = threadIdx.x;
  int e0b = blockIdx.x*EB;
  if (tid < EB){
    int e = e0b + tid;
    int s = eidx[e], d = eidx[EE + e];
    ssrc[tid]=s; sdst[tid]=d;
    float rd = 0.f;
    #pragma unroll
    for (int k=0;k<3;k++){ float r = mnc[s*ID+k]-mnc[d*ID+k]; srel[tid][k]=r; rd += r*r; }
    srel[tid][3] = rd;
  }
  for (int idx=tid; idx<EB*5; idx+=256){ mij[idx/5][63+idx%5] = 0.f; }
  __syncthreads();
  // eh = silu(A[dst] + B[src] + wr*rd)   (A carries e1b)
  for (int idx=tid; idx<EB*256; idx+=256){
    int e = idx>>8, u = idx&255;
    float v = 0.f;
    if (u < 254) v = silu_(ws[OFF_A + sdst[e]*256 + u] + ws[OFF_B + ssrc[e]*256 + u]
                           + ws[OFF_WR + u]*srel[e][3]);
    eh[e][u] = v;
  }
  for (int idx=tid; idx<EB*4; idx+=256){ eh[idx>>2][256+(idx&3)] = 0.f; }
  __syncthreads();
  int eg = tid&7, ug = tid>>3;   // 4 edges (eg+8i) x 2 units (2ug,2ug+1)
  // L2: mij = silu(eh @ W2P^T + e2b), K=256 in 4 chunks of 64 staged in LDS
  {
    float4 a0=Z4,a1=Z4,a2=Z4,a3=Z4,b0=Z4,b1=Z4,b2=Z4,b3=Z4;
    for (int kc=0;kc<4;kc++){
      for (int idx=tid; idx<4096; idx+=256){ int u=idx>>6, j=idx&63; wst[u][j]=ws[OFF_W2P+u*256+kc*64+j]; }
      __syncthreads();
      for (int jj=0;jj<16;jj++){
        float4 w0 = *(const float4*)&wst[2*ug  ][jj*4];
        float4 w1 = *(const float4*)&wst[2*ug+1][jj*4];
        float4 x0 = *(const float4*)&eh[eg   ][kc*64+jj*4];
        float4 x1 = *(const float4*)&eh[eg+ 8][kc*64+jj*4];
        float4 x2 = *(const float4*)&eh[eg+16][kc*64+jj*4];
        float4 x3 = *(const float4*)&eh[eg+24][kc*64+jj*4];
        FMA4(a0,x0,w0) FMA4(a1,x1,w0) FMA4(a2,x2,w0) FMA4(a3,x3,w0)
        FMA4(b0,x0,w1) FMA4(b1,x1,w1) FMA4(b2,x2,w1) FMA4(b3,x3,w1)
      }
      __syncthreads();
    }
    int u0 = 2*ug, u1 = 2*ug+1;
    float va[4]={hsum4(a0),hsum4(a1),hsum4(a2),hsum4(a3)};
    float vb[4]={hsum4(b0),hsum4(b1),hsum4(b2),hsum4(b3)};
    float bv0 = e2b[u0];
    #pragma unroll
    for (int i=0;i<4;i++){
      int e = eg + 8*i;
      float v = silu_(bv0 + va[i]);
      mij[e][u0] = v; ws[OFF_EDGE + (e0b+e)*68 + u0] = v;
      if (u1 < 63){
        float v1 = silu_(e2b[u1] + vb[i]);
        mij[e][u1] = v1; ws[OFF_EDGE + (e0b+e)*68 + u1] = v1;
      }
    }
  }
  __syncthreads();
  // L3: ch = silu(mij @ C1P^T + c1b) into eh, K=64, units in 4 chunks of 64
  for (int uc=0; uc<4; uc++){
    for (int idx=tid; idx<4096; idx+=256){ int u=idx>>6, j=idx&63; wst[u][j]=ws[OFF_C1P+(uc*64+u)*64+j]; }
    __syncthreads();
    float4 a0=Z4,a1=Z4,a2=Z4,a3=Z4,b0=Z4,b1=Z4,b2=Z4,b3=Z4;
    for (int jj=0;jj<16;jj++){
      float4 w0 = *(const float4*)&wst[2*ug  ][jj*4];
      float4 w1 = *(const float4*)&wst[2*ug+1][jj*4];
      float4 x0 = *(const float4*)&mij[eg   ][jj*4];
      float4 x1 = *(const float4*)&mij[eg+ 8][jj*4];
      float4 x2 = *(const float4*)&mij[eg+16][jj*4];
      float4 x3 = *(const float4*)&mij[eg+24][jj*4];
      FMA4(a0,x0,w0) FMA4(a1,x1,w0) FMA4(a2,x2,w0) FMA4(a3,x3,w0)
      FMA4(b0,x0,w1) FMA4(b1,x1,w1) FMA4(b2,x2,w1) FMA4(b3,x3,w1)
    }
    int u0 = uc*64 + 2*ug, u1 = u0+1;
    float va[4]={hsum4(a0),hsum4(a1),hsum4(a2),hsum4(a3)};
    float vb[4]={hsum4(b0),hsum4(b1),hsum4(b2),hsum4(b3)};
    #pragma unroll
    for (int i=0;i<4;i++){
      int e = eg + 8*i;
      if (u0 < 252) eh[e][u0] = silu_(c1b[u0] + va[i]);
      if (u1 < 252) eh[e][u1] = silu_(c1b[u1] + vb[i]);
    }
    __syncthreads();
  }
  // L4: cw = ch·c2w + c2b; EDGE[64..66] = cw*rel
  {
    int e = tid>>3, q = tid&7;
    const float4* xr = (const float4*)&eh[e][0];
    const float4* wr4 = (const float4*)c2w;
    float4 a = Z4;
    for (int jj=q; jj<63; jj+=8){ float4 xv=xr[jj], wv=wr4[jj]; FMA4(a,xv,wv) }
    float s = hsum4(a);
    s += __shfl_down(s,4,64); s += __shfl_down(s,2,64); s += __shfl_down(s,1,64);
    if (q == 0){
      float cw = s + c2b[0];
      #pragma unroll
      for (int k=0;k<3;k++) ws[OFF_EDGE + (e0b+e)*68 + 64 + k] = cw*srel[e][k];
    }
  }
}

// ---- node MLP + gathers (m_i, coor) -> smi_pre ----
#define NB 16
__global__ __launch_bounds__(256) void k_node(
    const float* __restrict__ mnc,
    const float* __restrict__ n1w, const float* __restrict__ n1b,
    const float* __restrict__ n2w, const float* __restrict__ n2b,
    float* __restrict__ ws, const int* __restrict__ iw)
{
  __shared__ float xin[NB][132];
  __shared__ float t1 [NB][132];
  int tid = threadIdx.x;
  int n0 = blockIdx.x*NB;
  for (int idx=tid; idx<NB*126; idx+=256){
    int e = idx/126, j = idx%126;
    int node = n0 + e;
    float v;
    if (j < 63) v = mnc[node*ID + 3 + j];
    else {
      int u = j - 63;
      int cnt = iw[IOFF_ECNT+node]; if (cnt > ECAP) cnt = ECAP;
      v = 0.f;
      for (int q=0;q<cnt;q++) v += ws[OFF_EDGE + iw[IOFF_ELIST+node*ECAP+q]*68 + u];
    }
    xin[e][j] = v;
  }
  __syncthreads();
  for (int idx=tid; idx<NB*126; idx+=256){
    int e = idx & 15, u = idx >> 4;
    float s = n1b[u];
    const float* w = n1w + u*126;
    for (int j=0;j<126;j++) s += xin[e][j]*w[j];
    t1[e][u] = silu_(s);
  }
  __syncthreads();
  for (int idx=tid; idx<NB*FT; idx+=256){
    int e = idx & 15, u = idx >> 4;
    float s = n2b[u];
    const float* w = n2w + u*126;
    for (int j=0;j<126;j++) s += t1[e][j]*w[j];
    int node = n0 + e;
    ws[OFF_SMIP + node*ID + 3 + u] = nan0(xin[e][u] + s);
  }
  if (tid < NB*3){
    int e = tid/3, k = tid%3;
    int node = n0 + e;
    int cnt = iw[IOFF_ECNT+node]; if (cnt > ECAP) cnt = ECAP;
    float s = mnc[node*ID + k];
    for (int q=0;q<cnt;q++) s += ws[OFF_EDGE + iw[IOFF_ELIST+node*ECAP+q]*68 + 64 + k];
    ws[OFF_SMIP + node*ID + k] = nan0(s);
  }
}

// ---- batchnorm ----
__global__ __launch_bounds__(256) void k_bn_stats(float* __restrict__ ws){
  __shared__ float scr[8];
  int j = blockIdx.x, tid = threadIdx.x;
  float s=0.f, ss=0.f;
  for (int i=tid; i<NN; i+=256){ float x = ws[OFF_SMIP + i*ID + j]; s+=x; ss+=x*x; }
  for (int o=32;o>0;o>>=1){ s += __shfl_down(s,o,64); ss += __shfl_down(ss,o,64); }
  int w = tid>>6;
  if ((tid&63)==0){ scr[w]=s; scr[4+w]=ss; }
  __syncthreads();
  if (tid==0){
    float S=0,SS=0;
    for (int q=0;q<4;q++){S+=scr[q];SS+=scr[4+q];}
    float mean = S/NN;
    float var  = SS/NN - mean*mean;
    ws[OFF_STATS + j]      = mean;
    ws[OFF_STATS + 66 + j] = 1.0f/sqrtf(var + 1e-5f);
  }
}
__global__ void k_bn_apply(const float* __restrict__ bng, const float* __restrict__ bnb,
                           float* __restrict__ ws){
  int idx = blockIdx.x*256 + threadIdx.x;
  if (idx < NN*ID){
    int j = idx % ID;
    ws[OFF_OUT + idx] = bng[j]*(ws[OFF_SMIP+idx]-ws[OFF_STATS+j])*ws[OFF_STATS+66+j] + bnb[j];
  }
}

// ---- T[n][t*66+o] = sum_i out[n,i]*Qaug[i,t,o]  (GEMM 1024x66x726) ----
__global__ __launch_bounds__(256) void k_tbuild(float* __restrict__ ws){
  __shared__ float xs[16][68];
  int tid = threadIdx.x;
  int n0 = blockIdx.x*16;
  for (int idx=tid; idx<16*68; idx+=256){ int n=idx/68, j=idx%68;
    xs[n][j] = (j<66)? ws[OFF_OUT + (n0+n)*ID + j] : 0.f; }
  __syncthreads();
  for (int pass=0; pass<3; pass++){
    int to = pass*256 + tid;
    if (to < 726){
      float acc[16];
      #pragma unroll
      for (int n=0;n<16;n++) acc[n] = 0.f;
      const float4* qp = (const float4*)(ws + OFF_QAUG + to*68);
      for (int jj=0;jj<17;jj++){
        float4 w = qp[jj];
        #pragma unroll
        for (int n=0;n<16;n++){
          float4 x = *(const float4*)&xs[n][jj*4];
          acc[n] += x.x*w.x + x.y*w.y + x.z*w.z + x.w*w.w;
        }
      }
      #pragma unroll
      for (int n=0;n<16;n++) ws[OFF_T + (n0+n)*726 + to] = acc[n];
    }
  }
}

// ---- m = relu(gathered_msg/deg + out@root + nn_bias) ----
__global__ __launch_bounds__(256) void k_mnode(
    const float* __restrict__ root, const float* __restrict__ nnbias,
    const int* __restrict__ eidx, const float* __restrict__ ea,
    float* __restrict__ ws, const int* __restrict__ iw)
{
  __shared__ float rs[66][68];
  __shared__ float xo[NB][68];
  int tid = threadIdx.x;
  int n0 = blockIdx.x*NB;
  for (int idx=tid; idx<66*66; idx+=256) rs[idx/66][idx%66] = root[idx];
  for (int idx=tid; idx<NB*66; idx+=256) xo[idx/66][idx%66] = ws[OFF_OUT + n0*ID + idx];
  __syncthreads();
  for (int idx=tid; idx<NB*66; idx+=256){
    int n = idx/66, o = idx%66;
    int node = n0 + n;
    int rawcnt = iw[IOFF_ECNT+node];
    int cnt = rawcnt > ECAP ? ECAP : rawcnt;
    float magg = 0.f;
    for (int q=0;q<cnt;q++){
      int e = iw[IOFF_ELIST + node*ECAP + q];
      int s = eidx[e];
      const float* Tp = ws + OFF_T + s*726 + o;
      const float* eap = ea + e*10;
      float av = Tp[660];                 // t=10 slot (nn_b), ea_aug=1
      #pragma unroll
      for (int t=0;t<10;t++) av += eap[t]*Tp[t*66];
      magg += av;
    }
    float deg = fmaxf((float)rawcnt, 1.0f);
    float s2 = nnbias[o] + magg/deg;
    for (int j=0;j<66;j++) s2 += xo[n][j]*rs[j][o];
    s2 = fmaxf(s2, 0.0f);
    ws[OFF_M  + node*ID  + o] = s2;
    ws[OFF_CM + node*132 + o] = s2;
  }
}

// ---- fused sparse conv (bulk-staged neighbors, no per-nnz sync) ----
__global__ __launch_bounds__(256) void k_spconv(
    const float* __restrict__ cv1b, const float* __restrict__ cv2w,
    const float* __restrict__ cv2b,
    int it, float* __restrict__ ws, const int* __restrict__ iw)
{
  __shared__ float mid[DD][68];
  __shared__ float mps[32][68];
  __shared__ float w1s[32][192];
  __shared__ float vv[32];
  __shared__ float w2s[204];
  __shared__ float part[4][64];
  int tid = threadIdx.x;
  int a = blockIdx.x;
  for (int idx=tid; idx<DD*68; idx+=256) (&mid[0][0])[idx] = 0.f;
  if (tid < 198) w2s[tid] = cv2w[it*198 + tid];
  int nnz = iw[IOFF_CNT + a]; if (nnz > CAP) nnz = CAP;
  __syncthreads();
  for (int q0=0; q0<nnz; q0+=32){
    int qn = nnz - q0; if (qn > 32) qn = 32;
    for (int idx=tid; idx<qn*68; idx+=256){
      int q=idx/68, cc=idx%68;
      int b = iw[IOFF_CIDX + a*CAP + q0 + q];
      mps[q][cc] = (cc>=1 && cc<=66)? ws[OFF_M + b*ID + cc-1] : 0.f;
    }
    for (int idx=tid; idx<qn*192; idx+=256){
      int q=idx/192, r=idx%192;
      int b = iw[IOFF_CIDX + a*CAP + q0 + q];
      w1s[q][r] = ws[OFF_C1R + (it*1024+b)*192 + r];
    }
    if (tid < qn) vv[tid] = ws[OFF_CVAL + a*CAP + q0 + tid];
    __syncthreads();
    for (int idx=tid; idx<DD*ID; idx+=256){
      int o = idx/ID, cc = idx%ID;
      float acc = mid[o][cc];
      for (int q=0;q<qn;q++){
        acc += vv[q]*(w1s[q][o*3]*mps[q][cc] + w1s[q][o*3+1]*mps[q][cc+1] + w1s[q][o*3+2]*mps[q][cc+2]);
      }
      mid[o][cc] = acc;
    }
    __syncthreads();
  }
  for (int idx=tid; idx<DD*ID; idx+=256){ int o=idx/ID, cc=idx%ID; mid[o][cc] += cv1b[it*DD+o]; }
  __syncthreads();
  {
    int x = tid & 63, qq = tid >> 6;
    int c0 = qq*17, cN = c0+17; if (cN > ID) cN = ID;
    float s = 0.f;
    for (int cc=c0; cc<cN; cc++){
      #pragma unroll
      for (int k=0;k<3;k++){
        int oo = x + k - 1;
        if (oo >= 0 && oo < DD) s += mid[oo][cc]*w2s[cc*3+k];
      }
    }
    part[qq][x] = s;
  }
  __syncthreads();
  if (tid < DD)
    ws[OFF_CM + a*132 + ID + tid] = part[0][tid]+part[1][tid]+part[2][tid]+part[3][tid] + cv2b[it];
}

// ---- gate + segment softmax + GRU ----
__global__ __launch_bounds__(256) void k_gru(
    const int* __restrict__ mb,
    const float* __restrict__ lfw, const float* __restrict__ lfb,
    const float* __restrict__ bih, const float* __restrict__ bhh,
    float* __restrict__ ws)
{
  __shared__ int memb[GM]; __shared__ int lcnt;
  __shared__ float cms [GM][132];
  __shared__ float hrow[GM][68];
  __shared__ float gg  [GM][132];
  __shared__ float gn1 [GM][68];
  __shared__ float gn2 [GM][68];
  __shared__ float av[GM];
  int tid = threadIdx.x, m = blockIdx.x;
  if (tid==0) lcnt = 0;
  __syncthreads();
  for (int i=tid; i<NN; i+=256)
    if (mb[i]==m){ int p = atomicAdd(&lcnt,1); if (p<GM) memb[p]=i; }
  __syncthreads();
  int M = lcnt; if (M > GM) M = GM;
  for (int idx=tid; idx<M*132; idx+=256){ int i=idx/132, j=idx%132; cms[i][j] = (j<130)? ws[OFF_CM+memb[i]*132+j] : 0.f; }
  for (int idx=tid; idx<M*68; idx+=256){ int i=idx/68, j=idx%68; hrow[i][j] = (j<66)? ws[OFF_OUT+memb[i]*ID+j] : 0.f; }
  __syncthreads();
  if (tid < 64){
    float x = -INFINITY;
    if (tid < M){
      float s = lfb[0];
      for (int j=0;j<130;j++) s += cms[tid][j]*lfw[j];
      x = (s > 0.f) ? s : 0.01f*s;
    }
    float mx = x;
    for (int o=32;o>0;o>>=1) mx = fmaxf(mx, __shfl_xor(mx,o,64));
    float ex = (tid<M) ? expf(x-mx) : 0.f;
    float sm = ex;
    for (int o=32;o>0;o>>=1) sm += __shfl_xor(sm,o,64);
    if (tid<M) av[tid] = ex/(sm + 1e-16f);
  }
  __syncthreads();
  {
    int ug = tid>>3, ig = tid&7;
    for (int u=ug; u<198; u+=32){
      const float4* w1 = (const float4*)(ws+OFF_GIH + u*132);
      const float4* w2 = (const float4*)(ws+OFF_GHH + u*68);
      float bv1 = bih[u], bv2 = bhh[u];
      for (int i0 = ig*4; i0 < M; i0 += 32){
        const float4* x0 = (const float4*)&cms[i0+0][0];
        const float4* x1 = (const float4*)&cms[i0+1][0];
        const float4* x2 = (const float4*)&cms[i0+2][0];
        const float4* x3 = (const float4*)&cms[i0+3][0];
        float4 a0=Z4,a1=Z4,a2=Z4,a3=Z4;
        for (int jj=0;jj<33;jj++){
          float4 w=w1[jj];
          FMA4(a0,x0[jj],w) FMA4(a1,x1[jj],w) FMA4(a2,x2[jj],w) FMA4(a3,x3[jj],w)
        }
        const float4* h0 = (const float4*)&hrow[i0+0][0];
        const float4* h1 = (const float4*)&hrow[i0+1][0];
        const float4* h2 = (const float4*)&hrow[i0+2][0];
        const float4* h3 = (const float4*)&hrow[i0+3][0];
        float4 b0=Z4,b1=Z4,b2=Z4,b3=Z4;
        for (int jj=0;jj<17;jj++){
          float4 w=w2[jj];
          FMA4(b0,h0[jj],w) FMA4(b1,h1[jj],w) FMA4(b2,h2[jj],w) FMA4(b3,h3[jj],w)
        }
        float d1[4] = {hsum4(a0),hsum4(a1),hsum4(a2),hsum4(a3)};
        float d2[4] = {hsum4(b0),hsum4(b1),hsum4(b2),hsum4(b3)};
        #pragma unroll
        for (int ii=0;ii<4;ii++){
          int i = i0+ii;
          if (i < M){
            float v1 = bv1 + av[i]*d1[ii];
            float v2 = bv2 + d2[ii];
            if (u < 132) gg[i][u] = sgm(v1+v2);
            else { gn1[i][u-132] = v1; gn2[i][u-132] = v2; }
          }
        }
      }
    }
  }
  __syncthreads();
  for (int idx=tid; idx<M*ID; idx+=256){
    int i = idx/ID, u = idx%ID;
    float r = gg[i][u], z = gg[i][66+u];
    float n_ = tanhf(gn1[i][u] + r*gn2[i][u]);
    ws[OFF_OUT + memb[i]*ID + u] = (1.f - z)*n_ + z*hrow[i][u];
  }
}

// ---- Set2Set readout ----
__global__ __launch_bounds__(256) void k_s2s(
    const int* __restrict__ mb,
    const float* __restrict__ wih, const float* __restrict__ whh,
    const float* __restrict__ bih, const float* __restrict__ bhh,
    float* __restrict__ ws)
{
  __shared__ int memb[MAXM]; __shared__ int lcnt;
  __shared__ float orow[MAXM][68];
  __shared__ float hsv[66], csv[66], qsv[132], gv[264];
  __shared__ float av[MAXM];
  int tid = threadIdx.x, m = blockIdx.x;
  if (tid==0) lcnt = 0;
  __syncthreads();
  for (int i=tid; i<NN; i+=256)
    if (mb[i]==m){ int p = atomicAdd(&lcnt,1); if (p<MAXM) memb[p]=i; }
  __syncthreads();
  int M = lcnt; if (M > MAXM) M = MAXM;
  for (int idx=tid; idx<M*ID; idx+=256){ int i=idx/ID, j=idx%ID; orow[i][j]=ws[OFF_OUT+memb[i]*ID+j]; }
  if (tid < 66){ hsv[tid]=0.f; csv[tid]=0.f; }
  if (tid < 132) qsv[tid]=0.f;
  __syncthreads();
  for (int step=0; step<3; step++){
    for (int u=tid; u<264; u+=256){
      float s = bih[u] + bhh[u];
      const float* w1 = wih + u*132;
      for (int j=0;j<132;j++) s += qsv[j]*w1[j];
      const float* w2 = whh + u*ID;
      for (int j=0;j<ID;j++) s += hsv[j]*w2[j];
      gv[u] = s;
    }
    __syncthreads();
    if (tid < 66){
      float ig=gv[tid], fg=gv[66+tid], gg_=gv[132+tid], og=gv[198+tid];
      float c = sgm(fg)*csv[tid] + sgm(ig)*tanhf(gg_);
      csv[tid] = c;
      hsv[tid] = sgm(og)*tanhf(c);
    }
    __syncthreads();
    if (tid < 64){
      float e = -INFINITY;
      if (tid < M){ e = 0.f; for (int j=0;j<ID;j++) e += orow[tid][j]*hsv[j]; }
      float mx = e;
      for (int o=32;o>0;o>>=1) mx = fmaxf(mx, __shfl_xor(mx,o,64));
      float ex = (tid<M) ? expf(e-mx) : 0.f;
      float sm = ex;
      for (int o=32;o>0;o>>=1) sm += __shfl_xor(sm,o,64);
      if (tid<M) av[tid] = ex/(sm + 1e-16f);
    }
    __syncthreads();
    if (tid < 66){
      float r = 0.f;
      for (int i=0;i<M;i++) r += av[i]*orow[i][tid];
      qsv[tid]      = hsv[tid];
      qsv[66+tid]   = r;
    }
    __syncthreads();
  }
  if (tid < 132) ws[OFF_QSTAR + m*132 + tid] = qsv[tid];
}

// ---- fingers MLP ----
__global__ __launch_bounds__(256) void k_fd1(
    const float* __restrict__ fing, const float* __restrict__ d1w, const float* __restrict__ d1b,
    float* __restrict__ ws)
{
  __shared__ __align__(16) float fin[1024];
  int tid = threadIdx.x;
  int b = blockIdx.x >> 4, u0 = (blockIdx.x & 15)*32;
  for (int j=tid; j<1024; j+=256) fin[j] = fing[b*1024+j];
  __syncthreads();
  int u = u0 + (tid>>3), q = tid & 7;
  const float4* w4 = (const float4*)(d1w + u*1024);
  const float4* x4 = (const float4*)fin;
  float4 a = Z4;
  for (int jj=q; jj<256; jj+=8){ float4 wv=w4[jj], xv=x4[jj]; FMA4(a,xv,wv) }
  float s = hsum4(a);
  s += __shfl_xor(s,1,64); s += __shfl_xor(s,2,64); s += __shfl_xor(s,4,64);
  if (q==0) ws[OFF_F1 + b*512 + u] = fmaxf(s + d1b[u], 0.f);
}
__global__ __launch_bounds__(256) void k_fd2(
    const float* __restrict__ d2w, const float* __restrict__ d2b, float* __restrict__ ws)
{
  __shared__ __align__(16) float f1[512];
  int tid = threadIdx.x;
  int b = blockIdx.x >> 3, u0 = (blockIdx.x & 7)*32;
  for (int j=tid; j<512; j+=256) f1[j] = ws[OFF_F1 + b*512 + j];
  __syncthreads();
  int u = u0 + (tid>>3), q = tid & 7;
  const float4* w4 = (const float4*)(d2w + u*512);
  const float4* x4 = (const float4*)f1;
  float4 a = Z4;
  for (int jj=q; jj<128; jj+=8){ float4 wv=w4[jj], xv=x4[jj]; FMA4(a,xv,wv) }
  float s = hsum4(a);
  s += __shfl_xor(s,1,64); s += __shfl_xor(s,2,64); s += __shfl_xor(s,4,64);
  if (q==0) ws[OFF_F2 + b*256 + u] = fmaxf(s + d2b[u], 0.f);
}
__global__ __launch_bounds__(256) void k_fd3p(
    const float* __restrict__ d3w, const float* __restrict__ d3b,
    const float* __restrict__ pw,  const float* __restrict__ pb,
    const float* __restrict__ ws,  float* __restrict__ outp)
{
  __shared__ __align__(16) float f2[256];
  __shared__ float f3[64];
  int tid = threadIdx.x, b = blockIdx.x;
  for (int j=tid; j<256; j+=256) f2[j] = ws[OFF_F2 + b*256 + j];
  __syncthreads();
  {
    int u = tid>>2, q = tid&3;
    const float4* w4 = (const float4*)(d3w + u*256);
    const float4* x4 = (const float4*)f2;
    float4 a = Z4;
    for (int jj=q; jj<64; jj+=4){ float4 wv=w4[jj], xv=x4[jj]; FMA4(a,xv,wv) }
    float s = hsum4(a);
    s += __shfl_xor(s,1,64); s += __shfl_xor(s,2,64);
    if (q==0) f3[u] = s + d3b[u];
  }
  __syncthreads();
  if (tid < 64){
    float s = 0.f;
    for (int j=tid; j<132; j+=64) s += ws[OFF_QSTAR + b*132 + j]*pw[j];
    s += f3[tid]*pw[132 + tid];
    for (int o=32;o>0;o>>=1) s += __shfl_xor(s,o,64);
    if (tid==0) outp[b] = s + pb[0];
  }
}

extern "C" void kernel_launch(void* const* d_in, const int* in_sizes, int n_in,
                              void* d_out, int out_size, void* d_ws, size_t ws_size,
                              hipStream_t stream)
{
  const float* mnc = (const float*)d_in[0];
  const float* ea  = (const float*)d_in[1];
  const float* fing= (const float*)d_in[2];
  const int*   eidx= (const int*)d_in[3];
  const int*   mb  = (const int*)d_in[4];
  const float* adj = (const float*)d_in[5];
  const float* e1w=(const float*)d_in[6],  *e1b=(const float*)d_in[7];
  const float* e2w=(const float*)d_in[8],  *e2b=(const float*)d_in[9];
  const float* c1w=(const float*)d_in[10], *c1b=(const float*)d_in[11];
  const float* c2w=(const float*)d_in[12], *c2b=(const float*)d_in[13];
  const float* n1w=(const float*)d_in[14], *n1b=(const float*)d_in[15];
  const float* n2w=(const float*)d_in[16], *n2b=(const float*)d_in[17];
  const float* bng=(const float*)d_in[18], *bnb=(const float*)d_in[19];
  const float* nnw=(const float*)d_in[20], *nnb=(const float*)d_in[21];
  const float* root=(const float*)d_in[22],*nnbias=(const float*)d_in[23];
  const float* cv1w=(const float*)d_in[24],*cv1b=(const float*)d_in[25];
  const float* cv2w=(const float*)d_in[26],*cv2b=(const float*)d_in[27];
  const float* lfw=(const float*)d_in[28], *lfb=(const float*)d_in[29];
  const float* gwih=(const float*)d_in[30],*gwhh=(const float*)d_in[31];
  const float* gbih=(const float*)d_in[32],*gbhh=(const float*)d_in[33];
  const float* lwih=(const float*)d_in[34],*lwhh=(const float*)d_in[35];
  const float* lbih=(const float*)d_in[36],*lbhh=(const float*)d_in[37];
  const float* d1w=(const float*)d_in[38], *d1b=(const float*)d_in[39];
  const float* d2w=(const float*)d_in[40], *d2b=(const float*)d_in[41];
  const float* d3w=(const float*)d_in[42], *d3b=(const float*)d_in[43];
  const float* pw =(const float*)d_in[44], *pb =(const float*)d_in[45];
  float* ws = (float*)d_ws;
  int*   iw = (int*)(ws + OFF_FEND);
  float* outp = (float*)d_out;

  const long long setup_total = (long long)NN*NN + EE + 16384 + 16384 + 16384
                              + 726*68 + 3*1024*192 + 198*132 + 198*68;
  int setup_blocks = (int)((setup_total + 255)/256);

  k_zero0    <<<4, 256, 0, stream>>>(iw);
  k_setup    <<<setup_blocks, 256, 0, stream>>>(adj, eidx, e1w, e2w, c1w, nnw, nnb, cv1w, gwih, gwhh, ws, iw);
  k_ab       <<<NN/32, 256, 0, stream>>>(mnc, e1b, ws);
  k_edge     <<<EE/EB, 256, 0, stream>>>(mnc, eidx, e2b, c1b, c2w, c2b, ws);
  k_node     <<<NN/NB, 256, 0, stream>>>(mnc, n1w, n1b, n2w, n2b, ws, iw);
  k_bn_stats <<<ID, 256, 0, stream>>>(ws);
  k_bn_apply <<<(NN*ID+255)/256, 256, 0, stream>>>(bng, bnb, ws);
  for (int it=0; it<3; ++it){
    k_tbuild <<<NN/16, 256, 0, stream>>>(ws);
    k_mnode  <<<NN/NB, 256, 0, stream>>>(root, nnbias, eidx, ea, ws, iw);
    k_spconv <<<NN, 256, 0, stream>>>(cv1b, cv2w, cv2b, it, ws, iw);
    k_gru    <<<BB, 256, 0, stream>>>(mb, lfw, lfb, gbih, gbhh, ws);
  }
  k_s2s      <<<BB, 256, 0, stream>>>(mb, lwih, lwhh, lbih, lbhh, ws);
  k_fd1      <<<BB*16, 256, 0, stream>>>(fing, d1w, d1b, ws);
  k_fd2      <<<BB*8, 256, 0, stream>>>(d2w, d2b, ws);
  k_fd3p     <<<BB, 256, 0, stream>>>(d3w, d3b, pw, pb, ws, outp);
}

// Round 5
// 808.649 us; speedup vs baseline: 1.5045x; 1.5045x over previous
//
#include <hip/hip_runtime.h>
#include <math.h>

// Problem constants (fixed by the reference)
#define NN 1024   // nodes
#define BB 32     // mols
#define EE 8192   // edges
#define DD 64     // DIM
#define ID 66     // IN_DIM
#define FT 63     // feats dim
#define CAP 128   // max nnz per adj column
#define ECAP 64   // max in-edges per node (data: Poisson(8), P(>64)~0)
#define MAXM 64   // max nodes per mol (s2s)
#define GM 40     // max nodes per mol (gru)

// ---- workspace layout (float offsets) ----
enum : int {
  OFF_SMIP  = 0,                        // N*66 pre-BN smi
  OFF_OUT   = OFF_SMIP + NN*ID,         // N*66 h == out
  OFF_STATS = OFF_OUT + NN*ID,          // 144 mean/rstd
  OFF_M     = OFF_STATS + 144,          // N*66 m buffer
  OFF_CM    = OFF_M + NN*ID,            // N*132 cm
  OFF_QSTAR = OFF_CM + NN*132,          // 32*132
  OFF_CVAL  = OFF_QSTAR + BB*132,       // N*CAP csc values
  OFF_A     = OFF_CVAL + NN*CAP,        // 1024*256 A = feats@W1a^T + e1b
  OFF_B     = OFF_A + 1024*256,         // 1024*256 B = feats@W1b^T
  OFF_EDGE  = OFF_B + 1024*256,         // 8192*68: [0..62]=mij, [64..66]=cw*rel
  OFF_T     = OFF_EDGE + EE*68,         // 1024*726 T[n][t*66+o]
  OFF_QAUG  = OFF_T + NN*726,           // 726*68 Qaug[(t*66+o)][i]
  OFF_W1A   = OFF_QAUG + 726*68,        // 256*64
  OFF_W1B   = OFF_W1A + 16384,          // 256*64
  OFF_WR    = OFF_W1B + 16384,          // 256
  OFF_W2P   = OFF_WR + 256,             // 64*256 padded e2w (row-major [u][256])
  OFF_C1P   = OFF_W2P + 16384,          // 256*64 padded c1w
  OFF_C1R   = OFF_C1P + 16384,          // 3*1024*192 conv1_w reorg [it][b][o*3+k]
  OFF_GIH   = OFF_C1R + 3*1024*192,     // 198*132
  OFF_GHH   = OFF_GIH + 198*132,        // 198*68
  OFF_F1    = OFF_GHH + 198*68,         // 32*512
  OFF_F2    = OFF_F1 + BB*512,          // 32*256
  OFF_FEND  = OFF_F2 + BB*256
};
enum : int {  // int region at ws + OFF_FEND
  IOFF_CNT   = 0,                 // N   csc col counts
  IOFF_CIDX  = NN,                // N*CAP
  IOFF_ECNT  = NN + NN*CAP,       // N   in-degree
  IOFF_ELIST = NN + NN*CAP + NN,  // N*ECAP edge ids sorted by dst
  IOFF_END   = NN + NN*CAP + NN + NN*ECAP
};

__device__ __forceinline__ float sgm(float x){ return 1.0f/(1.0f+expf(-x)); }
__device__ __forceinline__ float silu_(float x){ return x/(1.0f+expf(-x)); }
__device__ __forceinline__ float nan0(float v){ return (v!=v) ? 0.0f : v; }
__device__ __forceinline__ float hsum4(float4 v){ return v.x+v.y+v.z+v.w; }
#define FMA4(A,X,W) {A.x += (X).x*(W).x; A.y += (X).y*(W).y; A.z += (X).z*(W).z; A.w += (X).w*(W).w;}
#define Z4 {0.f,0.f,0.f,0.f}

// ---- zero the atomic counters ----
__global__ void k_zero0(int* __restrict__ iw){
  int i = blockIdx.x*256 + threadIdx.x;
  if (i < NN){ iw[IOFF_CNT + i] = 0; iw[IOFF_ECNT + i] = 0; }
}

// ---- one-shot setup: csc(adj), edge sort by dst, weight reorg/pad ----
__global__ void k_setup(const float* __restrict__ adj, const int* __restrict__ eidx,
                        const float* __restrict__ e1w, const float* __restrict__ e2w,
                        const float* __restrict__ c1w,
                        const float* __restrict__ nnw, const float* __restrict__ nnb,
                        const float* __restrict__ cv1w,
                        const float* __restrict__ gwih, const float* __restrict__ gwhh,
                        float* __restrict__ ws, int* __restrict__ iw){
  long long idx = (long long)blockIdx.x*256 + threadIdx.x;
  if (idx < (long long)NN*NN){
    float v = adj[idx];
    if (v != 0.0f){
      int a = (int)(idx & 1023), b = (int)(idx >> 10);
      int p = atomicAdd(iw + IOFF_CNT + a, 1);
      if (p < CAP){ iw[IOFF_CIDX + a*CAP + p] = b; ws[OFF_CVAL + a*CAP + p] = v; }
    }
    return;
  }
  idx -= (long long)NN*NN;
  if (idx < EE){
    int e = (int)idx, d = eidx[EE + e];
    int p = atomicAdd(iw + IOFF_ECNT + d, 1);
    if (p < ECAP) iw[IOFF_ELIST + d*ECAP + p] = e;
    return;
  }
  idx -= EE;
  if (idx < 16384){ int u=(int)idx>>6, j=(int)idx&63;
    ws[OFF_W1A+idx] = (u<254 && j<63)? e1w[u*127+j]      : 0.f;
    ws[OFF_W1B+idx] = (u<254 && j<63)? e1w[u*127+63+j]   : 0.f;
    if (j==0) ws[OFF_WR+u] = (u<254)? e1w[u*127+126] : 0.f;
    return; }
  idx -= 16384;
  if (idx < 16384){ int u=(int)idx>>8, j=(int)idx&255; ws[OFF_W2P+idx] = (u<63 && j<254)? e2w[u*254+j] : 0.f; return; }
  idx -= 16384;
  if (idx < 16384){ int u=(int)idx>>6, j=(int)idx&63; ws[OFF_C1P+idx] = (u<252 && j<63)? c1w[u*63+j] : 0.f; return; }
  idx -= 16384;
  if (idx < 726*68){ int to=(int)idx/68, i=(int)idx%68; int t=to/66, o=to%66;
    float v = 0.f;
    if (i < 66) v = (t<10)? nnw[(i*66+o)*10+t] : nnb[i*66+o];
    ws[OFF_QAUG+idx] = v; return; }
  idx -= 726*68;
  if (idx < 3*1024*192){ int it=(int)(idx/196608); int r=(int)(idx%196608); int b=r/192; int z=r%192; int o=z/3, k=z%3;
    ws[OFF_C1R+idx] = cv1w[((it*64+o)*1024+b)*3+k]; return; }
  idx -= 3*1024*192;
  if (idx < 198*132){ int u=(int)idx/132, j=(int)idx%132; ws[OFF_GIH+idx] = (j<130)? gwih[u*130+j] : 0.f; return; }
  idx -= 198*132;
  if (idx < 198*68){ int u=(int)idx/68, j=(int)idx%68; ws[OFF_GHH+idx] = (j<66)? gwhh[u*66+j] : 0.f; return; }
}

// ---- A/B build: A[n][u] = e1b[u] + feats[n]·W1a[u], B[n][u] = feats[n]·W1b[u] ----
__global__ __launch_bounds__(256) void k_ab(const float* __restrict__ mnc,
                                            const float* __restrict__ e1b,
                                            float* __restrict__ ws){
  __shared__ float xf[32][68];
  int tid = threadIdx.x;
  int n0 = blockIdx.x*32;
  for (int idx=tid; idx<32*64; idx+=256){ int n=idx>>6, j=idx&63;
    xf[n][j] = (j<63)? mnc[(n0+n)*ID + 3 + j] : 0.f; }
  __syncthreads();
  int eg = tid&7, ug = tid>>3;
  for (int pass=0; pass<8; pass++){
    int u = pass*32 + ug;
    const float4* wa = (const float4*)(ws + OFF_W1A + u*64);
    const float4* wb = (const float4*)(ws + OFF_W1B + u*64);
    float4 a0=Z4,a1=Z4,a2=Z4,a3=Z4,b0=Z4,b1=Z4,b2=Z4,b3=Z4;
    for (int jj=0;jj<16;jj++){
      float4 w1 = wa[jj], w2 = wb[jj];
      float4 x0 = *(const float4*)&xf[eg   ][jj*4];
      float4 x1 = *(const float4*)&xf[eg+ 8][jj*4];
      float4 x2 = *(const float4*)&xf[eg+16][jj*4];
      float4 x3 = *(const float4*)&xf[eg+24][jj*4];
      FMA4(a0,x0,w1) FMA4(a1,x1,w1) FMA4(a2,x2,w1) FMA4(a3,x3,w1)
      FMA4(b0,x0,w2) FMA4(b1,x1,w2) FMA4(b2,x2,w2) FMA4(b3,x3,w2)
    }
    if (u < 254){
      float bv = e1b[u];
      float va[4]={hsum4(a0),hsum4(a1),hsum4(a2),hsum4(a3)};
      float vb[4]={hsum4(b0),hsum4(b1),hsum4(b2),hsum4(b3)};
      #pragma unroll
      for (int i=0;i<4;i++){
        int n = n0 + eg + 8*i;
        ws[OFF_A + n*256 + u] = bv + va[i];
        ws[OFF_B + n*256 + u] = vb[i];
      }
    }
  }
}

// ---- per-edge chain: eh (from A/B) -> mij -> ch -> cw; writes EDGE buffer ----
// Direct-global weight reads (L2-resident, broadcast) -- NO LDS weight staging,
// NO accumulators live across barriers (R4 spill post-mortem: VGPR=256, 700MB scratch).
#define EB 32
__global__ __launch_bounds__(256) void k_edge(
    const float* __restrict__ mnc, const int* __restrict__ eidx,
    const float* __restrict__ e2b, const float* __restrict__ c1b,
    const float* __restrict__ c2w, const float* __restrict__ c2b,
    float* __restrict__ ws)
{
  __shared__ float eh [EB][260];   // L1 out (254 used, stride 260 = bank-conflict-free); later ch (252)
  __shared__ float mij[EB][68];    // 63 used, stride 68
  __shared__ float srel[EB][4];
  __shared__ int ssrc[EB], sdst[EB];
  int tid = threadIdx.x;
  int e0b = blockIdx.x*EB;
  if (tid < EB){
    int e = e0b + tid;
    int s = eidx[e], d = eidx[EE + e];
    ssrc[tid]=s; sdst[tid]=d;
    float rd = 0.f;
    #pragma unroll
    for (int k=0;k<3;k++){ float r = mnc[s*ID+k]-mnc[d*ID+k]; srel[tid][k]=r; rd += r*r; }
    srel[tid][3] = rd;
  }
  for (int idx=tid; idx<EB*5; idx+=256){ mij[idx/5][63+idx%5] = 0.f; }
  __syncthreads();
  // L1: eh = silu(A[dst] + B[src] + wr*rd)   (A carries e1b)
  for (int idx=tid; idx<EB*256; idx+=256){
    int e = idx>>8, u = idx&255;
    float v = 0.f;
    if (u < 254) v = silu_(ws[OFF_A + sdst[e]*256 + u] + ws[OFF_B + ssrc[e]*256 + u]
                           + ws[OFF_WR + u]*srel[e][3]);
    eh[e][u] = v;
  }
  for (int idx=tid; idx<EB*4; idx+=256){ eh[idx>>2][256+(idx&3)] = 0.f; }
  __syncthreads();
  int eg = tid&7, ug = tid>>3;   // 4 edges (eg+8i) x 2 units (2ug,2ug+1)
  // L2: mij = silu(eh @ W2P^T + e2b), K=256, weights direct from global (L2)
  {
    int u0 = 2*ug, u1 = 2*ug+1;
    const float4* w0 = (const float4*)(ws+OFF_W2P + u0*256);
    const float4* w1 = (const float4*)(ws+OFF_W2P + u1*256);
    float4 a0=Z4,a1=Z4,a2=Z4,a3=Z4,b0=Z4,b1=Z4,b2=Z4,b3=Z4;
    for (int jj=0;jj<64;jj++){
      float4 wv0=w0[jj], wv1=w1[jj];
      float4 x0 = *(const float4*)&eh[eg   ][jj*4];
      float4 x1 = *(const float4*)&eh[eg+ 8][jj*4];
      float4 x2 = *(const float4*)&eh[eg+16][jj*4];
      float4 x3 = *(const float4*)&eh[eg+24][jj*4];
      FMA4(a0,x0,wv0) FMA4(a1,x1,wv0) FMA4(a2,x2,wv0) FMA4(a3,x3,wv0)
      FMA4(b0,x0,wv1) FMA4(b1,x1,wv1) FMA4(b2,x2,wv1) FMA4(b3,x3,wv1)
    }
    float va[4]={hsum4(a0),hsum4(a1),hsum4(a2),hsum4(a3)};
    float vb[4]={hsum4(b0),hsum4(b1),hsum4(b2),hsum4(b3)};
    float bv0 = e2b[u0];
    #pragma unroll
    for (int i=0;i<4;i++){
      int e = eg + 8*i;
      float v = silu_(bv0 + va[i]);
      mij[e][u0] = v; ws[OFF_EDGE + (e0b+e)*68 + u0] = v;
      if (u1 < 63){
        float v1 = silu_(e2b[u1] + vb[i]);
        mij[e][u1] = v1; ws[OFF_EDGE + (e0b+e)*68 + u1] = v1;
      }
    }
  }
  __syncthreads();
  // L3: ch = silu(mij @ C1P^T + c1b) into eh, K=64, weights direct from global.
  // Each uc chunk: fresh accumulators, distinct u-range, no barrier needed between chunks.
  for (int uc=0; uc<4; uc++){
    int u0 = uc*64 + 2*ug, u1 = u0+1;
    const float4* w0 = (const float4*)(ws+OFF_C1P + u0*64);
    const float4* w1 = (const float4*)(ws+OFF_C1P + u1*64);
    float4 a0=Z4,a1=Z4,a2=Z4,a3=Z4,b0=Z4,b1=Z4,b2=Z4,b3=Z4;
    for (int jj=0;jj<16;jj++){
      float4 wv0=w0[jj], wv1=w1[jj];
      float4 x0 = *(const float4*)&mij[eg   ][jj*4];
      float4 x1 = *(const float4*)&mij[eg+ 8][jj*4];
      float4 x2 = *(const float4*)&mij[eg+16][jj*4];
      float4 x3 = *(const float4*)&mij[eg+24][jj*4];
      FMA4(a0,x0,wv0) FMA4(a1,x1,wv0) FMA4(a2,x2,wv0) FMA4(a3,x3,wv0)
      FMA4(b0,x0,wv1) FMA4(b1,x1,wv1) FMA4(b2,x2,wv1) FMA4(b3,x3,wv1)
    }
    float va[4]={hsum4(a0),hsum4(a1),hsum4(a2),hsum4(a3)};
    float vb[4]={hsum4(b0),hsum4(b1),hsum4(b2),hsum4(b3)};
    #pragma unroll
    for (int i=0;i<4;i++){
      int e = eg + 8*i;
      if (u0 < 252) eh[e][u0] = silu_(c1b[u0] + va[i]);
      if (u1 < 252) eh[e][u1] = silu_(c1b[u1] + vb[i]);
    }
  }
  __syncthreads();
  // L4: cw = ch·c2w + c2b; EDGE[64..66] = cw*rel
  {
    int e = tid>>3, q = tid&7;
    const float4* xr = (const float4*)&eh[e][0];
    const float4* wr4 = (const float4*)c2w;
    float4 a = Z4;
    for (int jj=q; jj<63; jj+=8){ float4 xv=xr[jj], wv=wr4[jj]; FMA4(a,xv,wv) }
    float s = hsum4(a);
    s += __shfl_down(s,4,64); s += __shfl_down(s,2,64); s += __shfl_down(s,1,64);
    if (q == 0){
      float cw = s + c2b[0];
      #pragma unroll
      for (int k=0;k<3;k++) ws[OFF_EDGE + (e0b+e)*68 + 64 + k] = cw*srel[e][k];
    }
  }
}

// ---- node MLP + gathers (m_i, coor) -> smi_pre ----
#define NB 16
__global__ __launch_bounds__(256) void k_node(
    const float* __restrict__ mnc,
    const float* __restrict__ n1w, const float* __restrict__ n1b,
    const float* __restrict__ n2w, const float* __restrict__ n2b,
    float* __restrict__ ws, const int* __restrict__ iw)
{
  __shared__ float xin[NB][132];
  __shared__ float t1 [NB][132];
  int tid = threadIdx.x;
  int n0 = blockIdx.x*NB;
  for (int idx=tid; idx<NB*126; idx+=256){
    int e = idx/126, j = idx%126;
    int node = n0 + e;
    float v;
    if (j < 63) v = mnc[node*ID + 3 + j];
    else {
      int u = j - 63;
      int cnt = iw[IOFF_ECNT+node]; if (cnt > ECAP) cnt = ECAP;
      v = 0.f;
      for (int q=0;q<cnt;q++) v += ws[OFF_EDGE + iw[IOFF_ELIST+node*ECAP+q]*68 + u];
    }
    xin[e][j] = v;
  }
  __syncthreads();
  for (int idx=tid; idx<NB*126; idx+=256){
    int e = idx & 15, u = idx >> 4;
    float s = n1b[u];
    const float* w = n1w + u*126;
    for (int j=0;j<126;j++) s += xin[e][j]*w[j];
    t1[e][u] = silu_(s);
  }
  __syncthreads();
  for (int idx=tid; idx<NB*FT; idx+=256){
    int e = idx & 15, u = idx >> 4;
    float s = n2b[u];
    const float* w = n2w + u*126;
    for (int j=0;j<126;j++) s += t1[e][j]*w[j];
    int node = n0 + e;
    ws[OFF_SMIP + node*ID + 3 + u] = nan0(xin[e][u] + s);
  }
  if (tid < NB*3){
    int e = tid/3, k = tid%3;
    int node = n0 + e;
    int cnt = iw[IOFF_ECNT+node]; if (cnt > ECAP) cnt = ECAP;
    float s = mnc[node*ID + k];
    for (int q=0;q<cnt;q++) s += ws[OFF_EDGE + iw[IOFF_ELIST+node*ECAP+q]*68 + 64 + k];
    ws[OFF_SMIP + node*ID + k] = nan0(s);
  }
}

// ---- batchnorm ----
__global__ __launch_bounds__(256) void k_bn_stats(float* __restrict__ ws){
  __shared__ float scr[8];
  int j = blockIdx.x, tid = threadIdx.x;
  float s=0.f, ss=0.f;
  for (int i=tid; i<NN; i+=256){ float x = ws[OFF_SMIP + i*ID + j]; s+=x; ss+=x*x; }
  for (int o=32;o>0;o>>=1){ s += __shfl_down(s,o,64); ss += __shfl_down(ss,o,64); }
  int w = tid>>6;
  if ((tid&63)==0){ scr[w]=s; scr[4+w]=ss; }
  __syncthreads();
  if (tid==0){
    float S=0,SS=0;
    for (int q=0;q<4;q++){S+=scr[q];SS+=scr[4+q];}
    float mean = S/NN;
    float var  = SS/NN - mean*mean;
    ws[OFF_STATS + j]      = mean;
    ws[OFF_STATS + 66 + j] = 1.0f/sqrtf(var + 1e-5f);
  }
}
__global__ void k_bn_apply(const float* __restrict__ bng, const float* __restrict__ bnb,
                           float* __restrict__ ws){
  int idx = blockIdx.x*256 + threadIdx.x;
  if (idx < NN*ID){
    int j = idx % ID;
    ws[OFF_OUT + idx] = bng[j]*(ws[OFF_SMIP+idx]-ws[OFF_STATS+j])*ws[OFF_STATS+66+j] + bnb[j];
  }
}

// ---- T[n][t*66+o] = sum_i out[n,i]*Qaug[i,t,o]  (GEMM 1024x66x726) ----
__global__ __launch_bounds__(256) void k_tbuild(float* __restrict__ ws){
  __shared__ float xs[16][68];
  int tid = threadIdx.x;
  int n0 = blockIdx.x*16;
  for (int idx=tid; idx<16*68; idx+=256){ int n=idx/68, j=idx%68;
    xs[n][j] = (j<66)? ws[OFF_OUT + (n0+n)*ID + j] : 0.f; }
  __syncthreads();
  for (int pass=0; pass<3; pass++){
    int to = pass*256 + tid;
    if (to < 726){
      float acc[16];
      #pragma unroll
      for (int n=0;n<16;n++) acc[n] = 0.f;
      const float4* qp = (const float4*)(ws + OFF_QAUG + to*68);
      for (int jj=0;jj<17;jj++){
        float4 w = qp[jj];
        #pragma unroll
        for (int n=0;n<16;n++){
          float4 x = *(const float4*)&xs[n][jj*4];
          acc[n] += x.x*w.x + x.y*w.y + x.z*w.z + x.w*w.w;
        }
      }
      #pragma unroll
      for (int n=0;n<16;n++) ws[OFF_T + (n0+n)*726 + to] = acc[n];
    }
  }
}

// ---- m = relu(gathered_msg/deg + out@root + nn_bias) ----
__global__ __launch_bounds__(256) void k_mnode(
    const float* __restrict__ root, const float* __restrict__ nnbias,
    const int* __restrict__ eidx, const float* __restrict__ ea,
    float* __restrict__ ws, const int* __restrict__ iw)
{
  __shared__ float rs[66][68];
  __shared__ float xo[NB][68];
  int tid = threadIdx.x;
  int n0 = blockIdx.x*NB;
  for (int idx=tid; idx<66*66; idx+=256) rs[idx/66][idx%66] = root[idx];
  for (int idx=tid; idx<NB*66; idx+=256) xo[idx/66][idx%66] = ws[OFF_OUT + n0*ID + idx];
  __syncthreads();
  for (int idx=tid; idx<NB*66; idx+=256){
    int n = idx/66, o = idx%66;
    int node = n0 + n;
    int rawcnt = iw[IOFF_ECNT+node];
    int cnt = rawcnt > ECAP ? ECAP : rawcnt;
    float magg = 0.f;
    for (int q=0;q<cnt;q++){
      int e = iw[IOFF_ELIST + node*ECAP + q];
      int s = eidx[e];
      const float* Tp = ws + OFF_T + s*726 + o;
      const float* eap = ea + e*10;
      float av = Tp[660];                 // t=10 slot (nn_b), ea_aug=1
      #pragma unroll
      for (int t=0;t<10;t++) av += eap[t]*Tp[t*66];
      magg += av;
    }
    float deg = fmaxf((float)rawcnt, 1.0f);
    float s2 = nnbias[o] + magg/deg;
    for (int j=0;j<66;j++) s2 += xo[n][j]*rs[j][o];
    s2 = fmaxf(s2, 0.0f);
    ws[OFF_M  + node*ID  + o] = s2;
    ws[OFF_CM + node*132 + o] = s2;
  }
}

// ---- fused sparse conv (bulk-staged neighbors, no per-nnz sync) ----
__global__ __launch_bounds__(256) void k_spconv(
    const float* __restrict__ cv1b, const float* __restrict__ cv2w,
    const float* __restrict__ cv2b,
    int it, float* __restrict__ ws, const int* __restrict__ iw)
{
  __shared__ float mid[DD][68];
  __shared__ float mps[32][68];
  __shared__ float w1s[32][192];
  __shared__ float vv[32];
  __shared__ float w2s[204];
  __shared__ float part[4][64];
  int tid = threadIdx.x;
  int a = blockIdx.x;
  for (int idx=tid; idx<DD*68; idx+=256) (&mid[0][0])[idx] = 0.f;
  if (tid < 198) w2s[tid] = cv2w[it*198 + tid];
  int nnz = iw[IOFF_CNT + a]; if (nnz > CAP) nnz = CAP;
  __syncthreads();
  for (int q0=0; q0<nnz; q0+=32){
    int qn = nnz - q0; if (qn > 32) qn = 32;
    for (int idx=tid; idx<qn*68; idx+=256){
      int q=idx/68, cc=idx%68;
      int b = iw[IOFF_CIDX + a*CAP + q0 + q];
      mps[q][cc] = (cc>=1 && cc<=66)? ws[OFF_M + b*ID + cc-1] : 0.f;
    }
    for (int idx=tid; idx<qn*192; idx+=256){
      int q=idx/192, r=idx%192;
      int b = iw[IOFF_CIDX + a*CAP + q0 + q];
      w1s[q][r] = ws[OFF_C1R + (it*1024+b)*192 + r];
    }
    if (tid < qn) vv[tid] = ws[OFF_CVAL + a*CAP + q0 + tid];
    __syncthreads();
    for (int idx=tid; idx<DD*ID; idx+=256){
      int o = idx/ID, cc = idx%ID;
      float acc = mid[o][cc];
      for (int q=0;q<qn;q++){
        acc += vv[q]*(w1s[q][o*3]*mps[q][cc] + w1s[q][o*3+1]*mps[q][cc+1] + w1s[q][o*3+2]*mps[q][cc+2]);
      }
      mid[o][cc] = acc;
    }
    __syncthreads();
  }
  for (int idx=tid; idx<DD*ID; idx+=256){ int o=idx/ID, cc=idx%ID; mid[o][cc] += cv1b[it*DD+o]; }
  __syncthreads();
  {
    int x = tid & 63, qq = tid >> 6;
    int c0 = qq*17, cN = c0+17; if (cN > ID) cN = ID;
    float s = 0.f;
    for (int cc=c0; cc<cN; cc++){
      #pragma unroll
      for (int k=0;k<3;k++){
        int oo = x + k - 1;
        if (oo >= 0 && oo < DD) s += mid[oo][cc]*w2s[cc*3+k];
      }
    }
    part[qq][x] = s;
  }
  __syncthreads();
  if (tid < DD)
    ws[OFF_CM + a*132 + ID + tid] = part[0][tid]+part[1][tid]+part[2][tid]+part[3][tid] + cv2b[it];
}

// ---- gate + segment softmax + GRU ----
__global__ __launch_bounds__(256) void k_gru(
    const int* __restrict__ mb,
    const float* __restrict__ lfw, const float* __restrict__ lfb,
    const float* __restrict__ bih, const float* __restrict__ bhh,
    float* __restrict__ ws)
{
  __shared__ int memb[GM]; __shared__ int lcnt;
  __shared__ float cms [GM][132];
  __shared__ float hrow[GM][68];
  __shared__ float gg  [GM][132];
  __shared__ float gn1 [GM][68];
  __shared__ float gn2 [GM][68];
  __shared__ float av[GM];
  int tid = threadIdx.x, m = blockIdx.x;
  if (tid==0) lcnt = 0;
  __syncthreads();
  for (int i=tid; i<NN; i+=256)
    if (mb[i]==m){ int p = atomicAdd(&lcnt,1); if (p<GM) memb[p]=i; }
  __syncthreads();
  int M = lcnt; if (M > GM) M = GM;
  for (int idx=tid; idx<M*132; idx+=256){ int i=idx/132, j=idx%132; cms[i][j] = (j<130)? ws[OFF_CM+memb[i]*132+j] : 0.f; }
  for (int idx=tid; idx<M*68; idx+=256){ int i=idx/68, j=idx%68; hrow[i][j] = (j<66)? ws[OFF_OUT+memb[i]*ID+j] : 0.f; }
  __syncthreads();
  if (tid < 64){
    float x = -INFINITY;
    if (tid < M){
      float s = lfb[0];
      for (int j=0;j<130;j++) s += cms[tid][j]*lfw[j];
      x = (s > 0.f) ? s : 0.01f*s;
    }
    float mx = x;
    for (int o=32;o>0;o>>=1) mx = fmaxf(mx, __shfl_xor(mx,o,64));
    float ex = (tid<M) ? expf(x-mx) : 0.f;
    float sm = ex;
    for (int o=32;o>0;o>>=1) sm += __shfl_xor(sm,o,64);
    if (tid<M) av[tid] = ex/(sm + 1e-16f);
  }
  __syncthreads();
  {
    int ug = tid>>3, ig = tid&7;
    for (int u=ug; u<198; u+=32){
      const float4* w1 = (const float4*)(ws+OFF_GIH + u*132);
      const float4* w2 = (const float4*)(ws+OFF_GHH + u*68);
      float bv1 = bih[u], bv2 = bhh[u];
      for (int i0 = ig*4; i0 < M; i0 += 32){
        const float4* x0 = (const float4*)&cms[i0+0][0];
        const float4* x1 = (const float4*)&cms[i0+1][0];
        const float4* x2 = (const float4*)&cms[i0+2][0];
        const float4* x3 = (const float4*)&cms[i0+3][0];
        float4 a0=Z4,a1=Z4,a2=Z4,a3=Z4;
        for (int jj=0;jj<33;jj++){
          float4 w=w1[jj];
          FMA4(a0,x0[jj],w) FMA4(a1,x1[jj],w) FMA4(a2,x2[jj],w) FMA4(a3,x3[jj],w)
        }
        const float4* h0 = (const float4*)&hrow[i0+0][0];
        const float4* h1 = (const float4*)&hrow[i0+1][0];
        const float4* h2 = (const float4*)&hrow[i0+2][0];
        const float4* h3 = (const float4*)&hrow[i0+3][0];
        float4 b0=Z4,b1=Z4,b2=Z4,b3=Z4;
        for (int jj=0;jj<17;jj++){
          float4 w=w2[jj];
          FMA4(b0,h0[jj],w) FMA4(b1,h1[jj],w) FMA4(b2,h2[jj],w) FMA4(b3,h3[jj],w)
        }
        float d1[4] = {hsum4(a0),hsum4(a1),hsum4(a2),hsum4(a3)};
        float d2[4] = {hsum4(b0),hsum4(b1),hsum4(b2),hsum4(b3)};
        #pragma unroll
        for (int ii=0;ii<4;ii++){
          int i = i0+ii;
          if (i < M){
            float v1 = bv1 + av[i]*d1[ii];
            float v2 = bv2 + d2[ii];
            if (u < 132) gg[i][u] = sgm(v1+v2);
            else { gn1[i][u-132] = v1; gn2[i][u-132] = v2; }
          }
        }
      }
    }
  }
  __syncthreads();
  for (int idx=tid; idx<M*ID; idx+=256){
    int i = idx/ID, u = idx%ID;
    float r = gg[i][u], z = gg[i][66+u];
    float n_ = tanhf(gn1[i][u] + r*gn2[i][u]);
    ws[OFF_OUT + memb[i]*ID + u] = (1.f - z)*n_ + z*hrow[i][u];
  }
}

// ---- Set2Set readout ----
__global__ __launch_bounds__(256) void k_s2s(
    const int* __restrict__ mb,
    const float* __restrict__ wih, const float* __restrict__ whh,
    const float* __restrict__ bih, const float* __restrict__ bhh,
    float* __restrict__ ws)
{
  __shared__ int memb[MAXM]; __shared__ int lcnt;
  __shared__ float orow[MAXM][68];
  __shared__ float hsv[66], csv[66], qsv[132], gv[264];
  __shared__ float av[MAXM];
  int tid = threadIdx.x, m = blockIdx.x;
  if (tid==0) lcnt = 0;
  __syncthreads();
  for (int i=tid; i<NN; i+=256)
    if (mb[i]==m){ int p = atomicAdd(&lcnt,1); if (p<MAXM) memb[p]=i; }
  __syncthreads();
  int M = lcnt; if (M > MAXM) M = MAXM;
  for (int idx=tid; idx<M*ID; idx+=256){ int i=idx/ID, j=idx%ID; orow[i][j]=ws[OFF_OUT+memb[i]*ID+j]; }
  if (tid < 66){ hsv[tid]=0.f; csv[tid]=0.f; }
  if (tid < 132) qsv[tid]=0.f;
  __syncthreads();
  for (int step=0; step<3; step++){
    for (int u=tid; u<264; u+=256){
      float s = bih[u] + bhh[u];
      const float* w1 = wih + u*132;
      for (int j=0;j<132;j++) s += qsv[j]*w1[j];
      const float* w2 = whh + u*ID;
      for (int j=0;j<ID;j++) s += hsv[j]*w2[j];
      gv[u] = s;
    }
    __syncthreads();
    if (tid < 66){
      float ig=gv[tid], fg=gv[66+tid], gg_=gv[132+tid], og=gv[198+tid];
      float c = sgm(fg)*csv[tid] + sgm(ig)*tanhf(gg_);
      csv[tid] = c;
      hsv[tid] = sgm(og)*tanhf(c);
    }
    __syncthreads();
    if (tid < 64){
      float e = -INFINITY;
      if (tid < M){ e = 0.f; for (int j=0;j<ID;j++) e += orow[tid][j]*hsv[j]; }
      float mx = e;
      for (int o=32;o>0;o>>=1) mx = fmaxf(mx, __shfl_xor(mx,o,64));
      float ex = (tid<M) ? expf(e-mx) : 0.f;
      float sm = ex;
      for (int o=32;o>0;o>>=1) sm += __shfl_xor(sm,o,64);
      if (tid<M) av[tid] = ex/(sm + 1e-16f);
    }
    __syncthreads();
    if (tid < 66){
      float r = 0.f;
      for (int i=0;i<M;i++) r += av[i]*orow[i][tid];
      qsv[tid]      = hsv[tid];
      qsv[66+tid]   = r;
    }
    __syncthreads();
  }
  if (tid < 132) ws[OFF_QSTAR + m*132 + tid] = qsv[tid];
}

// ---- fingers MLP ----
__global__ __launch_bounds__(256) void k_fd1(
    const float* __restrict__ fing, const float* __restrict__ d1w, const float* __restrict__ d1b,
    float* __restrict__ ws)
{
  __shared__ __align__(16) float fin[1024];
  int tid = threadIdx.x;
  int b = blockIdx.x >> 4, u0 = (blockIdx.x & 15)*32;
  for (int j=tid; j<1024; j+=256) fin[j] = fing[b*1024+j];
  __syncthreads();
  int u = u0 + (tid>>3), q = tid & 7;
  const float4* w4 = (const float4*)(d1w + u*1024);
  const float4* x4 = (const float4*)fin;
  float4 a = Z4;
  for (int jj=q; jj<256; jj+=8){ float4 wv=w4[jj], xv=x4[jj]; FMA4(a,xv,wv) }
  float s = hsum4(a);
  s += __shfl_xor(s,1,64); s += __shfl_xor(s,2,64); s += __shfl_xor(s,4,64);
  if (q==0) ws[OFF_F1 + b*512 + u] = fmaxf(s + d1b[u], 0.f);
}
__global__ __launch_bounds__(256) void k_fd2(
    const float* __restrict__ d2w, const float* __restrict__ d2b, float* __restrict__ ws)
{
  __shared__ __align__(16) float f1[512];
  int tid = threadIdx.x;
  int b = blockIdx.x >> 3, u0 = (blockIdx.x & 7)*32;
  for (int j=tid; j<512; j+=256) f1[j] = ws[OFF_F1 + b*512 + j];
  __syncthreads();
  int u = u0 + (tid>>3), q = tid & 7;
  const float4* w4 = (const float4*)(d2w + u*512);
  const float4* x4 = (const float4*)f1;
  float4 a = Z4;
  for (int jj=q; jj<128; jj+=8){ float4 wv=w4[jj], xv=x4[jj]; FMA4(a,xv,wv) }
  float s = hsum4(a);
  s += __shfl_xor(s,1,64); s += __shfl_xor(s,2,64); s += __shfl_xor(s,4,64);
  if (q==0) ws[OFF_F2 + b*256 + u] = fmaxf(s + d2b[u], 0.f);
}
__global__ __launch_bounds__(256) void k_fd3p(
    const float* __restrict__ d3w, const float* __restrict__ d3b,
    const float* __restrict__ pw,  const float* __restrict__ pb,
    const float* __restrict__ ws,  float* __restrict__ outp)
{
  __shared__ __align__(16) float f2[256];
  __shared__ float f3[64];
  int tid = threadIdx.x, b = blockIdx.x;
  for (int j=tid; j<256; j+=256) f2[j] = ws[OFF_F2 + b*256 + j];
  __syncthreads();
  {
    int u = tid>>2, q = tid&3;
    const float4* w4 = (const float4*)(d3w + u*256);
    const float4* x4 = (const float4*)f2;
    float4 a = Z4;
    for (int jj=q; jj<64; jj+=4){ float4 wv=w4[jj], xv=x4[jj]; FMA4(a,xv,wv) }
    float s = hsum4(a);
    s += __shfl_xor(s,1,64); s += __shfl_xor(s,2,64);
    if (q==0) f3[u] = s + d3b[u];
  }
  __syncthreads();
  if (tid < 64){
    float s = 0.f;
    for (int j=tid; j<132; j+=64) s += ws[OFF_QSTAR + b*132 + j]*pw[j];
    s += f3[tid]*pw[132 + tid];
    for (int o=32;o>0;o>>=1) s += __shfl_xor(s,o,64);
    if (tid==0) outp[b] = s + pb[0];
  }
}

extern "C" void kernel_launch(void* const* d_in, const int* in_sizes, int n_in,
                              void* d_out, int out_size, void* d_ws, size_t ws_size,
                              hipStream_t stream)
{
  const float* mnc = (const float*)d_in[0];
  const float* ea  = (const float*)d_in[1];
  const float* fing= (const float*)d_in[2];
  const int*   eidx= (const int*)d_in[3];
  const int*   mb  = (const int*)d_in[4];
  const float* adj = (const float*)d_in[5];
  const float* e1w=(const float*)d_in[6],  *e1b=(const float*)d_in[7];
  const float* e2w=(const float*)d_in[8],  *e2b=(const float*)d_in[9];
  const float* c1w=(const float*)d_in[10], *c1b=(const float*)d_in[11];
  const float* c2w=(const float*)d_in[12], *c2b=(const float*)d_in[13];
  const float* n1w=(const float*)d_in[14], *n1b=(const float*)d_in[15];
  const float* n2w=(const float*)d_in[16], *n2b=(const float*)d_in[17];
  const float* bng=(const float*)d_in[18], *bnb=(const float*)d_in[19];
  const float* nnw=(const float*)d_in[20], *nnb=(const float*)d_in[21];
  const float* root=(const float*)d_in[22],*nnbias=(const float*)d_in[23];
  const float* cv1w=(const float*)d_in[24],*cv1b=(const float*)d_in[25];
  const float* cv2w=(const float*)d_in[26],*cv2b=(const float*)d_in[27];
  const float* lfw=(const float*)d_in[28], *lfb=(const float*)d_in[29];
  const float* gwih=(const float*)d_in[30],*gwhh=(const float*)d_in[31];
  const float* gbih=(const float*)d_in[32],*gbhh=(const float*)d_in[33];
  const float* lwih=(const float*)d_in[34],*lwhh=(const float*)d_in[35];
  const float* lbih=(const float*)d_in[36],*lbhh=(const float*)d_in[37];
  const float* d1w=(const float*)d_in[38], *d1b=(const float*)d_in[39];
  const float* d2w=(const float*)d_in[40], *d2b=(const float*)d_in[41];
  const float* d3w=(const float*)d_in[42], *d3b=(const float*)d_in[43];
  const float* pw =(const float*)d_in[44], *pb =(const float*)d_in[45];
  float* ws = (float*)d_ws;
  int*   iw = (int*)(ws + OFF_FEND);
  float* outp = (float*)d_out;

  const long long setup_total = (long long)NN*NN + EE + 16384 + 16384 + 16384
                              + 726*68 + 3*1024*192 + 198*132 + 198*68;
  int setup_blocks = (int)((setup_total + 255)/256);

  k_zero0    <<<4, 256, 0, stream>>>(iw);
  k_setup    <<<setup_blocks, 256, 0, stream>>>(adj, eidx, e1w, e2w, c1w, nnw, nnb, cv1w, gwih, gwhh, ws, iw);
  k_ab       <<<NN/32, 256, 0, stream>>>(mnc, e1b, ws);
  k_edge     <<<EE/EB, 256, 0, stream>>>(mnc, eidx, e2b, c1b, c2w, c2b, ws);
  k_node     <<<NN/NB, 256, 0, stream>>>(mnc, n1w, n1b, n2w, n2b, ws, iw);
  k_bn_stats <<<ID, 256, 0, stream>>>(ws);
  k_bn_apply <<<(NN*ID+255)/256, 256, 0, stream>>>(bng, bnb, ws);
  for (int it=0; it<3; ++it){
    k_tbuild <<<NN/16, 256, 0, stream>>>(ws);
    k_mnode  <<<NN/NB, 256, 0, stream>>>(root, nnbias, eidx, ea, ws, iw);
    k_spconv <<<NN, 256, 0, stream>>>(cv1b, cv2w, cv2b, it, ws, iw);
    k_gru    <<<BB, 256, 0, stream>>>(mb, lfw, lfb, gbih, gbhh, ws);
  }
  k_s2s      <<<BB, 256, 0, stream>>>(mb, lwih, lwhh, lbih, lbhh, ws);
  k_fd1      <<<BB*16, 256, 0, stream>>>(fing, d1w, d1b, ws);
  k_fd2      <<<BB*8, 256, 0, stream>>>(d2w, d2b, ws);
  k_fd3p     <<<BB, 256, 0, stream>>>(d3w, d3b, pw, pb, ws, outp);
}

// Round 7
// 793.785 us; speedup vs baseline: 1.5327x; 1.0187x over previous
//
#include <hip/hip_runtime.h>
#include <math.h>

// Problem constants (fixed by the reference)
#define NN 1024   // nodes
#define BB 32     // mols
#define EE 8192   // edges
#define DD 64     // DIM
#define ID 66     // IN_DIM
#define FT 63     // feats dim
#define CAP 128   // max nnz per adj column
#define ECAP 64   // max in-edges per node
#define MAXM 64   // max nodes per mol (s2s)
#define GM 40     // max nodes per mol (gru)
#define GUC 9     // gru outputs per u-chunk (8 chunks x 9 >= 66)

// ---- workspace layout (float offsets) ----
enum : int {
  OFF_SMIP  = 0,                        // N*66 pre-BN smi
  OFF_OUT   = OFF_SMIP + NN*ID,         // N*66 h buffer 0
  OFF_STATS = OFF_OUT + NN*ID,          // 144 mean/rstd
  OFF_M     = OFF_STATS + 144,          // N*66 m buffer
  OFF_CM    = OFF_M + NN*ID,            // N*132 cm
  OFF_QSTAR = OFF_CM + NN*132,          // 32*132
  OFF_CVAL  = OFF_QSTAR + BB*132,       // N*CAP csc values
  OFF_A     = OFF_CVAL + NN*CAP,        // 1024*256 A = feats@W1a^T + e1b
  OFF_B     = OFF_A + 1024*256,         // 1024*256 B = feats@W1b^T
  OFF_EDGE  = OFF_B + 1024*256,         // 8192*68: [0..62]=mij, [64..66]=cw*rel
  OFF_T     = OFF_EDGE + EE*68,         // 1024*726 T[n][t*66+o]
  OFF_QAUG  = OFF_T + NN*726,           // 726*68 Qaug[(t*66+o)][i]
  OFF_W1A   = OFF_QAUG + 726*68,        // 256*64
  OFF_W1B   = OFF_W1A + 16384,          // 256*64
  OFF_WR    = OFF_W1B + 16384,          // 256
  OFF_W2P   = OFF_WR + 256,             // 64*256 padded e2w
  OFF_C1P   = OFF_W2P + 16384,          // 256*64 padded c1w
  OFF_C1R   = OFF_C1P + 16384,          // 3*1024*192 conv1_w reorg
  OFF_GIH   = OFF_C1R + 3*1024*192,     // 198*132
  OFF_GHH   = OFF_GIH + 198*132,        // 198*68
  OFF_F1    = OFF_GHH + 198*68,         // 32*512
  OFF_F2    = OFF_F1 + BB*512,          // 32*256
  OFF_OUT2  = OFF_F2 + BB*256,          // N*66 h buffer 1 (ping-pong)
  OFF_N1P   = OFF_OUT2 + NN*ID,         // 126*128 padded n1w
  OFF_N2P   = OFF_N1P + 126*128,        // 63*128  padded n2w
  OFF_FEND  = OFF_N2P + 63*128
};
enum : int {  // int region at ws + OFF_FEND
  IOFF_CNT   = 0,                 // N   csc col counts
  IOFF_CIDX  = NN,                // N*CAP
  IOFF_ECNT  = NN + NN*CAP,       // N   in-degree
  IOFF_ELIST = NN + NN*CAP + NN,  // N*ECAP edge ids sorted by dst
  IOFF_END   = NN + NN*CAP + NN + NN*ECAP
};

__device__ __forceinline__ float sgm(float x){ return 1.0f/(1.0f+expf(-x)); }
__device__ __forceinline__ float silu_(float x){ return x/(1.0f+expf(-x)); }
__device__ __forceinline__ float nan0(float v){ return (v!=v) ? 0.0f : v; }
__device__ __forceinline__ float hsum4(float4 v){ return v.x+v.y+v.z+v.w; }
#define FMA4(A,X,W) {A.x += (X).x*(W).x; A.y += (X).y*(W).y; A.z += (X).z*(W).z; A.w += (X).w*(W).w;}
#define Z4 {0.f,0.f,0.f,0.f}

// ---- zero the atomic counters ----
__global__ void k_zero0(int* __restrict__ iw){
  int i = blockIdx.x*256 + threadIdx.x;
  if (i < NN){ iw[IOFF_CNT + i] = 0; iw[IOFF_ECNT + i] = 0; }
}

// ---- one-shot setup: csc(adj), edge sort by dst, weight reorg/pad ----
__global__ void k_setup(const float* __restrict__ adj, const int* __restrict__ eidx,
                        const float* __restrict__ e1w, const float* __restrict__ e2w,
                        const float* __restrict__ c1w,
                        const float* __restrict__ nnw, const float* __restrict__ nnb,
                        const float* __restrict__ cv1w,
                        const float* __restrict__ gwih, const float* __restrict__ gwhh,
                        const float* __restrict__ n1w, const float* __restrict__ n2w,
                        float* __restrict__ ws, int* __restrict__ iw){
  long long idx = (long long)blockIdx.x*256 + threadIdx.x;
  if (idx < (long long)NN*NN){
    float v = adj[idx];
    if (v != 0.0f){
      int a = (int)(idx & 1023), b = (int)(idx >> 10);
      int p = atomicAdd(iw + IOFF_CNT + a, 1);
      if (p < CAP){ iw[IOFF_CIDX + a*CAP + p] = b; ws[OFF_CVAL + a*CAP + p] = v; }
    }
    return;
  }
  idx -= (long long)NN*NN;
  if (idx < EE){
    int e = (int)idx, d = eidx[EE + e];
    int p = atomicAdd(iw + IOFF_ECNT + d, 1);
    if (p < ECAP) iw[IOFF_ELIST + d*ECAP + p] = e;
    return;
  }
  idx -= EE;
  if (idx < 16384){ int u=(int)idx>>6, j=(int)idx&63;
    ws[OFF_W1A+idx] = (u<254 && j<63)? e1w[u*127+j]      : 0.f;
    ws[OFF_W1B+idx] = (u<254 && j<63)? e1w[u*127+63+j]   : 0.f;
    if (j==0) ws[OFF_WR+u] = (u<254)? e1w[u*127+126] : 0.f;
    return; }
  idx -= 16384;
  if (idx < 16384){ int u=(int)idx>>8, j=(int)idx&255; ws[OFF_W2P+idx] = (u<63 && j<254)? e2w[u*254+j] : 0.f; return; }
  idx -= 16384;
  if (idx < 16384){ int u=(int)idx>>6, j=(int)idx&63; ws[OFF_C1P+idx] = (u<252 && j<63)? c1w[u*63+j] : 0.f; return; }
  idx -= 16384;
  if (idx < 726*68){ int to=(int)idx/68, i=(int)idx%68; int t=to/66, o=to%66;
    float v = 0.f;
    if (i < 66) v = (t<10)? nnw[(i*66+o)*10+t] : nnb[i*66+o];
    ws[OFF_QAUG+idx] = v; return; }
  idx -= 726*68;
  if (idx < 3*1024*192){ int it=(int)(idx/196608); int r=(int)(idx%196608); int b=r/192; int z=r%192; int o=z/3, k=z%3;
    ws[OFF_C1R+idx] = cv1w[((it*64+o)*1024+b)*3+k]; return; }
  idx -= 3*1024*192;
  if (idx < 198*132){ int u=(int)idx/132, j=(int)idx%132; ws[OFF_GIH+idx] = (j<130)? gwih[u*130+j] : 0.f; return; }
  idx -= 198*132;
  if (idx < 198*68){ int u=(int)idx/68, j=(int)idx%68; ws[OFF_GHH+idx] = (j<66)? gwhh[u*66+j] : 0.f; return; }
  idx -= 198*68;
  if (idx < 126*128){ int u=(int)idx>>7, j=(int)idx&127; ws[OFF_N1P+idx] = (j<126)? n1w[u*126+j] : 0.f; return; }
  idx -= 126*128;
  if (idx < 63*128){ int u=(int)idx>>7, j=(int)idx&127; ws[OFF_N2P+idx] = (j<126)? n2w[u*126+j] : 0.f; return; }
}

// ---- A/B build: A[n][u] = e1b[u] + feats[n]·W1a[u], B[n][u] = feats[n]·W1b[u] ----
__global__ __launch_bounds__(256) void k_ab(const float* __restrict__ mnc,
                                            const float* __restrict__ e1b,
                                            float* __restrict__ ws){
  __shared__ float xf[32][68];
  int tid = threadIdx.x;
  int n0 = blockIdx.x*32;
  for (int idx=tid; idx<32*64; idx+=256){ int n=idx>>6, j=idx&63;
    xf[n][j] = (j<63)? mnc[(n0+n)*ID + 3 + j] : 0.f; }
  __syncthreads();
  int eg = tid&7, ug = tid>>3;
  for (int pass=0; pass<8; pass++){
    int u = pass*32 + ug;
    const float4* wa = (const float4*)(ws + OFF_W1A + u*64);
    const float4* wb = (const float4*)(ws + OFF_W1B + u*64);
    float4 a0=Z4,a1=Z4,a2=Z4,a3=Z4,b0=Z4,b1=Z4,b2=Z4,b3=Z4;
    for (int jj=0;jj<16;jj++){
      float4 w1 = wa[jj], w2 = wb[jj];
      float4 x0 = *(const float4*)&xf[eg   ][jj*4];
      float4 x1 = *(const float4*)&xf[eg+ 8][jj*4];
      float4 x2 = *(const float4*)&xf[eg+16][jj*4];
      float4 x3 = *(const float4*)&xf[eg+24][jj*4];
      FMA4(a0,x0,w1) FMA4(a1,x1,w1) FMA4(a2,x2,w1) FMA4(a3,x3,w1)
      FMA4(b0,x0,w2) FMA4(b1,x1,w2) FMA4(b2,x2,w2) FMA4(b3,x3,w2)
    }
    if (u < 254){
      float bv = e1b[u];
      float va[4]={hsum4(a0),hsum4(a1),hsum4(a2),hsum4(a3)};
      float vb[4]={hsum4(b0),hsum4(b1),hsum4(b2),hsum4(b3)};
      #pragma unroll
      for (int i=0;i<4;i++){
        int n = n0 + eg + 8*i;
        ws[OFF_A + n*256 + u] = bv + va[i];
        ws[OFF_B + n*256 + u] = vb[i];
      }
    }
  }
}

// ---- per-edge chain (spill-free pattern) ----
#define EB 32
__global__ __launch_bounds__(256) void k_edge(
    const float* __restrict__ mnc, const int* __restrict__ eidx,
    const float* __restrict__ e2b, const float* __restrict__ c1b,
    const float* __restrict__ c2w, const float* __restrict__ c2b,
    float* __restrict__ ws)
{
  __shared__ float eh [EB][260];
  __shared__ float mij[EB][68];
  __shared__ float srel[EB][4];
  __shared__ int ssrc[EB], sdst[EB];
  int tid = threadIdx.x;
  int e0b = blockIdx.x*EB;
  if (tid < EB){
    int e = e0b + tid;
    int s = eidx[e], d = eidx[EE + e];
    ssrc[tid]=s; sdst[tid]=d;
    float rd = 0.f;
    #pragma unroll
    for (int k=0;k<3;k++){ float r = mnc[s*ID+k]-mnc[d*ID+k]; srel[tid][k]=r; rd += r*r; }
    srel[tid][3] = rd;
  }
  for (int idx=tid; idx<EB*5; idx+=256){ mij[idx/5][63+idx%5] = 0.f; }
  __syncthreads();
  for (int idx=tid; idx<EB*256; idx+=256){
    int e = idx>>8, u = idx&255;
    float v = 0.f;
    if (u < 254) v = silu_(ws[OFF_A + sdst[e]*256 + u] + ws[OFF_B + ssrc[e]*256 + u]
                           + ws[OFF_WR + u]*srel[e][3]);
    eh[e][u] = v;
  }
  for (int idx=tid; idx<EB*4; idx+=256){ eh[idx>>2][256+(idx&3)] = 0.f; }
  __syncthreads();
  int eg = tid&7, ug = tid>>3;
  {
    int u0 = 2*ug, u1 = 2*ug+1;
    const float4* w0 = (const float4*)(ws+OFF_W2P + u0*256);
    const float4* w1 = (const float4*)(ws+OFF_W2P + u1*256);
    float4 a0=Z4,a1=Z4,a2=Z4,a3=Z4,b0=Z4,b1=Z4,b2=Z4,b3=Z4;
    for (int jj=0;jj<64;jj++){
      float4 wv0=w0[jj], wv1=w1[jj];
      float4 x0 = *(const float4*)&eh[eg   ][jj*4];
      float4 x1 = *(const float4*)&eh[eg+ 8][jj*4];
      float4 x2 = *(const float4*)&eh[eg+16][jj*4];
      float4 x3 = *(const float4*)&eh[eg+24][jj*4];
      FMA4(a0,x0,wv0) FMA4(a1,x1,wv0) FMA4(a2,x2,wv0) FMA4(a3,x3,wv0)
      FMA4(b0,x0,wv1) FMA4(b1,x1,wv1) FMA4(b2,x2,wv1) FMA4(b3,x3,wv1)
    }
    float va[4]={hsum4(a0),hsum4(a1),hsum4(a2),hsum4(a3)};
    float vb[4]={hsum4(b0),hsum4(b1),hsum4(b2),hsum4(b3)};
    float bv0 = e2b[u0];
    #pragma unroll
    for (int i=0;i<4;i++){
      int e = eg + 8*i;
      float v = silu_(bv0 + va[i]);
      mij[e][u0] = v; ws[OFF_EDGE + (e0b+e)*68 + u0] = v;
      if (u1 < 63){
        float v1 = silu_(e2b[u1] + vb[i]);
        mij[e][u1] = v1; ws[OFF_EDGE + (e0b+e)*68 + u1] = v1;
      }
    }
  }
  __syncthreads();
  for (int uc=0; uc<4; uc++){
    int u0 = uc*64 + 2*ug, u1 = u0+1;
    const float4* w0 = (const float4*)(ws+OFF_C1P + u0*64);
    const float4* w1 = (const float4*)(ws+OFF_C1P + u1*64);
    float4 a0=Z4,a1=Z4,a2=Z4,a3=Z4,b0=Z4,b1=Z4,b2=Z4,b3=Z4;
    for (int jj=0;jj<16;jj++){
      float4 wv0=w0[jj], wv1=w1[jj];
      float4 x0 = *(const float4*)&mij[eg   ][jj*4];
      float4 x1 = *(const float4*)&mij[eg+ 8][jj*4];
      float4 x2 = *(const float4*)&mij[eg+16][jj*4];
      float4 x3 = *(const float4*)&mij[eg+24][jj*4];
      FMA4(a0,x0,wv0) FMA4(a1,x1,wv0) FMA4(a2,x2,wv0) FMA4(a3,x3,wv0)
      FMA4(b0,x0,wv1) FMA4(b1,x1,wv1) FMA4(b2,x2,wv1) FMA4(b3,x3,wv1)
    }
    float va[4]={hsum4(a0),hsum4(a1),hsum4(a2),hsum4(a3)};
    float vb[4]={hsum4(b0),hsum4(b1),hsum4(b2),hsum4(b3)};
    #pragma unroll
    for (int i=0;i<4;i++){
      int e = eg + 8*i;
      if (u0 < 252) eh[e][u0] = silu_(c1b[u0] + va[i]);
      if (u1 < 252) eh[e][u1] = silu_(c1b[u1] + vb[i]);
    }
  }
  __syncthreads();
  {
    int e = tid>>3, q = tid&7;
    const float4* xr = (const float4*)&eh[e][0];
    const float4* wr4 = (const float4*)c2w;
    float4 a = Z4;
    for (int jj=q; jj<63; jj+=8){ float4 xv=xr[jj], wv=wr4[jj]; FMA4(a,xv,wv) }
    float s = hsum4(a);
    s += __shfl_down(s,4,64); s += __shfl_down(s,2,64); s += __shfl_down(s,1,64);
    if (q == 0){
      float cw = s + c2b[0];
      #pragma unroll
      for (int k=0;k<3;k++) ws[OFF_EDGE + (e0b+e)*68 + 64 + k] = cw*srel[e][k];
    }
  }
}

// ---- node MLP (float4, padded weights) + gathers -> smi_pre ----
#define NNB 8
__global__ __launch_bounds__(256) void k_node(
    const float* __restrict__ mnc,
    const float* __restrict__ n1b, const float* __restrict__ n2b,
    float* __restrict__ ws, const int* __restrict__ iw)
{
  __shared__ float xin[NNB][132];  // [0..125] data, 126..127 zero (K pad)
  __shared__ float t1 [NNB][132];
  int tid = threadIdx.x;
  int n0 = blockIdx.x*NNB;
  for (int idx=tid; idx<NNB*128; idx+=256){
    int e = idx>>7, j = idx&127;
    int node = n0 + e;
    float v = 0.f;
    if (j < 63) v = mnc[node*ID + 3 + j];
    else if (j < 126){
      int u = j - 63;
      int cnt = iw[IOFF_ECNT+node]; if (cnt > ECAP) cnt = ECAP;
      for (int q=0;q<cnt;q++) v += ws[OFF_EDGE + iw[IOFF_ELIST+node*ECAP+q]*68 + u];
    }
    xin[e][j] = v;
    t1[e][j] = 0.f;
  }
  __syncthreads();
  // n1: 126 outputs, K=128 padded
  {
    int ng = tid&3, ug = tid>>2;           // nodes ng, ng+4; u = 2ug, 2ug+1
    int u0 = 2*ug, u1 = u0+1;
    const float4* w0 = (const float4*)(ws+OFF_N1P + u0*128);
    const float4* w1 = (const float4*)(ws+OFF_N1P + u1*128);
    float4 a0=Z4,a1=Z4,b0=Z4,b1=Z4;
    for (int jj=0;jj<32;jj++){
      float4 wv0=w0[jj], wv1=w1[jj];
      float4 x0 = *(const float4*)&xin[ng  ][jj*4];
      float4 x1 = *(const float4*)&xin[ng+4][jj*4];
      FMA4(a0,x0,wv0) FMA4(a1,x1,wv0)
      FMA4(b0,x0,wv1) FMA4(b1,x1,wv1)
    }
    if (u0 < 126){ float bv=n1b[u0]; t1[ng][u0]=silu_(bv+hsum4(a0)); t1[ng+4][u0]=silu_(bv+hsum4(a1)); }
    if (u1 < 126){ float bv=n1b[u1]; t1[ng][u1]=silu_(bv+hsum4(b0)); t1[ng+4][u1]=silu_(bv+hsum4(b1)); }
  }
  __syncthreads();
  // n2: 63 outputs, K=128 padded; residual add + nan0
  {
    int ng = tid&7, ug = tid>>3;           // node ng; u = 2ug, 2ug+1
    int u0 = 2*ug, u1 = u0+1;
    const float4* w0 = (const float4*)(ws+OFF_N2P + u0*128);
    const float4* w1 = (const float4*)(ws+OFF_N2P + u1*128);
    float4 a0=Z4,b0=Z4;
    if (u0 < 63){
      for (int jj=0;jj<32;jj++){
        float4 x0 = *(const float4*)&t1[ng][jj*4];
        FMA4(a0,x0,w0[jj]) FMA4(b0,x0,w1[jj])
      }
      int node = n0 + ng;
      ws[OFF_SMIP + node*ID + 3 + u0] = nan0(xin[ng][u0] + n2b[u0] + hsum4(a0));
      if (u1 < 63)
        ws[OFF_SMIP + node*ID + 3 + u1] = nan0(xin[ng][u1] + n2b[u1] + hsum4(b0));
    }
  }
  if (tid < NNB*3){
    int e = tid/3, k = tid%3;
    int node = n0 + e;
    int cnt = iw[IOFF_ECNT+node]; if (cnt > ECAP) cnt = ECAP;
    float s = mnc[node*ID + k];
    for (int q=0;q<cnt;q++) s += ws[OFF_EDGE + iw[IOFF_ELIST+node*ECAP+q]*68 + 64 + k];
    ws[OFF_SMIP + node*ID + k] = nan0(s);
  }
}

// ---- batchnorm ----
__global__ __launch_bounds__(256) void k_bn_stats(float* __restrict__ ws){
  __shared__ float scr[8];
  int j = blockIdx.x, tid = threadIdx.x;
  float s=0.f, ss=0.f;
  for (int i=tid; i<NN; i+=256){ float x = ws[OFF_SMIP + i*ID + j]; s+=x; ss+=x*x; }
  for (int o=32;o>0;o>>=1){ s += __shfl_down(s,o,64); ss += __shfl_down(ss,o,64); }
  int w = tid>>6;
  if ((tid&63)==0){ scr[w]=s; scr[4+w]=ss; }
  __syncthreads();
  if (tid==0){
    float S=0,SS=0;
    for (int q=0;q<4;q++){S+=scr[q];SS+=scr[4+q];}
    float mean = S/NN;
    float var  = SS/NN - mean*mean;
    ws[OFF_STATS + j]      = mean;
    ws[OFF_STATS + 66 + j] = 1.0f/sqrtf(var + 1e-5f);
  }
}
__global__ void k_bn_apply(const float* __restrict__ bng, const float* __restrict__ bnb,
                           float* __restrict__ ws){
  int idx = blockIdx.x*256 + threadIdx.x;
  if (idx < NN*ID){
    int j = idx % ID;
    ws[OFF_OUT + idx] = bng[j]*(ws[OFF_SMIP+idx]-ws[OFF_STATS+j])*ws[OFF_STATS+66+j] + bnb[j];
  }
}

// ---- T[n][t*66+o] = sum_i h[n,i]*Qaug[i,t,o] ----
__global__ __launch_bounds__(256) void k_tbuild(int rdo, float* __restrict__ ws){
  __shared__ float xs[16][68];
  int tid = threadIdx.x;
  int n0 = blockIdx.x*16;
  for (int idx=tid; idx<16*68; idx+=256){ int n=idx/68, j=idx%68;
    xs[n][j] = (j<66)? ws[rdo + (n0+n)*ID + j] : 0.f; }
  __syncthreads();
  for (int pass=0; pass<3; pass++){
    int to = pass*256 + tid;
    if (to < 726){
      float acc[16];
      #pragma unroll
      for (int n=0;n<16;n++) acc[n] = 0.f;
      const float4* qp = (const float4*)(ws + OFF_QAUG + to*68);
      for (int jj=0;jj<17;jj++){
        float4 w = qp[jj];
        #pragma unroll
        for (int n=0;n<16;n++){
          float4 x = *(const float4*)&xs[n][jj*4];
          acc[n] += x.x*w.x + x.y*w.y + x.z*w.z + x.w*w.w;
        }
      }
      #pragma unroll
      for (int n=0;n<16;n++) ws[OFF_T + (n0+n)*726 + to] = acc[n];
    }
  }
}

// ---- m = relu(gathered_msg/deg + h@root + nn_bias) ----
#define MNB 8
__global__ __launch_bounds__(256) void k_mnode(
    const float* __restrict__ root, const float* __restrict__ nnbias,
    const int* __restrict__ eidx, const float* __restrict__ ea,
    int rdo, float* __restrict__ ws, const int* __restrict__ iw)
{
  __shared__ float rs[66][68];
  __shared__ float xo[MNB][68];
  int tid = threadIdx.x;
  int n0 = blockIdx.x*MNB;
  for (int idx=tid; idx<66*66; idx+=256) rs[idx/66][idx%66] = root[idx];
  for (int idx=tid; idx<MNB*66; idx+=256) xo[idx/66][idx%66] = ws[rdo + n0*ID + idx];
  __syncthreads();
  for (int idx=tid; idx<MNB*66; idx+=256){
    int n = idx/66, o = idx%66;
    int node = n0 + n;
    int rawcnt = iw[IOFF_ECNT+node];
    int cnt = rawcnt > ECAP ? ECAP : rawcnt;
    float magg = 0.f;
    for (int q=0;q<cnt;q++){
      int e = iw[IOFF_ELIST + node*ECAP + q];
      int s = eidx[e];
      const float* Tp = ws + OFF_T + s*726 + o;
      const float* eap = ea + e*10;
      float av = Tp[660];
      #pragma unroll
      for (int t=0;t<10;t++) av += eap[t]*Tp[t*66];
      magg += av;
    }
    float deg = fmaxf((float)rawcnt, 1.0f);
    float s2 = nnbias[o] + magg/deg;
    for (int j=0;j<66;j++) s2 += xo[n][j]*rs[j][o];
    s2 = fmaxf(s2, 0.0f);
    ws[OFF_M  + node*ID  + o] = s2;
    ws[OFF_CM + node*132 + o] = s2;
  }
}

// ---- fused sparse conv ----
__global__ __launch_bounds__(256) void k_spconv(
    const float* __restrict__ cv1b, const float* __restrict__ cv2w,
    const float* __restrict__ cv2b,
    int it, float* __restrict__ ws, const int* __restrict__ iw)
{
  __shared__ float mid[DD][68];
  __shared__ float mps[32][68];
  __shared__ float w1s[32][192];
  __shared__ float vv[32];
  __shared__ float w2s[204];
  __shared__ float part[4][64];
  int tid = threadIdx.x;
  int a = blockIdx.x;
  for (int idx=tid; idx<DD*68; idx+=256) (&mid[0][0])[idx] = 0.f;
  if (tid < 198) w2s[tid] = cv2w[it*198 + tid];
  int nnz = iw[IOFF_CNT + a]; if (nnz > CAP) nnz = CAP;
  __syncthreads();
  for (int q0=0; q0<nnz; q0+=32){
    int qn = nnz - q0; if (qn > 32) qn = 32;
    for (int idx=tid; idx<qn*68; idx+=256){
      int q=idx/68, cc=idx%68;
      int b = iw[IOFF_CIDX + a*CAP + q0 + q];
      mps[q][cc] = (cc>=1 && cc<=66)? ws[OFF_M + b*ID + cc-1] : 0.f;
    }
    for (int idx=tid; idx<qn*192; idx+=256){
      int q=idx/192, r=idx%192;
      int b = iw[IOFF_CIDX + a*CAP + q0 + q];
      w1s[q][r] = ws[OFF_C1R + (it*1024+b)*192 + r];
    }
    if (tid < qn) vv[tid] = ws[OFF_CVAL + a*CAP + q0 + tid];
    __syncthreads();
    for (int idx=tid; idx<DD*ID; idx+=256){
      int o = idx/ID, cc = idx%ID;
      float acc = mid[o][cc];
      for (int q=0;q<qn;q++){
        acc += vv[q]*(w1s[q][o*3]*mps[q][cc] + w1s[q][o*3+1]*mps[q][cc+1] + w1s[q][o*3+2]*mps[q][cc+2]);
      }
      mid[o][cc] = acc;
    }
    __syncthreads();
  }
  for (int idx=tid; idx<DD*ID; idx+=256){ int o=idx/ID, cc=idx%ID; mid[o][cc] += cv1b[it*DD+o]; }
  __syncthreads();
  {
    int x = tid & 63, qq = tid >> 6;
    int c0 = qq*17, cN = c0+17; if (cN > ID) cN = ID;
    float s = 0.f;
    for (int cc=c0; cc<cN; cc++){
      #pragma unroll
      for (int k=0;k<3;k++){
        int oo = x + k - 1;
        if (oo >= 0 && oo < DD) s += mid[oo][cc]*w2s[cc*3+k];
      }
    }
    part[qq][x] = s;
  }
  __syncthreads();
  if (tid < DD)
    ws[OFF_CM + a*132 + ID + tid] = part[0][tid]+part[1][tid]+part[2][tid]+part[3][tid] + cv2b[it];
}

// ---- gate + segment softmax + GRU, split (mol x 8 u-chunks) = 256 blocks ----
__global__ __launch_bounds__(256) void k_gru2(
    const int* __restrict__ mb,
    const float* __restrict__ lfw, const float* __restrict__ lfb,
    const float* __restrict__ bih, const float* __restrict__ bhh,
    int rdo, int wro, float* __restrict__ ws)
{
  __shared__ int memb[GM]; __shared__ int lcnt;
  __shared__ float cms [GM][132];
  __shared__ float hrow[GM][68];
  __shared__ float av[GM];
  __shared__ float rr[GUC][GM+2], zz[GUC][GM+2], p1[GUC][GM+2], p2[GUC][GM+2];
  int tid = threadIdx.x;
  int m = blockIdx.x >> 3, uc = blockIdx.x & 7;
  int u0 = uc*GUC;
  if (tid==0) lcnt = 0;
  __syncthreads();
  for (int i=tid; i<NN; i+=256)
    if (mb[i]==m){ int p = atomicAdd(&lcnt,1); if (p<GM) memb[p]=i; }
  __syncthreads();
  int M = lcnt; if (M > GM) M = GM;
  for (int idx=tid; idx<M*132; idx+=256){ int i=idx/132, j=idx%132; cms[i][j] = (j<130)? ws[OFF_CM+memb[i]*132+j] : 0.f; }
  for (int idx=tid; idx<M*68; idx+=256){ int i=idx/68, j=idx%68; hrow[i][j] = (j<66)? ws[rdo+memb[i]*ID+j] : 0.f; }
  __syncthreads();
  // av (deterministic recompute per block)
  if (tid < 64){
    float x = -INFINITY;
    if (tid < M){
      const float4* cr = (const float4*)&cms[tid][0];
      const float4* lw = (const float4*)lfw;
      float4 a = Z4;
      for (int jj=0;jj<32;jj++){ FMA4(a,cr[jj],lw[jj]) }
      float s = hsum4(a) + cms[tid][128]*lfw[128] + cms[tid][129]*lfw[129] + lfb[0];
      x = (s > 0.f) ? s : 0.01f*s;
    }
    float mx = x;
    for (int o=32;o>0;o>>=1) mx = fmaxf(mx, __shfl_xor(mx,o,64));
    float ex = (tid<M) ? expf(x-mx) : 0.f;
    float sm = ex;
    for (int o=32;o>0;o>>=1) sm += __shfl_xor(sm,o,64);
    if (tid<M) av[tid] = ex/(sm + 1e-16f);
  }
  __syncthreads();
  // gate GEMM rows {g*66 + u0+du : g<3, du<GUC}
  {
    int ug = tid>>3, ig = tid&7;
    if (ug < 3*GUC){
      int g = ug/GUC, du = ug%GUC;
      int u = u0 + du;
      if (u < 66){
        int urow = g*66 + u;
        const float4* w1 = (const float4*)(ws+OFF_GIH + urow*132);
        const float4* w2 = (const float4*)(ws+OFF_GHH + urow*68);
        float bv1 = bih[urow], bv2 = bhh[urow];
        for (int i0 = ig*4; i0 < M; i0 += 32){
          const float4* x0 = (const float4*)&cms[i0+0][0];
          const float4* x1 = (const float4*)&cms[i0+1][0];
          const float4* x2 = (const float4*)&cms[i0+2][0];
          const float4* x3 = (const float4*)&cms[i0+3][0];
          float4 a0=Z4,a1=Z4,a2=Z4,a3=Z4;
          for (int jj=0;jj<33;jj++){
            float4 w=w1[jj];
            FMA4(a0,x0[jj],w) FMA4(a1,x1[jj],w) FMA4(a2,x2[jj],w) FMA4(a3,x3[jj],w)
          }
          const float4* h0 = (const float4*)&hrow[i0+0][0];
          const float4* h1 = (const float4*)&hrow[i0+1][0];
          const float4* h2 = (const float4*)&hrow[i0+2][0];
          const float4* h3 = (const float4*)&hrow[i0+3][0];
          float4 b0=Z4,b1=Z4,b2=Z4,b3=Z4;
          for (int jj=0;jj<17;jj++){
            float4 w=w2[jj];
            FMA4(b0,h0[jj],w) FMA4(b1,h1[jj],w) FMA4(b2,h2[jj],w) FMA4(b3,h3[jj],w)
          }
          float d1[4] = {hsum4(a0),hsum4(a1),hsum4(a2),hsum4(a3)};
          float d2[4] = {hsum4(b0),hsum4(b1),hsum4(b2),hsum4(b3)};
          #pragma unroll
          for (int ii=0;ii<4;ii++){
            int i = i0+ii;
            if (i < M){
              float v1 = bv1 + av[i]*d1[ii];
              float v2 = bv2 + d2[ii];
              if (g == 0) rr[du][i] = sgm(v1+v2);
              else if (g == 1) zz[du][i] = sgm(v1+v2);
              else { p1[du][i] = v1; p2[du][i] = v2; }
            }
          }
        }
      }
    }
  }
  __syncthreads();
  for (int idx=tid; idx<GUC*M; idx+=256){
    int du = idx/M, i = idx%M;
    int u = u0 + du;
    if (u < 66){
      float r = rr[du][i], z = zz[du][i];
      float n_ = tanhf(p1[du][i] + r*p2[du][i]);
      ws[wro + memb[i]*ID + u] = (1.f - z)*n_ + z*hrow[i][u];
    }
  }
}

// ---- Set2Set readout ----
__global__ __launch_bounds__(256) void k_s2s(
    const int* __restrict__ mb,
    const float* __restrict__ wih, const float* __restrict__ whh,
    const float* __restrict__ bih, const float* __restrict__ bhh,
    int rdo, float* __restrict__ ws)
{
  __shared__ int memb[MAXM]; __shared__ int lcnt;
  __shared__ float orow[MAXM][68];
  __shared__ float hsv[66], csv[66], qsv[132], gv[264];
  __shared__ float av[MAXM];
  int tid = threadIdx.x, m = blockIdx.x;
  if (tid==0) lcnt = 0;
  __syncthreads();
  for (int i=tid; i<NN; i+=256)
    if (mb[i]==m){ int p = atomicAdd(&lcnt,1); if (p<MAXM) memb[p]=i; }
  __syncthreads();
  int M = lcnt; if (M > MAXM) M = MAXM;
  for (int idx=tid; idx<M*ID; idx+=256){ int i=idx/ID, j=idx%ID; orow[i][j]=ws[rdo+memb[i]*ID+j]; }
  if (tid < 66){ hsv[tid]=0.f; csv[tid]=0.f; }
  if (tid < 132) qsv[tid]=0.f;
  __syncthreads();
  for (int step=0; step<3; step++){
    for (int u=tid; u<264; u+=256){
      float s = bih[u] + bhh[u];
      const float* w1 = wih + u*132;
      for (int j=0;j<132;j++) s += qsv[j]*w1[j];
      const float* w2 = whh + u*ID;
      for (int j=0;j<ID;j++) s += hsv[j]*w2[j];
      gv[u] = s;
    }
    __syncthreads();
    if (tid < 66){
      float ig=gv[tid], fg=gv[66+tid], gg_=gv[132+tid], og=gv[198+tid];
      float c = sgm(fg)*csv[tid] + sgm(ig)*tanhf(gg_);
      csv[tid] = c;
      hsv[tid] = sgm(og)*tanhf(c);
    }
    __syncthreads();
    if (tid < 64){
      float e = -INFINITY;
      if (tid < M){ e = 0.f; for (int j=0;j<ID;j++) e += orow[tid][j]*hsv[j]; }
      float mx = e;
      for (int o=32;o>0;o>>=1) mx = fmaxf(mx, __shfl_xor(mx,o,64));
      float ex = (tid<M) ? expf(e-mx) : 0.f;
      float sm = ex;
      for (int o=32;o>0;o>>=1) sm += __shfl_xor(sm,o,64);
      if (tid<M) av[tid] = ex/(sm + 1e-16f);
    }
    __syncthreads();
    if (tid < 66){
      float r = 0.f;
      for (int i=0;i<M;i++) r += av[i]*orow[i][tid];
      qsv[tid]      = hsv[tid];
      qsv[66+tid]   = r;
    }
    __syncthreads();
  }
  if (tid < 132) ws[OFF_QSTAR + m*132 + tid] = qsv[tid];
}

// ---- fingers MLP ----
__global__ __launch_bounds__(256) void k_fd1(
    const float* __restrict__ fing, const float* __restrict__ d1w, const float* __restrict__ d1b,
    float* __restrict__ ws)
{
  __shared__ __align__(16) float fin[1024];
  int tid = threadIdx.x;
  int b = blockIdx.x >> 4, u0 = (blockIdx.x & 15)*32;
  for (int j=tid; j<1024; j+=256) fin[j] = fing[b*1024+j];
  __syncthreads();
  int u = u0 + (tid>>3), q = tid & 7;
  const float4* w4 = (const float4*)(d1w + u*1024);
  const float4* x4 = (const float4*)fin;
  float4 a = Z4;
  for (int jj=q; jj<256; jj+=8){ float4 wv=w4[jj], xv=x4[jj]; FMA4(a,xv,wv) }
  float s = hsum4(a);
  s += __shfl_xor(s,1,64); s += __shfl_xor(s,2,64); s += __shfl_xor(s,4,64);
  if (q==0) ws[OFF_F1 + b*512 + u] = fmaxf(s + d1b[u], 0.f);
}
__global__ __launch_bounds__(256) void k_fd2(
    const float* __restrict__ d2w, const float* __restrict__ d2b, float* __restrict__ ws)
{
  __shared__ __align__(16) float f1[512];
  int tid = threadIdx.x;
  int b = blockIdx.x >> 3, u0 = (blockIdx.x & 7)*32;
  for (int j=tid; j<512; j+=256) f1[j] = ws[OFF_F1 + b*512 + j];
  __syncthreads();
  int u = u0 + (tid>>3), q = tid & 7;
  const float4* w4 = (const float4*)(d2w + u*512);
  const float4* x4 = (const float4*)f1;
  float4 a = Z4;
  for (int jj=q; jj<128; jj+=8){ float4 wv=w4[jj], xv=x4[jj]; FMA4(a,xv,wv) }
  float s = hsum4(a);
  s += __shfl_xor(s,1,64); s += __shfl_xor(s,2,64); s += __shfl_xor(s,4,64);
  if (q==0) ws[OFF_F2 + b*256 + u] = fmaxf(s + d2b[u], 0.f);
}
__global__ __launch_bounds__(256) void k_fd3p(
    const float* __restrict__ d3w, const float* __restrict__ d3b,
    const float* __restrict__ pw,  const float* __restrict__ pb,
    const float* __restrict__ ws,  float* __restrict__ outp)
{
  __shared__ __align__(16) float f2[256];
  __shared__ float f3[64];
  int tid = threadIdx.x, b = blockIdx.x;
  for (int j=tid; j<256; j+=256) f2[j] = ws[OFF_F2 + b*256 + j];
  __syncthreads();
  {
    int u = tid>>2, q = tid&3;
    const float4* w4 = (const float4*)(d3w + u*256);
    const float4* x4 = (const float4*)f2;
    float4 a = Z4;
    for (int jj=q; jj<64; jj+=4){ float4 wv=w4[jj], xv=x4[jj]; FMA4(a,xv,wv) }
    float s = hsum4(a);
    s += __shfl_xor(s,1,64); s += __shfl_xor(s,2,64);
    if (q==0) f3[u] = s + d3b[u];
  }
  __syncthreads();
  if (tid < 64){
    float s = 0.f;
    for (int j=tid; j<132; j+=64) s += ws[OFF_QSTAR + b*132 + j]*pw[j];
    s += f3[tid]*pw[132 + tid];
    for (int o=32;o>0;o>>=1) s += __shfl_xor(s,o,64);
    if (tid==0) outp[b] = s + pb[0];
  }
}

extern "C" void kernel_launch(void* const* d_in, const int* in_sizes, int n_in,
                              void* d_out, int out_size, void* d_ws, size_t ws_size,
                              hipStream_t stream)
{
  const float* mnc = (const float*)d_in[0];
  const float* ea  = (const float*)d_in[1];
  const float* fing= (const float*)d_in[2];
  const int*   eidx= (const int*)d_in[3];
  const int*   mb  = (const int*)d_in[4];
  const float* adj = (const float*)d_in[5];
  const float* e1w=(const float*)d_in[6],  *e1b=(const float*)d_in[7];
  const float* e2w=(const float*)d_in[8],  *e2b=(const float*)d_in[9];
  const float* c1w=(const float*)d_in[10], *c1b=(const float*)d_in[11];
  const float* c2w=(const float*)d_in[12], *c2b=(const float*)d_in[13];
  const float* n1w=(const float*)d_in[14], *n1b=(const float*)d_in[15];
  const float* n2w=(const float*)d_in[16], *n2b=(const float*)d_in[17];
  const float* bng=(const float*)d_in[18], *bnb=(const float*)d_in[19];
  const float* nnw=(const float*)d_in[20], *nnb=(const float*)d_in[21];
  const float* root=(const float*)d_in[22],*nnbias=(const float*)d_in[23];
  const float* cv1w=(const float*)d_in[24],*cv1b=(const float*)d_in[25];
  const float* cv2w=(const float*)d_in[26],*cv2b=(const float*)d_in[27];
  const float* lfw=(const float*)d_in[28], *lfb=(const float*)d_in[29];
  const float* gwih=(const float*)d_in[30],*gwhh=(const float*)d_in[31];
  const float* gbih=(const float*)d_in[32],*gbhh=(const float*)d_in[33];
  const float* lwih=(const float*)d_in[34],*lwhh=(const float*)d_in[35];
  const float* lbih=(const float*)d_in[36],*lbhh=(const float*)d_in[37];
  const float* d1w=(const float*)d_in[38], *d1b=(const float*)d_in[39];
  const float* d2w=(const float*)d_in[40], *d2b=(const float*)d_in[41];
  const float* d3w=(const float*)d_in[42], *d3b=(const float*)d_in[43];
  const float* pw =(const float*)d_in[44], *pb =(const float*)d_in[45];
  float* ws = (float*)d_ws;
  int*   iw = (int*)(ws + OFF_FEND);
  float* outp = (float*)d_out;

  const long long setup_total = (long long)NN*NN + EE + 16384 + 16384 + 16384
                              + 726*68 + 3*1024*192 + 198*132 + 198*68
                              + 126*128 + 63*128;
  int setup_blocks = (int)((setup_total + 255)/256);

  k_zero0    <<<4, 256, 0, stream>>>(iw);
  k_setup    <<<setup_blocks, 256, 0, stream>>>(adj, eidx, e1w, e2w, c1w, nnw, nnb, cv1w, gwih, gwhh, n1w, n2w, ws, iw);
  k_ab       <<<NN/32, 256, 0, stream>>>(mnc, e1b, ws);
  k_edge     <<<EE/EB, 256, 0, stream>>>(mnc, eidx, e2b, c1b, c2w, c2b, ws);
  k_node     <<<NN/NNB, 256, 0, stream>>>(mnc, n1b, n2b, ws, iw);
  k_bn_stats <<<ID, 256, 0, stream>>>(ws);
  k_bn_apply <<<(NN*ID+255)/256, 256, 0, stream>>>(bng, bnb, ws);
  int rd = OFF_OUT, wr = OFF_OUT2;
  for (int it=0; it<3; ++it){
    k_tbuild <<<NN/16, 256, 0, stream>>>(rd, ws);
    k_mnode  <<<NN/MNB, 256, 0, stream>>>(root, nnbias, eidx, ea, rd, ws, iw);
    k_spconv <<<NN, 256, 0, stream>>>(cv1b, cv2w, cv2b, it, ws, iw);
    k_gru2   <<<BB*8, 256, 0, stream>>>(mb, lfw, lfb, gbih, gbhh, rd, wr, ws);
    int t = rd; rd = wr; wr = t;
  }
  k_s2s      <<<BB, 256, 0, stream>>>(mb, lwih, lwhh, lbih, lbhh, rd, ws);
  k_fd1      <<<BB*16, 256, 0, stream>>>(fing, d1w, d1b, ws);
  k_fd2      <<<BB*8, 256, 0, stream>>>(d2w, d2b, ws);
  k_fd3p     <<<BB, 256, 0, stream>>>(d3w, d3b, pw, pb, ws, outp);
}

// Round 8
// 769.564 us; speedup vs baseline: 1.5809x; 1.0315x over previous
//
#include <hip/hip_runtime.h>
#include <math.h>

// Problem constants (fixed by the reference)
#define NN 1024   // nodes
#define BB 32     // mols
#define EE 8192   // edges
#define DD 64     // DIM
#define ID 66     // IN_DIM
#define FT 63     // feats dim
#define CAP 128   // max nnz per adj column
#define ECAP 64   // max in-edges per node
#define MAXM 64   // max nodes per mol (s2s)
#define GNB 4     // nodes per block in gru gate gemm

// ---- workspace layout (float offsets) ----
enum : int {
  OFF_SMIP  = 0,                        // N*66 pre-BN smi
  OFF_OUT   = OFF_SMIP + NN*ID,         // N*66 h
  OFF_STATS = OFF_OUT + NN*ID,          // 144 mean/rstd
  OFF_M     = OFF_STATS + 144,          // N*66 m buffer
  OFF_CM    = OFF_M + NN*ID,            // N*132 cm
  OFF_QSTAR = OFF_CM + NN*132,          // 32*132
  OFF_CVAL  = OFF_QSTAR + BB*132,       // N*CAP csc values
  OFF_A     = OFF_CVAL + NN*CAP,        // 1024*256 A = feats@W1a^T + e1b
  OFF_B     = OFF_A + 1024*256,         // 1024*256 B = feats@W1b^T
  OFF_EDGE  = OFF_B + 1024*256,         // 8192*68: [0..62]=mij, [64..66]=cw*rel
  OFF_T     = OFF_EDGE + EE*68,         // 1024*726 T[n][t*66+o]
  OFF_QAUG  = OFF_T + NN*726,           // 726*68 Qaug[(t*66+o)][i]
  OFF_W1A   = OFF_QAUG + 726*68,        // 256*64
  OFF_W1B   = OFF_W1A + 16384,          // 256*64
  OFF_WR    = OFF_W1B + 16384,          // 256
  OFF_W2P   = OFF_WR + 256,             // 64*256 padded e2w
  OFF_C1P   = OFF_W2P + 16384,          // 256*64 padded c1w
  OFF_C1R   = OFF_C1P + 16384,          // 3*1024*192 conv1_w reorg
  OFF_GIH   = OFF_C1R + 3*1024*192,     // 198*132
  OFF_GHH   = OFF_GIH + 198*132,        // 198*68
  OFF_F1    = OFF_GHH + 198*68,         // 32*512
  OFF_F2    = OFF_F1 + BB*512,          // 32*256
  OFF_AV    = OFF_F2 + BB*256,          // N  softmax gate per node
  OFF_N1P   = OFF_AV + NN,              // 126*128 padded n1w
  OFF_N2P   = OFF_N1P + 126*128,        // 63*128  padded n2w
  OFF_FEND  = OFF_N2P + 63*128
};
enum : int {  // int region at ws + OFF_FEND
  IOFF_CNT   = 0,                 // N   csc col counts
  IOFF_CIDX  = NN,                // N*CAP
  IOFF_ECNT  = NN + NN*CAP,       // N   in-degree
  IOFF_ELIST = NN + NN*CAP + NN,  // N*ECAP edge ids sorted by dst
  IOFF_END   = NN + NN*CAP + NN + NN*ECAP
};

__device__ __forceinline__ float sgm(float x){ return 1.0f/(1.0f+expf(-x)); }
__device__ __forceinline__ float silu_(float x){ return x/(1.0f+expf(-x)); }
__device__ __forceinline__ float nan0(float v){ return (v!=v) ? 0.0f : v; }
__device__ __forceinline__ float hsum4(float4 v){ return v.x+v.y+v.z+v.w; }
#define FMA4(A,X,W) {A.x += (X).x*(W).x; A.y += (X).y*(W).y; A.z += (X).z*(W).z; A.w += (X).w*(W).w;}
#define Z4 {0.f,0.f,0.f,0.f}

// ---- zero the atomic counters ----
__global__ void k_zero0(int* __restrict__ iw){
  int i = blockIdx.x*256 + threadIdx.x;
  if (i < NN){ iw[IOFF_CNT + i] = 0; iw[IOFF_ECNT + i] = 0; }
}

// ---- one-shot setup: csc(adj), edge sort by dst, weight reorg/pad ----
__global__ void k_setup(const float* __restrict__ adj, const int* __restrict__ eidx,
                        const float* __restrict__ e1w, const float* __restrict__ e2w,
                        const float* __restrict__ c1w,
                        const float* __restrict__ nnw, const float* __restrict__ nnb,
                        const float* __restrict__ cv1w,
                        const float* __restrict__ gwih, const float* __restrict__ gwhh,
                        const float* __restrict__ n1w, const float* __restrict__ n2w,
                        float* __restrict__ ws, int* __restrict__ iw){
  long long idx = (long long)blockIdx.x*256 + threadIdx.x;
  if (idx < (long long)NN*NN){
    float v = adj[idx];
    if (v != 0.0f){
      int a = (int)(idx & 1023), b = (int)(idx >> 10);
      int p = atomicAdd(iw + IOFF_CNT + a, 1);
      if (p < CAP){ iw[IOFF_CIDX + a*CAP + p] = b; ws[OFF_CVAL + a*CAP + p] = v; }
    }
    return;
  }
  idx -= (long long)NN*NN;
  if (idx < EE){
    int e = (int)idx, d = eidx[EE + e];
    int p = atomicAdd(iw + IOFF_ECNT + d, 1);
    if (p < ECAP) iw[IOFF_ELIST + d*ECAP + p] = e;
    return;
  }
  idx -= EE;
  if (idx < 16384){ int u=(int)idx>>6, j=(int)idx&63;
    ws[OFF_W1A+idx] = (u<254 && j<63)? e1w[u*127+j]      : 0.f;
    ws[OFF_W1B+idx] = (u<254 && j<63)? e1w[u*127+63+j]   : 0.f;
    if (j==0) ws[OFF_WR+u] = (u<254)? e1w[u*127+126] : 0.f;
    return; }
  idx -= 16384;
  if (idx < 16384){ int u=(int)idx>>8, j=(int)idx&255; ws[OFF_W2P+idx] = (u<63 && j<254)? e2w[u*254+j] : 0.f; return; }
  idx -= 16384;
  if (idx < 16384){ int u=(int)idx>>6, j=(int)idx&63; ws[OFF_C1P+idx] = (u<252 && j<63)? c1w[u*63+j] : 0.f; return; }
  idx -= 16384;
  if (idx < 726*68){ int to=(int)idx/68, i=(int)idx%68; int t=to/66, o=to%66;
    float v = 0.f;
    if (i < 66) v = (t<10)? nnw[(i*66+o)*10+t] : nnb[i*66+o];
    ws[OFF_QAUG+idx] = v; return; }
  idx -= 726*68;
  if (idx < 3*1024*192){ int it=(int)(idx/196608); int r=(int)(idx%196608); int b=r/192; int z=r%192; int o=z/3, k=z%3;
    ws[OFF_C1R+idx] = cv1w[((it*64+o)*1024+b)*3+k]; return; }
  idx -= 3*1024*192;
  if (idx < 198*132){ int u=(int)idx/132, j=(int)idx%132; ws[OFF_GIH+idx] = (j<130)? gwih[u*130+j] : 0.f; return; }
  idx -= 198*132;
  if (idx < 198*68){ int u=(int)idx/68, j=(int)idx%68; ws[OFF_GHH+idx] = (j<66)? gwhh[u*66+j] : 0.f; return; }
  idx -= 198*68;
  if (idx < 126*128){ int u=(int)idx>>7, j=(int)idx&127; ws[OFF_N1P+idx] = (j<126)? n1w[u*126+j] : 0.f; return; }
  idx -= 126*128;
  if (idx < 63*128){ int u=(int)idx>>7, j=(int)idx&127; ws[OFF_N2P+idx] = (j<126)? n2w[u*126+j] : 0.f; return; }
}

// ---- A/B build ----
__global__ __launch_bounds__(256) void k_ab(const float* __restrict__ mnc,
                                            const float* __restrict__ e1b,
                                            float* __restrict__ ws){
  __shared__ float xf[32][68];
  int tid = threadIdx.x;
  int n0 = blockIdx.x*32;
  for (int idx=tid; idx<32*64; idx+=256){ int n=idx>>6, j=idx&63;
    xf[n][j] = (j<63)? mnc[(n0+n)*ID + 3 + j] : 0.f; }
  __syncthreads();
  int eg = tid&7, ug = tid>>3;
  for (int pass=0; pass<8; pass++){
    int u = pass*32 + ug;
    const float4* wa = (const float4*)(ws + OFF_W1A + u*64);
    const float4* wb = (const float4*)(ws + OFF_W1B + u*64);
    float4 a0=Z4,a1=Z4,a2=Z4,a3=Z4,b0=Z4,b1=Z4,b2=Z4,b3=Z4;
    for (int jj=0;jj<16;jj++){
      float4 w1 = wa[jj], w2 = wb[jj];
      float4 x0 = *(const float4*)&xf[eg   ][jj*4];
      float4 x1 = *(const float4*)&xf[eg+ 8][jj*4];
      float4 x2 = *(const float4*)&xf[eg+16][jj*4];
      float4 x3 = *(const float4*)&xf[eg+24][jj*4];
      FMA4(a0,x0,w1) FMA4(a1,x1,w1) FMA4(a2,x2,w1) FMA4(a3,x3,w1)
      FMA4(b0,x0,w2) FMA4(b1,x1,w2) FMA4(b2,x2,w2) FMA4(b3,x3,w2)
    }
    if (u < 254){
      float bv = e1b[u];
      float va[4]={hsum4(a0),hsum4(a1),hsum4(a2),hsum4(a3)};
      float vb[4]={hsum4(b0),hsum4(b1),hsum4(b2),hsum4(b3)};
      #pragma unroll
      for (int i=0;i<4;i++){
        int n = n0 + eg + 8*i;
        ws[OFF_A + n*256 + u] = bv + va[i];
        ws[OFF_B + n*256 + u] = vb[i];
      }
    }
  }
}

// ---- per-edge chain (spill-free pattern) ----
#define EB 32
__global__ __launch_bounds__(256) void k_edge(
    const float* __restrict__ mnc, const int* __restrict__ eidx,
    const float* __restrict__ e2b, const float* __restrict__ c1b,
    const float* __restrict__ c2w, const float* __restrict__ c2b,
    float* __restrict__ ws)
{
  __shared__ float eh [EB][260];
  __shared__ float mij[EB][68];
  __shared__ float srel[EB][4];
  __shared__ int ssrc[EB], sdst[EB];
  int tid = threadIdx.x;
  int e0b = blockIdx.x*EB;
  if (tid < EB){
    int e = e0b + tid;
    int s = eidx[e], d = eidx[EE + e];
    ssrc[tid]=s; sdst[tid]=d;
    float rd = 0.f;
    #pragma unroll
    for (int k=0;k<3;k++){ float r = mnc[s*ID+k]-mnc[d*ID+k]; srel[tid][k]=r; rd += r*r; }
    srel[tid][3] = rd;
  }
  for (int idx=tid; idx<EB*5; idx+=256){ mij[idx/5][63+idx%5] = 0.f; }
  __syncthreads();
  for (int idx=tid; idx<EB*256; idx+=256){
    int e = idx>>8, u = idx&255;
    float v = 0.f;
    if (u < 254) v = silu_(ws[OFF_A + sdst[e]*256 + u] + ws[OFF_B + ssrc[e]*256 + u]
                           + ws[OFF_WR + u]*srel[e][3]);
    eh[e][u] = v;
  }
  for (int idx=tid; idx<EB*4; idx+=256){ eh[idx>>2][256+(idx&3)] = 0.f; }
  __syncthreads();
  int eg = tid&7, ug = tid>>3;
  {
    int u0 = 2*ug, u1 = 2*ug+1;
    const float4* w0 = (const float4*)(ws+OFF_W2P + u0*256);
    const float4* w1 = (const float4*)(ws+OFF_W2P + u1*256);
    float4 a0=Z4,a1=Z4,a2=Z4,a3=Z4,b0=Z4,b1=Z4,b2=Z4,b3=Z4;
    for (int jj=0;jj<64;jj++){
      float4 wv0=w0[jj], wv1=w1[jj];
      float4 x0 = *(const float4*)&eh[eg   ][jj*4];
      float4 x1 = *(const float4*)&eh[eg+ 8][jj*4];
      float4 x2 = *(const float4*)&eh[eg+16][jj*4];
      float4 x3 = *(const float4*)&eh[eg+24][jj*4];
      FMA4(a0,x0,wv0) FMA4(a1,x1,wv0) FMA4(a2,x2,wv0) FMA4(a3,x3,wv0)
      FMA4(b0,x0,wv1) FMA4(b1,x1,wv1) FMA4(b2,x2,wv1) FMA4(b3,x3,wv1)
    }
    float va[4]={hsum4(a0),hsum4(a1),hsum4(a2),hsum4(a3)};
    float vb[4]={hsum4(b0),hsum4(b1),hsum4(b2),hsum4(b3)};
    float bv0 = e2b[u0];
    #pragma unroll
    for (int i=0;i<4;i++){
      int e = eg + 8*i;
      float v = silu_(bv0 + va[i]);
      mij[e][u0] = v; ws[OFF_EDGE + (e0b+e)*68 + u0] = v;
      if (u1 < 63){
        float v1 = silu_(e2b[u1] + vb[i]);
        mij[e][u1] = v1; ws[OFF_EDGE + (e0b+e)*68 + u1] = v1;
      }
    }
  }
  __syncthreads();
  for (int uc=0; uc<4; uc++){
    int u0 = uc*64 + 2*ug, u1 = u0+1;
    const float4* w0 = (const float4*)(ws+OFF_C1P + u0*64);
    const float4* w1 = (const float4*)(ws+OFF_C1P + u1*64);
    float4 a0=Z4,a1=Z4,a2=Z4,a3=Z4,b0=Z4,b1=Z4,b2=Z4,b3=Z4;
    for (int jj=0;jj<16;jj++){
      float4 wv0=w0[jj], wv1=w1[jj];
      float4 x0 = *(const float4*)&mij[eg   ][jj*4];
      float4 x1 = *(const float4*)&mij[eg+ 8][jj*4];
      float4 x2 = *(const float4*)&mij[eg+16][jj*4];
      float4 x3 = *(const float4*)&mij[eg+24][jj*4];
      FMA4(a0,x0,wv0) FMA4(a1,x1,wv0) FMA4(a2,x2,wv0) FMA4(a3,x3,wv0)
      FMA4(b0,x0,wv1) FMA4(b1,x1,wv1) FMA4(b2,x2,wv1) FMA4(b3,x3,wv1)
    }
    float va[4]={hsum4(a0),hsum4(a1),hsum4(a2),hsum4(a3)};
    float vb[4]={hsum4(b0),hsum4(b1),hsum4(b2),hsum4(b3)};
    #pragma unroll
    for (int i=0;i<4;i++){
      int e = eg + 8*i;
      if (u0 < 252) eh[e][u0] = silu_(c1b[u0] + va[i]);
      if (u1 < 252) eh[e][u1] = silu_(c1b[u1] + vb[i]);
    }
  }
  __syncthreads();
  {
    int e = tid>>3, q = tid&7;
    const float4* xr = (const float4*)&eh[e][0];
    const float4* wr4 = (const float4*)c2w;
    float4 a = Z4;
    for (int jj=q; jj<63; jj+=8){ float4 xv=xr[jj], wv=wr4[jj]; FMA4(a,xv,wv) }
    float s = hsum4(a);
    s += __shfl_down(s,4,64); s += __shfl_down(s,2,64); s += __shfl_down(s,1,64);
    if (q == 0){
      float cw = s + c2b[0];
      #pragma unroll
      for (int k=0;k<3;k++) ws[OFF_EDGE + (e0b+e)*68 + 64 + k] = cw*srel[e][k];
    }
  }
}

// ---- node MLP (float4, padded weights) + gathers -> smi_pre ----
#define NNB 8
__global__ __launch_bounds__(256) void k_node(
    const float* __restrict__ mnc,
    const float* __restrict__ n1b, const float* __restrict__ n2b,
    float* __restrict__ ws, const int* __restrict__ iw)
{
  __shared__ float xin[NNB][132];
  __shared__ float t1 [NNB][132];
  int tid = threadIdx.x;
  int n0 = blockIdx.x*NNB;
  for (int idx=tid; idx<NNB*128; idx+=256){
    int e = idx>>7, j = idx&127;
    int node = n0 + e;
    float v = 0.f;
    if (j < 63) v = mnc[node*ID + 3 + j];
    else if (j < 126){
      int u = j - 63;
      int cnt = iw[IOFF_ECNT+node]; if (cnt > ECAP) cnt = ECAP;
      for (int q=0;q<cnt;q++) v += ws[OFF_EDGE + iw[IOFF_ELIST+node*ECAP+q]*68 + u];
    }
    xin[e][j] = v;
    t1[e][j] = 0.f;
  }
  __syncthreads();
  {
    int ng = tid&3, ug = tid>>2;
    int u0 = 2*ug, u1 = u0+1;
    const float4* w0 = (const float4*)(ws+OFF_N1P + u0*128);
    const float4* w1 = (const float4*)(ws+OFF_N1P + u1*128);
    float4 a0=Z4,a1=Z4,b0=Z4,b1=Z4;
    for (int jj=0;jj<32;jj++){
      float4 wv0=w0[jj], wv1=w1[jj];
      float4 x0 = *(const float4*)&xin[ng  ][jj*4];
      float4 x1 = *(const float4*)&xin[ng+4][jj*4];
      FMA4(a0,x0,wv0) FMA4(a1,x1,wv0)
      FMA4(b0,x0,wv1) FMA4(b1,x1,wv1)
    }
    if (u0 < 126){ float bv=n1b[u0]; t1[ng][u0]=silu_(bv+hsum4(a0)); t1[ng+4][u0]=silu_(bv+hsum4(a1)); }
    if (u1 < 126){ float bv=n1b[u1]; t1[ng][u1]=silu_(bv+hsum4(b0)); t1[ng+4][u1]=silu_(bv+hsum4(b1)); }
  }
  __syncthreads();
  {
    int ng = tid&7, ug = tid>>3;
    int u0 = 2*ug, u1 = u0+1;
    const float4* w0 = (const float4*)(ws+OFF_N2P + u0*128);
    const float4* w1 = (const float4*)(ws+OFF_N2P + u1*128);
    float4 a0=Z4,b0=Z4;
    if (u0 < 63){
      for (int jj=0;jj<32;jj++){
        float4 x0 = *(const float4*)&t1[ng][jj*4];
        FMA4(a0,x0,w0[jj]) FMA4(b0,x0,w1[jj])
      }
      int node = n0 + ng;
      ws[OFF_SMIP + node*ID + 3 + u0] = nan0(xin[ng][u0] + n2b[u0] + hsum4(a0));
      if (u1 < 63)
        ws[OFF_SMIP + node*ID + 3 + u1] = nan0(xin[ng][u1] + n2b[u1] + hsum4(b0));
    }
  }
  if (tid < NNB*3){
    int e = tid/3, k = tid%3;
    int node = n0 + e;
    int cnt = iw[IOFF_ECNT+node]; if (cnt > ECAP) cnt = ECAP;
    float s = mnc[node*ID + k];
    for (int q=0;q<cnt;q++) s += ws[OFF_EDGE + iw[IOFF_ELIST+node*ECAP+q]*68 + 64 + k];
    ws[OFF_SMIP + node*ID + k] = nan0(s);
  }
}

// ---- batchnorm ----
__global__ __launch_bounds__(256) void k_bn_stats(float* __restrict__ ws){
  __shared__ float scr[8];
  int j = blockIdx.x, tid = threadIdx.x;
  float s=0.f, ss=0.f;
  for (int i=tid; i<NN; i+=256){ float x = ws[OFF_SMIP + i*ID + j]; s+=x; ss+=x*x; }
  for (int o=32;o>0;o>>=1){ s += __shfl_down(s,o,64); ss += __shfl_down(ss,o,64); }
  int w = tid>>6;
  if ((tid&63)==0){ scr[w]=s; scr[4+w]=ss; }
  __syncthreads();
  if (tid==0){
    float S=0,SS=0;
    for (int q=0;q<4;q++){S+=scr[q];SS+=scr[4+q];}
    float mean = S/NN;
    float var  = SS/NN - mean*mean;
    ws[OFF_STATS + j]      = mean;
    ws[OFF_STATS + 66 + j] = 1.0f/sqrtf(var + 1e-5f);
  }
}
__global__ void k_bn_apply(const float* __restrict__ bng, const float* __restrict__ bnb,
                           float* __restrict__ ws){
  int idx = blockIdx.x*256 + threadIdx.x;
  if (idx < NN*ID){
    int j = idx % ID;
    ws[OFF_OUT + idx] = bng[j]*(ws[OFF_SMIP+idx]-ws[OFF_STATS+j])*ws[OFF_STATS+66+j] + bnb[j];
  }
}

// ---- T[n][t*66+o] = sum_i h[n,i]*Qaug[i,t,o] ----
__global__ __launch_bounds__(256) void k_tbuild(float* __restrict__ ws){
  __shared__ float xs[16][68];
  int tid = threadIdx.x;
  int n0 = blockIdx.x*16;
  for (int idx=tid; idx<16*68; idx+=256){ int n=idx/68, j=idx%68;
    xs[n][j] = (j<66)? ws[OFF_OUT + (n0+n)*ID + j] : 0.f; }
  __syncthreads();
  for (int pass=0; pass<3; pass++){
    int to = pass*256 + tid;
    if (to < 726){
      float acc[16];
      #pragma unroll
      for (int n=0;n<16;n++) acc[n] = 0.f;
      const float4* qp = (const float4*)(ws + OFF_QAUG + to*68);
      for (int jj=0;jj<17;jj++){
        float4 w = qp[jj];
        #pragma unroll
        for (int n=0;n<16;n++){
          float4 x = *(const float4*)&xs[n][jj*4];
          acc[n] += x.x*w.x + x.y*w.y + x.z*w.z + x.w*w.w;
        }
      }
      #pragma unroll
      for (int n=0;n<16;n++) ws[OFF_T + (n0+n)*726 + to] = acc[n];
    }
  }
}

// ---- m = relu(gathered_msg/deg + h@root + nn_bias) ----
#define MNB 8
__global__ __launch_bounds__(256) void k_mnode(
    const float* __restrict__ root, const float* __restrict__ nnbias,
    const int* __restrict__ eidx, const float* __restrict__ ea,
    float* __restrict__ ws, const int* __restrict__ iw)
{
  __shared__ float rs[66][68];
  __shared__ float xo[MNB][68];
  int tid = threadIdx.x;
  int n0 = blockIdx.x*MNB;
  for (int idx=tid; idx<66*66; idx+=256) rs[idx/66][idx%66] = root[idx];
  for (int idx=tid; idx<MNB*66; idx+=256) xo[idx/66][idx%66] = ws[OFF_OUT + n0*ID + idx];
  __syncthreads();
  for (int idx=tid; idx<MNB*66; idx+=256){
    int n = idx/66, o = idx%66;
    int node = n0 + n;
    int rawcnt = iw[IOFF_ECNT+node];
    int cnt = rawcnt > ECAP ? ECAP : rawcnt;
    float magg = 0.f;
    for (int q=0;q<cnt;q++){
      int e = iw[IOFF_ELIST + node*ECAP + q];
      int s = eidx[e];
      const float* Tp = ws + OFF_T + s*726 + o;
      const float* eap = ea + e*10;
      float av = Tp[660];
      #pragma unroll
      for (int t=0;t<10;t++) av += eap[t]*Tp[t*66];
      magg += av;
    }
    float deg = fmaxf((float)rawcnt, 1.0f);
    float s2 = nnbias[o] + magg/deg;
    for (int j=0;j<66;j++) s2 += xo[n][j]*rs[j][o];
    s2 = fmaxf(s2, 0.0f);
    ws[OFF_M  + node*ID  + o] = s2;
    ws[OFF_CM + node*132 + o] = s2;
  }
}

// ---- fused sparse conv ----
__global__ __launch_bounds__(256) void k_spconv(
    const float* __restrict__ cv1b, const float* __restrict__ cv2w,
    const float* __restrict__ cv2b,
    int it, float* __restrict__ ws, const int* __restrict__ iw)
{
  __shared__ float mid[DD][68];
  __shared__ float mps[32][68];
  __shared__ float w1s[32][192];
  __shared__ float vv[32];
  __shared__ float w2s[204];
  __shared__ float part[4][64];
  int tid = threadIdx.x;
  int a = blockIdx.x;
  for (int idx=tid; idx<DD*68; idx+=256) (&mid[0][0])[idx] = 0.f;
  if (tid < 198) w2s[tid] = cv2w[it*198 + tid];
  int nnz = iw[IOFF_CNT + a]; if (nnz > CAP) nnz = CAP;
  __syncthreads();
  for (int q0=0; q0<nnz; q0+=32){
    int qn = nnz - q0; if (qn > 32) qn = 32;
    for (int idx=tid; idx<qn*68; idx+=256){
      int q=idx/68, cc=idx%68;
      int b = iw[IOFF_CIDX + a*CAP + q0 + q];
      mps[q][cc] = (cc>=1 && cc<=66)? ws[OFF_M + b*ID + cc-1] : 0.f;
    }
    for (int idx=tid; idx<qn*192; idx+=256){
      int q=idx/192, r=idx%192;
      int b = iw[IOFF_CIDX + a*CAP + q0 + q];
      w1s[q][r] = ws[OFF_C1R + (it*1024+b)*192 + r];
    }
    if (tid < qn) vv[tid] = ws[OFF_CVAL + a*CAP + q0 + tid];
    __syncthreads();
    for (int idx=tid; idx<DD*ID; idx+=256){
      int o = idx/ID, cc = idx%ID;
      float acc = mid[o][cc];
      for (int q=0;q<qn;q++){
        acc += vv[q]*(w1s[q][o*3]*mps[q][cc] + w1s[q][o*3+1]*mps[q][cc+1] + w1s[q][o*3+2]*mps[q][cc+2]);
      }
      mid[o][cc] = acc;
    }
    __syncthreads();
  }
  for (int idx=tid; idx<DD*ID; idx+=256){ int o=idx/ID, cc=idx%ID; mid[o][cc] += cv1b[it*DD+o]; }
  __syncthreads();
  {
    int x = tid & 63, qq = tid >> 6;
    int c0 = qq*17, cN = c0+17; if (cN > ID) cN = ID;
    float s = 0.f;
    for (int cc=c0; cc<cN; cc++){
      #pragma unroll
      for (int k=0;k<3;k++){
        int oo = x + k - 1;
        if (oo >= 0 && oo < DD) s += mid[oo][cc]*w2s[cc*3+k];
      }
    }
    part[qq][x] = s;
  }
  __syncthreads();
  if (tid < DD)
    ws[OFF_CM + a*132 + ID + tid] = part[0][tid]+part[1][tid]+part[2][tid]+part[3][tid] + cv2b[it];
}

// ---- gate score + per-mol segment softmax -> av[node] ----
__global__ __launch_bounds__(64) void k_af(
    const int* __restrict__ mb,
    const float* __restrict__ lfw, const float* __restrict__ lfb,
    float* __restrict__ ws)
{
  __shared__ int memb[MAXM]; __shared__ int lcnt;
  int tid = threadIdx.x, m = blockIdx.x;
  if (tid==0) lcnt = 0;
  __syncthreads();
  for (int i=tid; i<NN; i+=64)
    if (mb[i]==m){ int p = atomicAdd(&lcnt,1); if (p<MAXM) memb[p]=i; }
  __syncthreads();
  int M = lcnt; if (M > MAXM) M = MAXM;
  float x = -INFINITY;
  if (tid < M){
    const float4* cr = (const float4*)(ws + OFF_CM + memb[tid]*132);
    const float4* lw = (const float4*)lfw;
    float4 a = Z4;
    for (int jj=0;jj<32;jj++){ float4 cv=cr[jj], wv=lw[jj]; FMA4(a,cv,wv) }
    const float* crow = ws + OFF_CM + memb[tid]*132;
    float s = hsum4(a) + crow[128]*lfw[128] + crow[129]*lfw[129] + lfb[0];
    x = (s > 0.f) ? s : 0.01f*s;
  }
  float mx = x;
  for (int o=32;o>0;o>>=1) mx = fmaxf(mx, __shfl_xor(mx,o,64));
  float ex = (tid<M) ? expf(x-mx) : 0.f;
  float sm = ex;
  for (int o=32;o>0;o>>=1) sm += __shfl_xor(sm,o,64);
  if (tid<M) ws[OFF_AV + memb[tid]] = ex/(sm + 1e-16f);
}

// ---- GRU gate GEMM + blend, node-parallel (4 nodes/block, 256 blocks) ----
__global__ __launch_bounds__(256) void k_grug(
    const float* __restrict__ bih, const float* __restrict__ bhh,
    float* __restrict__ ws)
{
  __shared__ float xs[GNB][132];   // av*cm (130 data, pad 0)
  __shared__ float hs[GNB][68];    // h (66 data, pad 0)
  __shared__ float ggg[GNB][132];  // r,z
  __shared__ float g1[GNB][68], g2[GNB][68];
  int tid = threadIdx.x;
  int n0 = blockIdx.x*GNB;
  for (int idx=tid; idx<GNB*132; idx+=256){
    int n = idx/132, j = idx%132;
    xs[n][j] = (j<130)? ws[OFF_AV + n0 + n] * ws[OFF_CM + (n0+n)*132 + j] : 0.f;
  }
  for (int idx=tid; idx<GNB*68; idx+=256){
    int n = idx/68, j = idx%68;
    hs[n][j] = (j<66)? ws[OFF_OUT + (n0+n)*ID + j] : 0.f;
  }
  __syncthreads();
  if (tid < 198){
    int u = tid;
    const float4* w1 = (const float4*)(ws+OFF_GIH + u*132);
    const float4* w2 = (const float4*)(ws+OFF_GHH + u*68);
    float4 a0=Z4,a1=Z4,a2=Z4,a3=Z4;
    for (int jj=0;jj<33;jj++){
      float4 w = w1[jj];
      FMA4(a0,*(const float4*)&xs[0][jj*4],w)
      FMA4(a1,*(const float4*)&xs[1][jj*4],w)
      FMA4(a2,*(const float4*)&xs[2][jj*4],w)
      FMA4(a3,*(const float4*)&xs[3][jj*4],w)
    }
    float4 b0=Z4,b1=Z4,b2=Z4,b3=Z4;
    for (int jj=0;jj<17;jj++){
      float4 w = w2[jj];
      FMA4(b0,*(const float4*)&hs[0][jj*4],w)
      FMA4(b1,*(const float4*)&hs[1][jj*4],w)
      FMA4(b2,*(const float4*)&hs[2][jj*4],w)
      FMA4(b3,*(const float4*)&hs[3][jj*4],w)
    }
    float bv1 = bih[u], bv2 = bhh[u];
    float d1[4] = {hsum4(a0),hsum4(a1),hsum4(a2),hsum4(a3)};
    float d2[4] = {hsum4(b0),hsum4(b1),hsum4(b2),hsum4(b3)};
    #pragma unroll
    for (int n=0;n<4;n++){
      float v1 = bv1 + d1[n];
      float v2 = bv2 + d2[n];
      if (u < 132) ggg[n][u] = sgm(v1+v2);
      else { g1[n][u-132] = v1; g2[n][u-132] = v2; }
    }
  }
  __syncthreads();
  for (int idx=tid; idx<GNB*66; idx+=256){
    int n = idx/66, u = idx%66;
    float r = ggg[n][u], z = ggg[n][66+u];
    float nn_ = tanhf(g1[n][u] + r*g2[n][u]);
    ws[OFF_OUT + (n0+n)*ID + u] = (1.f - z)*nn_ + z*hs[n][u];
  }
}

// ---- Set2Set readout ----
__global__ __launch_bounds__(256) void k_s2s(
    const int* __restrict__ mb,
    const float* __restrict__ wih, const float* __restrict__ whh,
    const float* __restrict__ bih, const float* __restrict__ bhh,
    float* __restrict__ ws)
{
  __shared__ int memb[MAXM]; __shared__ int lcnt;
  __shared__ float orow[MAXM][68];
  __shared__ float hsv[66], csv[66], qsv[132], gv[264];
  __shared__ float av[MAXM];
  int tid = threadIdx.x, m = blockIdx.x;
  if (tid==0) lcnt = 0;
  __syncthreads();
  for (int i=tid; i<NN; i+=256)
    if (mb[i]==m){ int p = atomicAdd(&lcnt,1); if (p<MAXM) memb[p]=i; }
  __syncthreads();
  int M = lcnt; if (M > MAXM) M = MAXM;
  for (int idx=tid; idx<M*ID; idx+=256){ int i=idx/ID, j=idx%ID; orow[i][j]=ws[OFF_OUT+memb[i]*ID+j]; }
  if (tid < 66){ hsv[tid]=0.f; csv[tid]=0.f; }
  if (tid < 132) qsv[tid]=0.f;
  __syncthreads();
  for (int step=0; step<3; step++){
    for (int u=tid; u<264; u+=256){
      float s = bih[u] + bhh[u];
      const float* w1 = wih + u*132;
      for (int j=0;j<132;j++) s += qsv[j]*w1[j];
      const float* w2 = whh + u*ID;
      for (int j=0;j<ID;j++) s += hsv[j]*w2[j];
      gv[u] = s;
    }
    __syncthreads();
    if (tid < 66){
      float ig=gv[tid], fg=gv[66+tid], gg_=gv[132+tid], og=gv[198+tid];
      float c = sgm(fg)*csv[tid] + sgm(ig)*tanhf(gg_);
      csv[tid] = c;
      hsv[tid] = sgm(og)*tanhf(c);
    }
    __syncthreads();
    if (tid < 64){
      float e = -INFINITY;
      if (tid < M){ e = 0.f; for (int j=0;j<ID;j++) e += orow[tid][j]*hsv[j]; }
      float mx = e;
      for (int o=32;o>0;o>>=1) mx = fmaxf(mx, __shfl_xor(mx,o,64));
      float ex = (tid<M) ? expf(e-mx) : 0.f;
      float sm = ex;
      for (int o=32;o>0;o>>=1) sm += __shfl_xor(sm,o,64);
      if (tid<M) av[tid] = ex/(sm + 1e-16f);
    }
    __syncthreads();
    if (tid < 66){
      float r = 0.f;
      for (int i=0;i<M;i++) r += av[i]*orow[i][tid];
      qsv[tid]      = hsv[tid];
      qsv[66+tid]   = r;
    }
    __syncthreads();
  }
  if (tid < 132) ws[OFF_QSTAR + m*132 + tid] = qsv[tid];
}

// ---- fingers MLP ----
__global__ __launch_bounds__(256) void k_fd1(
    const float* __restrict__ fing, const float* __restrict__ d1w, const float* __restrict__ d1b,
    float* __restrict__ ws)
{
  __shared__ __align__(16) float fin[1024];
  int tid = threadIdx.x;
  int b = blockIdx.x >> 4, u0 = (blockIdx.x & 15)*32;
  for (int j=tid; j<1024; j+=256) fin[j] = fing[b*1024+j];
  __syncthreads();
  int u = u0 + (tid>>3), q = tid & 7;
  const float4* w4 = (const float4*)(d1w + u*1024);
  const float4* x4 = (const float4*)fin;
  float4 a = Z4;
  for (int jj=q; jj<256; jj+=8){ float4 wv=w4[jj], xv=x4[jj]; FMA4(a,xv,wv) }
  float s = hsum4(a);
  s += __shfl_xor(s,1,64); s += __shfl_xor(s,2,64); s += __shfl_xor(s,4,64);
  if (q==0) ws[OFF_F1 + b*512 + u] = fmaxf(s + d1b[u], 0.f);
}
__global__ __launch_bounds__(256) void k_fd2(
    const float* __restrict__ d2w, const float* __restrict__ d2b, float* __restrict__ ws)
{
  __shared__ __align__(16) float f1[512];
  int tid = threadIdx.x;
  int b = blockIdx.x >> 3, u0 = (blockIdx.x & 7)*32;
  for (int j=tid; j<512; j+=256) f1[j] = ws[OFF_F1 + b*512 + j];
  __syncthreads();
  int u = u0 + (tid>>3), q = tid & 7;
  const float4* w4 = (const float4*)(d2w + u*512);
  const float4* x4 = (const float4*)f1;
  float4 a = Z4;
  for (int jj=q; jj<128; jj+=8){ float4 wv=w4[jj], xv=x4[jj]; FMA4(a,xv,wv) }
  float s = hsum4(a);
  s += __shfl_xor(s,1,64); s += __shfl_xor(s,2,64); s += __shfl_xor(s,4,64);
  if (q==0) ws[OFF_F2 + b*256 + u] = fmaxf(s + d2b[u], 0.f);
}
__global__ __launch_bounds__(256) void k_fd3p(
    const float* __restrict__ d3w, const float* __restrict__ d3b,
    const float* __restrict__ pw,  const float* __restrict__ pb,
    const float* __restrict__ ws,  float* __restrict__ outp)
{
  __shared__ __align__(16) float f2[256];
  __shared__ float f3[64];
  int tid = threadIdx.x, b = blockIdx.x;
  for (int j=tid; j<256; j+=256) f2[j] = ws[OFF_F2 + b*256 + j];
  __syncthreads();
  {
    int u = tid>>2, q = tid&3;
    const float4* w4 = (const float4*)(d3w + u*256);
    const float4* x4 = (const float4*)f2;
    float4 a = Z4;
    for (int jj=q; jj<64; jj+=4){ float4 wv=w4[jj], xv=x4[jj]; FMA4(a,xv,wv) }
    float s = hsum4(a);
    s += __shfl_xor(s,1,64); s += __shfl_xor(s,2,64);
    if (q==0) f3[u] = s + d3b[u];
  }
  __syncthreads();
  if (tid < 64){
    float s = 0.f;
    for (int j=tid; j<132; j+=64) s += ws[OFF_QSTAR + b*132 + j]*pw[j];
    s += f3[tid]*pw[132 + tid];
    for (int o=32;o>0;o>>=1) s += __shfl_xor(s,o,64);
    if (tid==0) outp[b] = s + pb[0];
  }
}

extern "C" void kernel_launch(void* const* d_in, const int* in_sizes, int n_in,
                              void* d_out, int out_size, void* d_ws, size_t ws_size,
                              hipStream_t stream)
{
  const float* mnc = (const float*)d_in[0];
  const float* ea  = (const float*)d_in[1];
  const float* fing= (const float*)d_in[2];
  const int*   eidx= (const int*)d_in[3];
  const int*   mb  = (const int*)d_in[4];
  const float* adj = (const float*)d_in[5];
  const float* e1w=(const float*)d_in[6],  *e1b=(const float*)d_in[7];
  const float* e2w=(const float*)d_in[8],  *e2b=(const float*)d_in[9];
  const float* c1w=(const float*)d_in[10], *c1b=(const float*)d_in[11];
  const float* c2w=(const float*)d_in[12], *c2b=(const float*)d_in[13];
  const float* n1w=(const float*)d_in[14], *n1b=(const float*)d_in[15];
  const float* n2w=(const float*)d_in[16], *n2b=(const float*)d_in[17];
  const float* bng=(const float*)d_in[18], *bnb=(const float*)d_in[19];
  const float* nnw=(const float*)d_in[20], *nnb=(const float*)d_in[21];
  const float* root=(const float*)d_in[22],*nnbias=(const float*)d_in[23];
  const float* cv1w=(const float*)d_in[24],*cv1b=(const float*)d_in[25];
  const float* cv2w=(const float*)d_in[26],*cv2b=(const float*)d_in[27];
  const float* lfw=(const float*)d_in[28], *lfb=(const float*)d_in[29];
  const float* gwih=(const float*)d_in[30],*gwhh=(const float*)d_in[31];
  const float* gbih=(const float*)d_in[32],*gbhh=(const float*)d_in[33];
  const float* lwih=(const float*)d_in[34],*lwhh=(const float*)d_in[35];
  const float* lbih=(const float*)d_in[36],*lbhh=(const float*)d_in[37];
  const float* d1w=(const float*)d_in[38], *d1b=(const float*)d_in[39];
  const float* d2w=(const float*)d_in[40], *d2b=(const float*)d_in[41];
  const float* d3w=(const float*)d_in[42], *d3b=(const float*)d_in[43];
  const float* pw =(const float*)d_in[44], *pb =(const float*)d_in[45];
  float* ws = (float*)d_ws;
  int*   iw = (int*)(ws + OFF_FEND);
  float* outp = (float*)d_out;

  const long long setup_total = (long long)NN*NN + EE + 16384 + 16384 + 16384
                              + 726*68 + 3*1024*192 + 198*132 + 198*68
                              + 126*128 + 63*128;
  int setup_blocks = (int)((setup_total + 255)/256);

  k_zero0    <<<4, 256, 0, stream>>>(iw);
  k_setup    <<<setup_blocks, 256, 0, stream>>>(adj, eidx, e1w, e2w, c1w, nnw, nnb, cv1w, gwih, gwhh, n1w, n2w, ws, iw);
  k_ab       <<<NN/32, 256, 0, stream>>>(mnc, e1b, ws);
  k_edge     <<<EE/EB, 256, 0, stream>>>(mnc, eidx, e2b, c1b, c2w, c2b, ws);
  k_node     <<<NN/NNB, 256, 0, stream>>>(mnc, n1b, n2b, ws, iw);
  k_bn_stats <<<ID, 256, 0, stream>>>(ws);
  k_bn_apply <<<(NN*ID+255)/256, 256, 0, stream>>>(bng, bnb, ws);
  for (int it=0; it<3; ++it){
    k_tbuild <<<NN/16, 256, 0, stream>>>(ws);
    k_mnode  <<<NN/MNB, 256, 0, stream>>>(root, nnbias, eidx, ea, ws, iw);
    k_spconv <<<NN, 256, 0, stream>>>(cv1b, cv2w, cv2b, it, ws, iw);
    k_af     <<<BB, 64, 0, stream>>>(mb, lfw, lfb, ws);
    k_grug   <<<NN/GNB, 256, 0, stream>>>(gbih, gbhh, ws);
  }
  k_s2s      <<<BB, 256, 0, stream>>>(mb, lwih, lwhh, lbih, lbhh, ws);
  k_fd1      <<<BB*16, 256, 0, stream>>>(fing, d1w, d1b, ws);
  k_fd2      <<<BB*8, 256, 0, stream>>>(d2w, d2b, ws);
  k_fd3p     <<<BB, 256, 0, stream>>>(d3w, d3b, pw, pb, ws, outp);
}

// Round 9
// 658.760 us; speedup vs baseline: 1.8468x; 1.1682x over previous
//
#include <hip/hip_runtime.h>
#include <math.h>

// Problem constants (fixed by the reference)
#define NN 1024   // nodes
#define BB 32     // mols
#define EE 8192   // edges
#define DD 64     // DIM
#define ID 66     // IN_DIM
#define FT 63     // feats dim
#define CAP 128   // max nnz per adj column
#define ECAP 64   // max in-edges per node
#define MAXM 64   // max nodes per mol (s2s)
#define GNB 4     // nodes per block in gru gate gemm

// ---- workspace layout (float offsets) ----
enum : int {
  OFF_SMIP  = 0,                        // N*66 pre-BN smi
  OFF_OUT   = OFF_SMIP + NN*ID,         // N*66 h
  OFF_STATS = OFF_OUT + NN*ID,          // 144 mean/rstd
  OFF_M     = OFF_STATS + 144,          // N*66 m buffer
  OFF_CM    = OFF_M + NN*ID,            // N*132 cm
  OFF_QSTAR = OFF_CM + NN*132,          // 32*132
  OFF_CVAL  = OFF_QSTAR + BB*132,       // N*CAP csc values
  OFF_A     = OFF_CVAL + NN*CAP,        // 1024*256 A = feats@W1a^T + e1b
  OFF_B     = OFF_A + 1024*256,         // 1024*256 B = feats@W1b^T
  OFF_EDGE  = OFF_B + 1024*256,         // 8192*68: [0..62]=mij, [64..66]=cw*rel
  OFF_T     = OFF_EDGE + EE*68,         // 1024*726 T[n][t*66+o]
  OFF_QAUG  = OFF_T + NN*726,           // 726*68 Qaug[(t*66+o)][i]
  OFF_W1A   = OFF_QAUG + 726*68,        // 256*64
  OFF_W1B   = OFF_W1A + 16384,          // 256*64
  OFF_WR    = OFF_W1B + 16384,          // 256
  OFF_W2P   = OFF_WR + 256,             // 64*256 padded e2w
  OFF_C1P   = OFF_W2P + 16384,          // 256*64 padded c1w
  OFF_C1R   = OFF_C1P + 16384,          // 3*1024*192 conv1_w reorg
  OFF_GIH   = OFF_C1R + 3*1024*192,     // 198*132
  OFF_GHH   = OFF_GIH + 198*132,        // 198*68
  OFF_F1    = OFF_GHH + 198*68,         // 32*512
  OFF_F2    = OFF_F1 + BB*512,          // 32*256
  OFF_AV    = OFF_F2 + BB*256,          // N  softmax gate per node
  OFF_N1P   = OFF_AV + NN,              // 126*128 padded n1w
  OFF_N2P   = OFF_N1P + 126*128,        // 63*128  padded n2w
  OFF_FEND  = OFF_N2P + 63*128
};
enum : int {  // int region at ws + OFF_FEND
  IOFF_CNT   = 0,                 // N   csc col counts
  IOFF_CIDX  = NN,                // N*CAP
  IOFF_ECNT  = NN + NN*CAP,       // N   in-degree
  IOFF_ELIST = NN + NN*CAP + NN,  // N*ECAP edge ids sorted by dst
  IOFF_END   = NN + NN*CAP + NN + NN*ECAP
};

__device__ __forceinline__ float sgm(float x){ return 1.0f/(1.0f+expf(-x)); }
__device__ __forceinline__ float silu_(float x){ return x/(1.0f+expf(-x)); }
__device__ __forceinline__ float nan0(float v){ return (v!=v) ? 0.0f : v; }
__device__ __forceinline__ float hsum4(float4 v){ return v.x+v.y+v.z+v.w; }
#define FMA4(A,X,W) {A.x += (X).x*(W).x; A.y += (X).y*(W).y; A.z += (X).z*(W).z; A.w += (X).w*(W).w;}
#define Z4 {0.f,0.f,0.f,0.f}

// ---- zero the atomic counters ----
__global__ void k_zero0(int* __restrict__ iw){
  int i = blockIdx.x*256 + threadIdx.x;
  if (i < NN){ iw[IOFF_CNT + i] = 0; iw[IOFF_ECNT + i] = 0; }
}

// ---- one-shot setup: csc(adj), edge sort by dst, weight reorg/pad ----
__global__ void k_setup(const float* __restrict__ adj, const int* __restrict__ eidx,
                        const float* __restrict__ e1w, const float* __restrict__ e2w,
                        const float* __restrict__ c1w,
                        const float* __restrict__ nnw, const float* __restrict__ nnb,
                        const float* __restrict__ cv1w,
                        const float* __restrict__ gwih, const float* __restrict__ gwhh,
                        const float* __restrict__ n1w, const float* __restrict__ n2w,
                        float* __restrict__ ws, int* __restrict__ iw){
  long long idx = (long long)blockIdx.x*256 + threadIdx.x;
  if (idx < (long long)NN*NN){
    float v = adj[idx];
    if (v != 0.0f){
      int a = (int)(idx & 1023), b = (int)(idx >> 10);
      int p = atomicAdd(iw + IOFF_CNT + a, 1);
      if (p < CAP){ iw[IOFF_CIDX + a*CAP + p] = b; ws[OFF_CVAL + a*CAP + p] = v; }
    }
    return;
  }
  idx -= (long long)NN*NN;
  if (idx < EE){
    int e = (int)idx, d = eidx[EE + e];
    int p = atomicAdd(iw + IOFF_ECNT + d, 1);
    if (p < ECAP) iw[IOFF_ELIST + d*ECAP + p] = e;
    return;
  }
  idx -= EE;
  if (idx < 16384){ int u=(int)idx>>6, j=(int)idx&63;
    ws[OFF_W1A+idx] = (u<254 && j<63)? e1w[u*127+j]      : 0.f;
    ws[OFF_W1B+idx] = (u<254 && j<63)? e1w[u*127+63+j]   : 0.f;
    if (j==0) ws[OFF_WR+u] = (u<254)? e1w[u*127+126] : 0.f;
    return; }
  idx -= 16384;
  if (idx < 16384){ int u=(int)idx>>8, j=(int)idx&255; ws[OFF_W2P+idx] = (u<63 && j<254)? e2w[u*254+j] : 0.f; return; }
  idx -= 16384;
  if (idx < 16384){ int u=(int)idx>>6, j=(int)idx&63; ws[OFF_C1P+idx] = (u<252 && j<63)? c1w[u*63+j] : 0.f; return; }
  idx -= 16384;
  if (idx < 726*68){ int to=(int)idx/68, i=(int)idx%68; int t=to/66, o=to%66;
    float v = 0.f;
    if (i < 66) v = (t<10)? nnw[(i*66+o)*10+t] : nnb[i*66+o];
    ws[OFF_QAUG+idx] = v; return; }
  idx -= 726*68;
  if (idx < 3*1024*192){ int it=(int)(idx/196608); int r=(int)(idx%196608); int b=r/192; int z=r%192; int o=z/3, k=z%3;
    ws[OFF_C1R+idx] = cv1w[((it*64+o)*1024+b)*3+k]; return; }
  idx -= 3*1024*192;
  if (idx < 198*132){ int u=(int)idx/132, j=(int)idx%132; ws[OFF_GIH+idx] = (j<130)? gwih[u*130+j] : 0.f; return; }
  idx -= 198*132;
  if (idx < 198*68){ int u=(int)idx/68, j=(int)idx%68; ws[OFF_GHH+idx] = (j<66)? gwhh[u*66+j] : 0.f; return; }
  idx -= 198*68;
  if (idx < 126*128){ int u=(int)idx>>7, j=(int)idx&127; ws[OFF_N1P+idx] = (j<126)? n1w[u*126+j] : 0.f; return; }
  idx -= 126*128;
  if (idx < 63*128){ int u=(int)idx>>7, j=(int)idx&127; ws[OFF_N2P+idx] = (j<126)? n2w[u*126+j] : 0.f; return; }
}

// ---- A/B build ----
__global__ __launch_bounds__(256) void k_ab(const float* __restrict__ mnc,
                                            const float* __restrict__ e1b,
                                            float* __restrict__ ws){
  __shared__ float xf[32][68];
  int tid = threadIdx.x;
  int n0 = blockIdx.x*32;
  for (int idx=tid; idx<32*64; idx+=256){ int n=idx>>6, j=idx&63;
    xf[n][j] = (j<63)? mnc[(n0+n)*ID + 3 + j] : 0.f; }
  __syncthreads();
  int eg = tid&7, ug = tid>>3;
  for (int pass=0; pass<8; pass++){
    int u = pass*32 + ug;
    const float4* wa = (const float4*)(ws + OFF_W1A + u*64);
    const float4* wb = (const float4*)(ws + OFF_W1B + u*64);
    float4 a0=Z4,a1=Z4,a2=Z4,a3=Z4,b0=Z4,b1=Z4,b2=Z4,b3=Z4;
    for (int jj=0;jj<16;jj++){
      float4 w1 = wa[jj], w2 = wb[jj];
      float4 x0 = *(const float4*)&xf[eg   ][jj*4];
      float4 x1 = *(const float4*)&xf[eg+ 8][jj*4];
      float4 x2 = *(const float4*)&xf[eg+16][jj*4];
      float4 x3 = *(const float4*)&xf[eg+24][jj*4];
      FMA4(a0,x0,w1) FMA4(a1,x1,w1) FMA4(a2,x2,w1) FMA4(a3,x3,w1)
      FMA4(b0,x0,w2) FMA4(b1,x1,w2) FMA4(b2,x2,w2) FMA4(b3,x3,w2)
    }
    if (u < 254){
      float bv = e1b[u];
      float va[4]={hsum4(a0),hsum4(a1),hsum4(a2),hsum4(a3)};
      float vb[4]={hsum4(b0),hsum4(b1),hsum4(b2),hsum4(b3)};
      #pragma unroll
      for (int i=0;i<4;i++){
        int n = n0 + eg + 8*i;
        ws[OFF_A + n*256 + u] = bv + va[i];
        ws[OFF_B + n*256 + u] = vb[i];
      }
    }
  }
}

// ---- per-edge chain (spill-free pattern) ----
#define EB 32
__global__ __launch_bounds__(256) void k_edge(
    const float* __restrict__ mnc, const int* __restrict__ eidx,
    const float* __restrict__ e2b, const float* __restrict__ c1b,
    const float* __restrict__ c2w, const float* __restrict__ c2b,
    float* __restrict__ ws)
{
  __shared__ float eh [EB][260];
  __shared__ float mij[EB][68];
  __shared__ float srel[EB][4];
  __shared__ int ssrc[EB], sdst[EB];
  int tid = threadIdx.x;
  int e0b = blockIdx.x*EB;
  if (tid < EB){
    int e = e0b + tid;
    int s = eidx[e], d = eidx[EE + e];
    ssrc[tid]=s; sdst[tid]=d;
    float rd = 0.f;
    #pragma unroll
    for (int k=0;k<3;k++){ float r = mnc[s*ID+k]-mnc[d*ID+k]; srel[tid][k]=r; rd += r*r; }
    srel[tid][3] = rd;
  }
  for (int idx=tid; idx<EB*5; idx+=256){ mij[idx/5][63+idx%5] = 0.f; }
  __syncthreads();
  for (int idx=tid; idx<EB*256; idx+=256){
    int e = idx>>8, u = idx&255;
    float v = 0.f;
    if (u < 254) v = silu_(ws[OFF_A + sdst[e]*256 + u] + ws[OFF_B + ssrc[e]*256 + u]
                           + ws[OFF_WR + u]*srel[e][3]);
    eh[e][u] = v;
  }
  for (int idx=tid; idx<EB*4; idx+=256){ eh[idx>>2][256+(idx&3)] = 0.f; }
  __syncthreads();
  int eg = tid&7, ug = tid>>3;
  {
    int u0 = 2*ug, u1 = 2*ug+1;
    const float4* w0 = (const float4*)(ws+OFF_W2P + u0*256);
    const float4* w1 = (const float4*)(ws+OFF_W2P + u1*256);
    float4 a0=Z4,a1=Z4,a2=Z4,a3=Z4,b0=Z4,b1=Z4,b2=Z4,b3=Z4;
    for (int jj=0;jj<64;jj++){
      float4 wv0=w0[jj], wv1=w1[jj];
      float4 x0 = *(const float4*)&eh[eg   ][jj*4];
      float4 x1 = *(const float4*)&eh[eg+ 8][jj*4];
      float4 x2 = *(const float4*)&eh[eg+16][jj*4];
      float4 x3 = *(const float4*)&eh[eg+24][jj*4];
      FMA4(a0,x0,wv0) FMA4(a1,x1,wv0) FMA4(a2,x2,wv0) FMA4(a3,x3,wv0)
      FMA4(b0,x0,wv1) FMA4(b1,x1,wv1) FMA4(b2,x2,wv1) FMA4(b3,x3,wv1)
    }
    float va[4]={hsum4(a0),hsum4(a1),hsum4(a2),hsum4(a3)};
    float vb[4]={hsum4(b0),hsum4(b1),hsum4(b2),hsum4(b3)};
    float bv0 = e2b[u0];
    #pragma unroll
    for (int i=0;i<4;i++){
      int e = eg + 8*i;
      float v = silu_(bv0 + va[i]);
      mij[e][u0] = v; ws[OFF_EDGE + (e0b+e)*68 + u0] = v;
      if (u1 < 63){
        float v1 = silu_(e2b[u1] + vb[i]);
        mij[e][u1] = v1; ws[OFF_EDGE + (e0b+e)*68 + u1] = v1;
      }
    }
  }
  __syncthreads();
  for (int uc=0; uc<4; uc++){
    int u0 = uc*64 + 2*ug, u1 = u0+1;
    const float4* w0 = (const float4*)(ws+OFF_C1P + u0*64);
    const float4* w1 = (const float4*)(ws+OFF_C1P + u1*64);
    float4 a0=Z4,a1=Z4,a2=Z4,a3=Z4,b0=Z4,b1=Z4,b2=Z4,b3=Z4;
    for (int jj=0;jj<16;jj++){
      float4 wv0=w0[jj], wv1=w1[jj];
      float4 x0 = *(const float4*)&mij[eg   ][jj*4];
      float4 x1 = *(const float4*)&mij[eg+ 8][jj*4];
      float4 x2 = *(const float4*)&mij[eg+16][jj*4];
      float4 x3 = *(const float4*)&mij[eg+24][jj*4];
      FMA4(a0,x0,wv0) FMA4(a1,x1,wv0) FMA4(a2,x2,wv0) FMA4(a3,x3,wv0)
      FMA4(b0,x0,wv1) FMA4(b1,x1,wv1) FMA4(b2,x2,wv1) FMA4(b3,x3,wv1)
    }
    float va[4]={hsum4(a0),hsum4(a1),hsum4(a2),hsum4(a3)};
    float vb[4]={hsum4(b0),hsum4(b1),hsum4(b2),hsum4(b3)};
    #pragma unroll
    for (int i=0;i<4;i++){
      int e = eg + 8*i;
      if (u0 < 252) eh[e][u0] = silu_(c1b[u0] + va[i]);
      if (u1 < 252) eh[e][u1] = silu_(c1b[u1] + vb[i]);
    }
  }
  __syncthreads();
  {
    int e = tid>>3, q = tid&7;
    const float4* xr = (const float4*)&eh[e][0];
    const float4* wr4 = (const float4*)c2w;
    float4 a = Z4;
    for (int jj=q; jj<63; jj+=8){ float4 xv=xr[jj], wv=wr4[jj]; FMA4(a,xv,wv) }
    float s = hsum4(a);
    s += __shfl_down(s,4,64); s += __shfl_down(s,2,64); s += __shfl_down(s,1,64);
    if (q == 0){
      float cw = s + c2b[0];
      #pragma unroll
      for (int k=0;k<3;k++) ws[OFF_EDGE + (e0b+e)*68 + 64 + k] = cw*srel[e][k];
    }
  }
}

// ---- node MLP (float4, padded weights) + gathers -> smi_pre ----
#define NNB 8
__global__ __launch_bounds__(256) void k_node(
    const float* __restrict__ mnc,
    const float* __restrict__ n1b, const float* __restrict__ n2b,
    float* __restrict__ ws, const int* __restrict__ iw)
{
  __shared__ float xin[NNB][132];
  __shared__ float t1 [NNB][132];
  int tid = threadIdx.x;
  int n0 = blockIdx.x*NNB;
  for (int idx=tid; idx<NNB*128; idx+=256){
    int e = idx>>7, j = idx&127;
    int node = n0 + e;
    float v = 0.f;
    if (j < 63) v = mnc[node*ID + 3 + j];
    else if (j < 126){
      int u = j - 63;
      int cnt = iw[IOFF_ECNT+node]; if (cnt > ECAP) cnt = ECAP;
      for (int q=0;q<cnt;q++) v += ws[OFF_EDGE + iw[IOFF_ELIST+node*ECAP+q]*68 + u];
    }
    xin[e][j] = v;
    t1[e][j] = 0.f;
  }
  __syncthreads();
  {
    int ng = tid&3, ug = tid>>2;
    int u0 = 2*ug, u1 = u0+1;
    const float4* w0 = (const float4*)(ws+OFF_N1P + u0*128);
    const float4* w1 = (const float4*)(ws+OFF_N1P + u1*128);
    float4 a0=Z4,a1=Z4,b0=Z4,b1=Z4;
    for (int jj=0;jj<32;jj++){
      float4 wv0=w0[jj], wv1=w1[jj];
      float4 x0 = *(const float4*)&xin[ng  ][jj*4];
      float4 x1 = *(const float4*)&xin[ng+4][jj*4];
      FMA4(a0,x0,wv0) FMA4(a1,x1,wv0)
      FMA4(b0,x0,wv1) FMA4(b1,x1,wv1)
    }
    if (u0 < 126){ float bv=n1b[u0]; t1[ng][u0]=silu_(bv+hsum4(a0)); t1[ng+4][u0]=silu_(bv+hsum4(a1)); }
    if (u1 < 126){ float bv=n1b[u1]; t1[ng][u1]=silu_(bv+hsum4(b0)); t1[ng+4][u1]=silu_(bv+hsum4(b1)); }
  }
  __syncthreads();
  {
    int ng = tid&7, ug = tid>>3;
    int u0 = 2*ug, u1 = u0+1;
    const float4* w0 = (const float4*)(ws+OFF_N2P + u0*128);
    const float4* w1 = (const float4*)(ws+OFF_N2P + u1*128);
    float4 a0=Z4,b0=Z4;
    if (u0 < 63){
      for (int jj=0;jj<32;jj++){
        float4 x0 = *(const float4*)&t1[ng][jj*4];
        FMA4(a0,x0,w0[jj]) FMA4(b0,x0,w1[jj])
      }
      int node = n0 + ng;
      ws[OFF_SMIP + node*ID + 3 + u0] = nan0(xin[ng][u0] + n2b[u0] + hsum4(a0));
      if (u1 < 63)
        ws[OFF_SMIP + node*ID + 3 + u1] = nan0(xin[ng][u1] + n2b[u1] + hsum4(b0));
    }
  }
  if (tid < NNB*3){
    int e = tid/3, k = tid%3;
    int node = n0 + e;
    int cnt = iw[IOFF_ECNT+node]; if (cnt > ECAP) cnt = ECAP;
    float s = mnc[node*ID + k];
    for (int q=0;q<cnt;q++) s += ws[OFF_EDGE + iw[IOFF_ELIST+node*ECAP+q]*68 + 64 + k];
    ws[OFF_SMIP + node*ID + k] = nan0(s);
  }
}

// ---- batchnorm ----
__global__ __launch_bounds__(256) void k_bn_stats(float* __restrict__ ws){
  __shared__ float scr[8];
  int j = blockIdx.x, tid = threadIdx.x;
  float s=0.f, ss=0.f;
  for (int i=tid; i<NN; i+=256){ float x = ws[OFF_SMIP + i*ID + j]; s+=x; ss+=x*x; }
  for (int o=32;o>0;o>>=1){ s += __shfl_down(s,o,64); ss += __shfl_down(ss,o,64); }
  int w = tid>>6;
  if ((tid&63)==0){ scr[w]=s; scr[4+w]=ss; }
  __syncthreads();
  if (tid==0){
    float S=0,SS=0;
    for (int q=0;q<4;q++){S+=scr[q];SS+=scr[4+q];}
    float mean = S/NN;
    float var  = SS/NN - mean*mean;
    ws[OFF_STATS + j]      = mean;
    ws[OFF_STATS + 66 + j] = 1.0f/sqrtf(var + 1e-5f);
  }
}
__global__ void k_bn_apply(const float* __restrict__ bng, const float* __restrict__ bnb,
                           float* __restrict__ ws){
  int idx = blockIdx.x*256 + threadIdx.x;
  if (idx < NN*ID){
    int j = idx % ID;
    ws[OFF_OUT + idx] = bng[j]*(ws[OFF_SMIP+idx]-ws[OFF_STATS+j])*ws[OFF_STATS+66+j] + bnb[j];
  }
}

// ---- T[n][t*66+o] = sum_i h[n,i]*Qaug[i,t,o] ----
__global__ __launch_bounds__(256) void k_tbuild(float* __restrict__ ws){
  __shared__ float xs[16][68];
  int tid = threadIdx.x;
  int n0 = blockIdx.x*16;
  for (int idx=tid; idx<16*68; idx+=256){ int n=idx/68, j=idx%68;
    xs[n][j] = (j<66)? ws[OFF_OUT + (n0+n)*ID + j] : 0.f; }
  __syncthreads();
  for (int pass=0; pass<3; pass++){
    int to = pass*256 + tid;
    if (to < 726){
      float acc[16];
      #pragma unroll
      for (int n=0;n<16;n++) acc[n] = 0.f;
      const float4* qp = (const float4*)(ws + OFF_QAUG + to*68);
      for (int jj=0;jj<17;jj++){
        float4 w = qp[jj];
        #pragma unroll
        for (int n=0;n<16;n++){
          float4 x = *(const float4*)&xs[n][jj*4];
          acc[n] += x.x*w.x + x.y*w.y + x.z*w.z + x.w*w.w;
        }
      }
      #pragma unroll
      for (int n=0;n<16;n++) ws[OFF_T + (n0+n)*726 + to] = acc[n];
    }
  }
}

// ---- m = relu(gathered_msg/deg + h@root + nn_bias) ----
#define MNB 8
__global__ __launch_bounds__(256) void k_mnode(
    const float* __restrict__ root, const float* __restrict__ nnbias,
    const int* __restrict__ eidx, const float* __restrict__ ea,
    float* __restrict__ ws, const int* __restrict__ iw)
{
  __shared__ float rs[66][68];
  __shared__ float xo[MNB][68];
  int tid = threadIdx.x;
  int n0 = blockIdx.x*MNB;
  for (int idx=tid; idx<66*66; idx+=256) rs[idx/66][idx%66] = root[idx];
  for (int idx=tid; idx<MNB*66; idx+=256) xo[idx/66][idx%66] = ws[OFF_OUT + n0*ID + idx];
  __syncthreads();
  for (int idx=tid; idx<MNB*66; idx+=256){
    int n = idx/66, o = idx%66;
    int node = n0 + n;
    int rawcnt = iw[IOFF_ECNT+node];
    int cnt = rawcnt > ECAP ? ECAP : rawcnt;
    float magg = 0.f;
    for (int q=0;q<cnt;q++){
      int e = iw[IOFF_ELIST + node*ECAP + q];
      int s = eidx[e];
      const float* Tp = ws + OFF_T + s*726 + o;
      const float* eap = ea + e*10;
      float av = Tp[660];
      #pragma unroll
      for (int t=0;t<10;t++) av += eap[t]*Tp[t*66];
      magg += av;
    }
    float deg = fmaxf((float)rawcnt, 1.0f);
    float s2 = nnbias[o] + magg/deg;
    for (int j=0;j<66;j++) s2 += xo[n][j]*rs[j][o];
    s2 = fmaxf(s2, 0.0f);
    ws[OFF_M  + node*ID  + o] = s2;
    ws[OFF_CM + node*132 + o] = s2;
  }
}

// ---- fused sparse conv ----
__global__ __launch_bounds__(256) void k_spconv(
    const float* __restrict__ cv1b, const float* __restrict__ cv2w,
    const float* __restrict__ cv2b,
    int it, float* __restrict__ ws, const int* __restrict__ iw)
{
  __shared__ float mid[DD][68];
  __shared__ float mps[32][68];
  __shared__ float w1s[32][192];
  __shared__ float vv[32];
  __shared__ float w2s[204];
  __shared__ float part[4][64];
  int tid = threadIdx.x;
  int a = blockIdx.x;
  for (int idx=tid; idx<DD*68; idx+=256) (&mid[0][0])[idx] = 0.f;
  if (tid < 198) w2s[tid] = cv2w[it*198 + tid];
  int nnz = iw[IOFF_CNT + a]; if (nnz > CAP) nnz = CAP;
  __syncthreads();
  for (int q0=0; q0<nnz; q0+=32){
    int qn = nnz - q0; if (qn > 32) qn = 32;
    for (int idx=tid; idx<qn*68; idx+=256){
      int q=idx/68, cc=idx%68;
      int b = iw[IOFF_CIDX + a*CAP + q0 + q];
      mps[q][cc] = (cc>=1 && cc<=66)? ws[OFF_M + b*ID + cc-1] : 0.f;
    }
    for (int idx=tid; idx<qn*192; idx+=256){
      int q=idx/192, r=idx%192;
      int b = iw[IOFF_CIDX + a*CAP + q0 + q];
      w1s[q][r] = ws[OFF_C1R + (it*1024+b)*192 + r];
    }
    if (tid < qn) vv[tid] = ws[OFF_CVAL + a*CAP + q0 + tid];
    __syncthreads();
    for (int idx=tid; idx<DD*ID; idx+=256){
      int o = idx/ID, cc = idx%ID;
      float acc = mid[o][cc];
      for (int q=0;q<qn;q++){
        acc += vv[q]*(w1s[q][o*3]*mps[q][cc] + w1s[q][o*3+1]*mps[q][cc+1] + w1s[q][o*3+2]*mps[q][cc+2]);
      }
      mid[o][cc] = acc;
    }
    __syncthreads();
  }
  for (int idx=tid; idx<DD*ID; idx+=256){ int o=idx/ID, cc=idx%ID; mid[o][cc] += cv1b[it*DD+o]; }
  __syncthreads();
  {
    int x = tid & 63, qq = tid >> 6;
    int c0 = qq*17, cN = c0+17; if (cN > ID) cN = ID;
    float s = 0.f;
    for (int cc=c0; cc<cN; cc++){
      #pragma unroll
      for (int k=0;k<3;k++){
        int oo = x + k - 1;
        if (oo >= 0 && oo < DD) s += mid[oo][cc]*w2s[cc*3+k];
      }
    }
    part[qq][x] = s;
  }
  __syncthreads();
  if (tid < DD)
    ws[OFF_CM + a*132 + ID + tid] = part[0][tid]+part[1][tid]+part[2][tid]+part[3][tid] + cv2b[it];
}

// ---- gate score + per-mol segment softmax -> av[node] ----
__global__ __launch_bounds__(64) void k_af(
    const int* __restrict__ mb,
    const float* __restrict__ lfw, const float* __restrict__ lfb,
    float* __restrict__ ws)
{
  __shared__ int memb[MAXM]; __shared__ int lcnt;
  int tid = threadIdx.x, m = blockIdx.x;
  if (tid==0) lcnt = 0;
  __syncthreads();
  for (int i=tid; i<NN; i+=64)
    if (mb[i]==m){ int p = atomicAdd(&lcnt,1); if (p<MAXM) memb[p]=i; }
  __syncthreads();
  int M = lcnt; if (M > MAXM) M = MAXM;
  float x = -INFINITY;
  if (tid < M){
    const float4* cr = (const float4*)(ws + OFF_CM + memb[tid]*132);
    const float4* lw = (const float4*)lfw;
    float4 a = Z4;
    for (int jj=0;jj<32;jj++){ float4 cv=cr[jj], wv=lw[jj]; FMA4(a,cv,wv) }
    const float* crow = ws + OFF_CM + memb[tid]*132;
    float s = hsum4(a) + crow[128]*lfw[128] + crow[129]*lfw[129] + lfb[0];
    x = (s > 0.f) ? s : 0.01f*s;
  }
  float mx = x;
  for (int o=32;o>0;o>>=1) mx = fmaxf(mx, __shfl_xor(mx,o,64));
  float ex = (tid<M) ? expf(x-mx) : 0.f;
  float sm = ex;
  for (int o=32;o>0;o>>=1) sm += __shfl_xor(sm,o,64);
  if (tid<M) ws[OFF_AV + memb[tid]] = ex/(sm + 1e-16f);
}

// ---- GRU gate GEMM + blend, node-parallel (4 nodes/block, 256 blocks) ----
// #pragma unroll 4 on K-loops: full unroll (33x) made hipcc hoist all weight
// loads -> VGPR 256 + scratch spill (R8 counters: 37MB FETCH/61MB WRITE).
__global__ __launch_bounds__(256) void k_grug(
    const float* __restrict__ bih, const float* __restrict__ bhh,
    float* __restrict__ ws)
{
  __shared__ float xs[GNB][132];   // av*cm (130 data, pad 0)
  __shared__ float hs[GNB][68];    // h (66 data, pad 0)
  __shared__ float ggg[GNB][132];  // r,z
  __shared__ float g1[GNB][68], g2[GNB][68];
  int tid = threadIdx.x;
  int n0 = blockIdx.x*GNB;
  for (int idx=tid; idx<GNB*132; idx+=256){
    int n = idx/132, j = idx%132;
    xs[n][j] = (j<130)? ws[OFF_AV + n0 + n] * ws[OFF_CM + (n0+n)*132 + j] : 0.f;
  }
  for (int idx=tid; idx<GNB*68; idx+=256){
    int n = idx/68, j = idx%68;
    hs[n][j] = (j<66)? ws[OFF_OUT + (n0+n)*ID + j] : 0.f;
  }
  __syncthreads();
  if (tid < 198){
    int u = tid;
    const float4* w1 = (const float4*)(ws+OFF_GIH + u*132);
    const float4* w2 = (const float4*)(ws+OFF_GHH + u*68);
    float4 a0=Z4,a1=Z4,a2=Z4,a3=Z4;
    #pragma unroll 4
    for (int jj=0;jj<33;jj++){
      float4 w = w1[jj];
      FMA4(a0,*(const float4*)&xs[0][jj*4],w)
      FMA4(a1,*(const float4*)&xs[1][jj*4],w)
      FMA4(a2,*(const float4*)&xs[2][jj*4],w)
      FMA4(a3,*(const float4*)&xs[3][jj*4],w)
    }
    float4 b0=Z4,b1=Z4,b2=Z4,b3=Z4;
    #pragma unroll 4
    for (int jj=0;jj<17;jj++){
      float4 w = w2[jj];
      FMA4(b0,*(const float4*)&hs[0][jj*4],w)
      FMA4(b1,*(const float4*)&hs[1][jj*4],w)
      FMA4(b2,*(const float4*)&hs[2][jj*4],w)
      FMA4(b3,*(const float4*)&hs[3][jj*4],w)
    }
    float bv1 = bih[u], bv2 = bhh[u];
    float d1[4] = {hsum4(a0),hsum4(a1),hsum4(a2),hsum4(a3)};
    float d2[4] = {hsum4(b0),hsum4(b1),hsum4(b2),hsum4(b3)};
    #pragma unroll
    for (int n=0;n<4;n++){
      float v1 = bv1 + d1[n];
      float v2 = bv2 + d2[n];
      if (u < 132) ggg[n][u] = sgm(v1+v2);
      else { g1[n][u-132] = v1; g2[n][u-132] = v2; }
    }
  }
  __syncthreads();
  for (int idx=tid; idx<GNB*66; idx+=256){
    int n = idx/66, u = idx%66;
    float r = ggg[n][u], z = ggg[n][66+u];
    float nn_ = tanhf(g1[n][u] + r*g2[n][u]);
    ws[OFF_OUT + (n0+n)*ID + u] = (1.f - z)*nn_ + z*hs[n][u];
  }
}

// ---- Set2Set readout ----
__global__ __launch_bounds__(256) void k_s2s(
    const int* __restrict__ mb,
    const float* __restrict__ wih, const float* __restrict__ whh,
    const float* __restrict__ bih, const float* __restrict__ bhh,
    float* __restrict__ ws)
{
  __shared__ int memb[MAXM]; __shared__ int lcnt;
  __shared__ float orow[MAXM][68];
  __shared__ float hsv[66], csv[66], qsv[132], gv[264];
  __shared__ float av[MAXM];
  int tid = threadIdx.x, m = blockIdx.x;
  if (tid==0) lcnt = 0;
  __syncthreads();
  for (int i=tid; i<NN; i+=256)
    if (mb[i]==m){ int p = atomicAdd(&lcnt,1); if (p<MAXM) memb[p]=i; }
  __syncthreads();
  int M = lcnt; if (M > MAXM) M = MAXM;
  for (int idx=tid; idx<M*ID; idx+=256){ int i=idx/ID, j=idx%ID; orow[i][j]=ws[OFF_OUT+memb[i]*ID+j]; }
  if (tid < 66){ hsv[tid]=0.f; csv[tid]=0.f; }
  if (tid < 132) qsv[tid]=0.f;
  __syncthreads();
  for (int step=0; step<3; step++){
    for (int u=tid; u<264; u+=256){
      float s = bih[u] + bhh[u];
      const float* w1 = wih + u*132;
      for (int j=0;j<132;j++) s += qsv[j]*w1[j];
      const float* w2 = whh + u*ID;
      for (int j=0;j<ID;j++) s += hsv[j]*w2[j];
      gv[u] = s;
    }
    __syncthreads();
    if (tid < 66){
      float ig=gv[tid], fg=gv[66+tid], gg_=gv[132+tid], og=gv[198+tid];
      float c = sgm(fg)*csv[tid] + sgm(ig)*tanhf(gg_);
      csv[tid] = c;
      hsv[tid] = sgm(og)*tanhf(c);
    }
    __syncthreads();
    if (tid < 64){
      float e = -INFINITY;
      if (tid < M){ e = 0.f; for (int j=0;j<ID;j++) e += orow[tid][j]*hsv[j]; }
      float mx = e;
      for (int o=32;o>0;o>>=1) mx = fmaxf(mx, __shfl_xor(mx,o,64));
      float ex = (tid<M) ? expf(e-mx) : 0.f;
      float sm = ex;
      for (int o=32;o>0;o>>=1) sm += __shfl_xor(sm,o,64);
      if (tid<M) av[tid] = ex/(sm + 1e-16f);
    }
    __syncthreads();
    if (tid < 66){
      float r = 0.f;
      for (int i=0;i<M;i++) r += av[i]*orow[i][tid];
      qsv[tid]      = hsv[tid];
      qsv[66+tid]   = r;
    }
    __syncthreads();
  }
  if (tid < 132) ws[OFF_QSTAR + m*132 + tid] = qsv[tid];
}

// ---- fingers MLP ----
__global__ __launch_bounds__(256) void k_fd1(
    const float* __restrict__ fing, const float* __restrict__ d1w, const float* __restrict__ d1b,
    float* __restrict__ ws)
{
  __shared__ __align__(16) float fin[1024];
  int tid = threadIdx.x;
  int b = blockIdx.x >> 4, u0 = (blockIdx.x & 15)*32;
  for (int j=tid; j<1024; j+=256) fin[j] = fing[b*1024+j];
  __syncthreads();
  int u = u0 + (tid>>3), q = tid & 7;
  const float4* w4 = (const float4*)(d1w + u*1024);
  const float4* x4 = (const float4*)fin;
  float4 a = Z4;
  for (int jj=q; jj<256; jj+=8){ float4 wv=w4[jj], xv=x4[jj]; FMA4(a,xv,wv) }
  float s = hsum4(a);
  s += __shfl_xor(s,1,64); s += __shfl_xor(s,2,64); s += __shfl_xor(s,4,64);
  if (q==0) ws[OFF_F1 + b*512 + u] = fmaxf(s + d1b[u], 0.f);
}
__global__ __launch_bounds__(256) void k_fd2(
    const float* __restrict__ d2w, const float* __restrict__ d2b, float* __restrict__ ws)
{
  __shared__ __align__(16) float f1[512];
  int tid = threadIdx.x;
  int b = blockIdx.x >> 3, u0 = (blockIdx.x & 7)*32;
  for (int j=tid; j<512; j+=256) f1[j] = ws[OFF_F1 + b*512 + j];
  __syncthreads();
  int u = u0 + (tid>>3), q = tid & 7;
  const float4* w4 = (const float4*)(d2w + u*512);
  const float4* x4 = (const float4*)f1;
  float4 a = Z4;
  for (int jj=q; jj<128; jj+=8){ float4 wv=w4[jj], xv=x4[jj]; FMA4(a,xv,wv) }
  float s = hsum4(a);
  s += __shfl_xor(s,1,64); s += __shfl_xor(s,2,64); s += __shfl_xor(s,4,64);
  if (q==0) ws[OFF_F2 + b*256 + u] = fmaxf(s + d2b[u], 0.f);
}
__global__ __launch_bounds__(256) void k_fd3p(
    const float* __restrict__ d3w, const float* __restrict__ d3b,
    const float* __restrict__ pw,  const float* __restrict__ pb,
    const float* __restrict__ ws,  float* __restrict__ outp)
{
  __shared__ __align__(16) float f2[256];
  __shared__ float f3[64];
  int tid = threadIdx.x, b = blockIdx.x;
  for (int j=tid; j<256; j+=256) f2[j] = ws[OFF_F2 + b*256 + j];
  __syncthreads();
  {
    int u = tid>>2, q = tid&3;
    const float4* w4 = (const float4*)(d3w + u*256);
    const float4* x4 = (const float4*)f2;
    float4 a = Z4;
    for (int jj=q; jj<64; jj+=4){ float4 wv=w4[jj], xv=x4[jj]; FMA4(a,xv,wv) }
    float s = hsum4(a);
    s += __shfl_xor(s,1,64); s += __shfl_xor(s,2,64);
    if (q==0) f3[u] = s + d3b[u];
  }
  __syncthreads();
  if (tid < 64){
    float s = 0.f;
    for (int j=tid; j<132; j+=64) s += ws[OFF_QSTAR + b*132 + j]*pw[j];
    s += f3[tid]*pw[132 + tid];
    for (int o=32;o>0;o>>=1) s += __shfl_xor(s,o,64);
    if (tid==0) outp[b] = s + pb[0];
  }
}

extern "C" void kernel_launch(void* const* d_in, const int* in_sizes, int n_in,
                              void* d_out, int out_size, void* d_ws, size_t ws_size,
                              hipStream_t stream)
{
  const float* mnc = (const float*)d_in[0];
  const float* ea  = (const float*)d_in[1];
  const float* fing= (const float*)d_in[2];
  const int*   eidx= (const int*)d_in[3];
  const int*   mb  = (const int*)d_in[4];
  const float* adj = (const float*)d_in[5];
  const float* e1w=(const float*)d_in[6],  *e1b=(const float*)d_in[7];
  const float* e2w=(const float*)d_in[8],  *e2b=(const float*)d_in[9];
  const float* c1w=(const float*)d_in[10], *c1b=(const float*)d_in[11];
  const float* c2w=(const float*)d_in[12], *c2b=(const float*)d_in[13];
  const float* n1w=(const float*)d_in[14], *n1b=(const float*)d_in[15];
  const float* n2w=(const float*)d_in[16], *n2b=(const float*)d_in[17];
  const float* bng=(const float*)d_in[18], *bnb=(const float*)d_in[19];
  const float* nnw=(const float*)d_in[20], *nnb=(const float*)d_in[21];
  const float* root=(const float*)d_in[22],*nnbias=(const float*)d_in[23];
  const float* cv1w=(const float*)d_in[24],*cv1b=(const float*)d_in[25];
  const float* cv2w=(const float*)d_in[26],*cv2b=(const float*)d_in[27];
  const float* lfw=(const float*)d_in[28], *lfb=(const float*)d_in[29];
  const float* gwih=(const float*)d_in[30],*gwhh=(const float*)d_in[31];
  const float* gbih=(const float*)d_in[32],*gbhh=(const float*)d_in[33];
  const float* lwih=(const float*)d_in[34],*lwhh=(const float*)d_in[35];
  const float* lbih=(const float*)d_in[36],*lbhh=(const float*)d_in[37];
  const float* d1w=(const float*)d_in[38], *d1b=(const float*)d_in[39];
  const float* d2w=(const float*)d_in[40], *d2b=(const float*)d_in[41];
  const float* d3w=(const float*)d_in[42], *d3b=(const float*)d_in[43];
  const float* pw =(const float*)d_in[44], *pb =(const float*)d_in[45];
  float* ws = (float*)d_ws;
  int*   iw = (int*)(ws + OFF_FEND);
  float* outp = (float*)d_out;

  const long long setup_total = (long long)NN*NN + EE + 16384 + 16384 + 16384
                              + 726*68 + 3*1024*192 + 198*132 + 198*68
                              + 126*128 + 63*128;
  int setup_blocks = (int)((setup_total + 255)/256);

  k_zero0    <<<4, 256, 0, stream>>>(iw);
  k_setup    <<<setup_blocks, 256, 0, stream>>>(adj, eidx, e1w, e2w, c1w, nnw, nnb, cv1w, gwih, gwhh, n1w, n2w, ws, iw);
  k_ab       <<<NN/32, 256, 0, stream>>>(mnc, e1b, ws);
  k_edge     <<<EE/EB, 256, 0, stream>>>(mnc, eidx, e2b, c1b, c2w, c2b, ws);
  k_node     <<<NN/NNB, 256, 0, stream>>>(mnc, n1b, n2b, ws, iw);
  k_bn_stats <<<ID, 256, 0, stream>>>(ws);
  k_bn_apply <<<(NN*ID+255)/256, 256, 0, stream>>>(bng, bnb, ws);
  for (int it=0; it<3; ++it){
    k_tbuild <<<NN/16, 256, 0, stream>>>(ws);
    k_mnode  <<<NN/MNB, 256, 0, stream>>>(root, nnbias, eidx, ea, ws, iw);
    k_spconv <<<NN, 256, 0, stream>>>(cv1b, cv2w, cv2b, it, ws, iw);
    k_af     <<<BB, 64, 0, stream>>>(mb, lfw, lfb, ws);
    k_grug   <<<NN/GNB, 256, 0, stream>>>(gbih, gbhh, ws);
  }
  k_s2s      <<<BB, 256, 0, stream>>>(mb, lwih, lwhh, lbih, lbhh, ws);
  k_fd1      <<<BB*16, 256, 0, stream>>>(fing, d1w, d1b, ws);
  k_fd2      <<<BB*8, 256, 0, stream>>>(d2w, d2b, ws);
  k_fd3p     <<<BB, 256, 0, stream>>>(d3w, d3b, pw, pb, ws, outp);
}

// Round 10
// 562.216 us; speedup vs baseline: 2.1640x; 1.1717x over previous
//
#include <hip/hip_runtime.h>
#include <math.h>

// Problem constants (fixed by the reference)
#define NN 1024   // nodes
#define BB 32     // mols
#define EE 8192   // edges
#define DD 64     // DIM
#define ID 66     // IN_DIM
#define FT 63     // feats dim
#define CAP 128   // max nnz per adj column
#define ECAP 64   // max in-edges per node
#define MAXM 64   // max nodes per mol (s2s)
#define GNB 4     // nodes per block in gru gate gemm

// ---- workspace layout (float offsets) ----
enum : int {
  OFF_SMIP  = 0,                        // N*66 pre-BN smi
  OFF_OUT   = OFF_SMIP + NN*ID,         // N*66 h
  OFF_STATS = OFF_OUT + NN*ID,          // 144 mean/rstd
  OFF_M     = OFF_STATS + 144,          // N*66 m buffer
  OFF_CM    = OFF_M + NN*ID,            // N*132 cm
  OFF_QSTAR = OFF_CM + NN*132,          // 32*132
  OFF_CVAL  = OFF_QSTAR + BB*132,       // N*CAP csc values
  OFF_A     = OFF_CVAL + NN*CAP,        // 1024*256 A = feats@W1a^T + e1b
  OFF_B     = OFF_A + 1024*256,         // 1024*256 B = feats@W1b^T
  OFF_EDGE  = OFF_B + 1024*256,         // 8192*68: [0..62]=mij, [64..66]=cw*rel
  OFF_T     = OFF_EDGE + EE*68,         // 1024*726 T[n][t*66+o]
  OFF_QAUG  = OFF_T + NN*726,           // 726*68 Qaug[(t*66+o)][i]
  OFF_W1A   = OFF_QAUG + 726*68,        // 256*64
  OFF_W1B   = OFF_W1A + 16384,          // 256*64
  OFF_WR    = OFF_W1B + 16384,          // 256
  OFF_W2P   = OFF_WR + 256,             // 64*256 padded e2w
  OFF_C1P   = OFF_W2P + 16384,          // 256*64 padded c1w
  OFF_C1R   = OFF_C1P + 16384,          // 3*1024*192 conv1_w reorg
  OFF_GIH   = OFF_C1R + 3*1024*192,     // 198*132
  OFF_GHH   = OFF_GIH + 198*132,        // 198*68
  OFF_F1    = OFF_GHH + 198*68,         // 32*512
  OFF_F2    = OFF_F1 + BB*512,          // 32*256
  OFF_AV    = OFF_F2 + BB*256,          // N  softmax gate per node
  OFF_N1P   = OFF_AV + NN,              // 126*128 padded n1w
  OFF_N2P   = OFF_N1P + 126*128,        // 63*128  padded n2w
  OFF_FEND  = OFF_N2P + 63*128
};
enum : int {  // int region at ws + OFF_FEND
  IOFF_CNT   = 0,                 // N   csc col counts
  IOFF_CIDX  = NN,                // N*CAP
  IOFF_ECNT  = NN + NN*CAP,       // N   in-degree
  IOFF_ELIST = NN + NN*CAP + NN,  // N*ECAP edge ids sorted by dst
  IOFF_END   = NN + NN*CAP + NN + NN*ECAP
};

__device__ __forceinline__ float sgm(float x){ return 1.0f/(1.0f+expf(-x)); }
__device__ __forceinline__ float silu_(float x){ return x/(1.0f+expf(-x)); }
__device__ __forceinline__ float nan0(float v){ return (v!=v) ? 0.0f : v; }
__device__ __forceinline__ float hsum4(float4 v){ return v.x+v.y+v.z+v.w; }
#define FMA4(A,X,W) {A.x += (X).x*(W).x; A.y += (X).y*(W).y; A.z += (X).z*(W).z; A.w += (X).w*(W).w;}
#define Z4 {0.f,0.f,0.f,0.f}

// ---- zero the atomic counters ----
__global__ void k_zero0(int* __restrict__ iw){
  int i = blockIdx.x*256 + threadIdx.x;
  if (i < NN){ iw[IOFF_CNT + i] = 0; iw[IOFF_ECNT + i] = 0; }
}

// ---- one-shot setup: csc(adj), edge sort by dst, weight reorg/pad ----
__global__ void k_setup(const float* __restrict__ adj, const int* __restrict__ eidx,
                        const float* __restrict__ e1w, const float* __restrict__ e2w,
                        const float* __restrict__ c1w,
                        const float* __restrict__ nnw, const float* __restrict__ nnb,
                        const float* __restrict__ cv1w,
                        const float* __restrict__ gwih, const float* __restrict__ gwhh,
                        const float* __restrict__ n1w, const float* __restrict__ n2w,
                        float* __restrict__ ws, int* __restrict__ iw){
  long long idx = (long long)blockIdx.x*256 + threadIdx.x;
  if (idx < (long long)NN*NN){
    float v = adj[idx];
    if (v != 0.0f){
      int a = (int)(idx & 1023), b = (int)(idx >> 10);
      int p = atomicAdd(iw + IOFF_CNT + a, 1);
      if (p < CAP){ iw[IOFF_CIDX + a*CAP + p] = b; ws[OFF_CVAL + a*CAP + p] = v; }
    }
    return;
  }
  idx -= (long long)NN*NN;
  if (idx < EE){
    int e = (int)idx, d = eidx[EE + e];
    int p = atomicAdd(iw + IOFF_ECNT + d, 1);
    if (p < ECAP) iw[IOFF_ELIST + d*ECAP + p] = e;
    return;
  }
  idx -= EE;
  if (idx < 16384){ int u=(int)idx>>6, j=(int)idx&63;
    ws[OFF_W1A+idx] = (u<254 && j<63)? e1w[u*127+j]      : 0.f;
    ws[OFF_W1B+idx] = (u<254 && j<63)? e1w[u*127+63+j]   : 0.f;
    if (j==0) ws[OFF_WR+u] = (u<254)? e1w[u*127+126] : 0.f;
    return; }
  idx -= 16384;
  if (idx < 16384){ int u=(int)idx>>8, j=(int)idx&255; ws[OFF_W2P+idx] = (u<63 && j<254)? e2w[u*254+j] : 0.f; return; }
  idx -= 16384;
  if (idx < 16384){ int u=(int)idx>>6, j=(int)idx&63; ws[OFF_C1P+idx] = (u<252 && j<63)? c1w[u*63+j] : 0.f; return; }
  idx -= 16384;
  if (idx < 726*68){ int to=(int)idx/68, i=(int)idx%68; int t=to/66, o=to%66;
    float v = 0.f;
    if (i < 66) v = (t<10)? nnw[(i*66+o)*10+t] : nnb[i*66+o];
    ws[OFF_QAUG+idx] = v; return; }
  idx -= 726*68;
  if (idx < 3*1024*192){ int it=(int)(idx/196608); int r=(int)(idx%196608); int b=r/192; int z=r%192; int o=z/3, k=z%3;
    ws[OFF_C1R+idx] = cv1w[((it*64+o)*1024+b)*3+k]; return; }
  idx -= 3*1024*192;
  if (idx < 198*132){ int u=(int)idx/132, j=(int)idx%132; ws[OFF_GIH+idx] = (j<130)? gwih[u*130+j] : 0.f; return; }
  idx -= 198*132;
  if (idx < 198*68){ int u=(int)idx/68, j=(int)idx%68; ws[OFF_GHH+idx] = (j<66)? gwhh[u*66+j] : 0.f; return; }
  idx -= 198*68;
  if (idx < 126*128){ int u=(int)idx>>7, j=(int)idx&127; ws[OFF_N1P+idx] = (j<126)? n1w[u*126+j] : 0.f; return; }
  idx -= 126*128;
  if (idx < 63*128){ int u=(int)idx>>7, j=(int)idx&127; ws[OFF_N2P+idx] = (j<126)? n2w[u*126+j] : 0.f; return; }
}

// ---- A/B build: 128 blocks = 32 node-tiles x 4 u-tiles ----
__global__ __launch_bounds__(256) void k_ab(const float* __restrict__ mnc,
                                            const float* __restrict__ e1b,
                                            float* __restrict__ ws){
  __shared__ float xf[32][68];
  int tid = threadIdx.x;
  int n0 = (blockIdx.x>>2)*32;
  int ut = blockIdx.x&3;
  for (int idx=tid; idx<32*64; idx+=256){ int n=idx>>6, j=idx&63;
    xf[n][j] = (j<63)? mnc[(n0+n)*ID + 3 + j] : 0.f; }
  __syncthreads();
  int eg = tid&7, ug = tid>>3;
  for (int pass=0; pass<2; pass++){
    int u = ut*64 + pass*32 + ug;
    const float4* wa = (const float4*)(ws + OFF_W1A + u*64);
    const float4* wb = (const float4*)(ws + OFF_W1B + u*64);
    float4 a0=Z4,a1=Z4,a2=Z4,a3=Z4,b0=Z4,b1=Z4,b2=Z4,b3=Z4;
    for (int jj=0;jj<16;jj++){
      float4 w1 = wa[jj], w2 = wb[jj];
      float4 x0 = *(const float4*)&xf[eg   ][jj*4];
      float4 x1 = *(const float4*)&xf[eg+ 8][jj*4];
      float4 x2 = *(const float4*)&xf[eg+16][jj*4];
      float4 x3 = *(const float4*)&xf[eg+24][jj*4];
      FMA4(a0,x0,w1) FMA4(a1,x1,w1) FMA4(a2,x2,w1) FMA4(a3,x3,w1)
      FMA4(b0,x0,w2) FMA4(b1,x1,w2) FMA4(b2,x2,w2) FMA4(b3,x3,w2)
    }
    if (u < 254){
      float bv = e1b[u];
      float va[4]={hsum4(a0),hsum4(a1),hsum4(a2),hsum4(a3)};
      float vb[4]={hsum4(b0),hsum4(b1),hsum4(b2),hsum4(b3)};
      #pragma unroll
      for (int i=0;i<4;i++){
        int n = n0 + eg + 8*i;
        ws[OFF_A + n*256 + u] = bv + va[i];
        ws[OFF_B + n*256 + u] = vb[i];
      }
    }
  }
}

// ---- per-edge chain: EB=8 -> 1024 blocks (R9: EB=32 gave 1 blk/CU, occ 10.6%) ----
#define EB 8
__global__ __launch_bounds__(256) void k_edge(
    const float* __restrict__ mnc, const int* __restrict__ eidx,
    const float* __restrict__ e2b, const float* __restrict__ c1b,
    const float* __restrict__ c2w, const float* __restrict__ c2b,
    float* __restrict__ ws)
{
  __shared__ float eh [EB][260];   // L1 out; later ch
  __shared__ float mij[EB][68];
  __shared__ float srel[EB][4];
  __shared__ int ssrc[EB], sdst[EB];
  int tid = threadIdx.x;
  int e0b = blockIdx.x*EB;
  if (tid < EB){
    int e = e0b + tid;
    int s = eidx[e], d = eidx[EE + e];
    ssrc[tid]=s; sdst[tid]=d;
    float rd = 0.f;
    #pragma unroll
    for (int k=0;k<3;k++){ float r = mnc[s*ID+k]-mnc[d*ID+k]; srel[tid][k]=r; rd += r*r; }
    srel[tid][3] = rd;
  }
  if (tid < EB*5) mij[tid/5][63+tid%5] = 0.f;
  __syncthreads();
  // L1: eh = silu(A[dst] + B[src] + wr*rd)
  for (int idx=tid; idx<EB*256; idx+=256){
    int e = idx>>8, u = idx&255;
    float v = 0.f;
    if (u < 254) v = silu_(ws[OFF_A + sdst[e]*256 + u] + ws[OFF_B + ssrc[e]*256 + u]
                           + ws[OFF_WR + u]*srel[e][3]);
    eh[e][u] = v;
  }
  __syncthreads();
  int ug = tid>>2, eg = tid&3;   // u = ug; edges eg, eg+4
  // L2: mij = silu(eh @ W2P^T + e2b), K=256
  {
    const float4* w0 = (const float4*)(ws+OFF_W2P + ug*256);
    float4 a0=Z4,a1=Z4;
    for (int jj=0;jj<64;jj++){
      float4 w = w0[jj];
      FMA4(a0, *(const float4*)&eh[eg  ][jj*4], w)
      FMA4(a1, *(const float4*)&eh[eg+4][jj*4], w)
    }
    if (ug < 63){
      float bv = e2b[ug];
      float v0 = silu_(bv + hsum4(a0));
      float v1 = silu_(bv + hsum4(a1));
      mij[eg  ][ug] = v0; ws[OFF_EDGE + (e0b+eg  )*68 + ug] = v0;
      mij[eg+4][ug] = v1; ws[OFF_EDGE + (e0b+eg+4)*68 + ug] = v1;
    }
  }
  __syncthreads();
  // L3: ch = silu(mij @ C1P^T + c1b) into eh; 4 u-passes, no inter-pass barrier
  for (int uc=0; uc<4; uc++){
    int u = uc*64 + ug;
    const float4* w0 = (const float4*)(ws+OFF_C1P + u*64);
    float4 a0=Z4,a1=Z4;
    for (int jj=0;jj<16;jj++){
      float4 w = w0[jj];
      FMA4(a0, *(const float4*)&mij[eg  ][jj*4], w)
      FMA4(a1, *(const float4*)&mij[eg+4][jj*4], w)
    }
    if (u < 252){
      float bv = c1b[u];
      eh[eg  ][u] = silu_(bv + hsum4(a0));
      eh[eg+4][u] = silu_(bv + hsum4(a1));
    }
  }
  __syncthreads();
  // L4: cw = ch·c2w + c2b; 32 lanes per edge
  {
    int e = tid>>5, q = tid&31;
    const float4* xr = (const float4*)&eh[e][0];
    const float4* wr4 = (const float4*)c2w;
    float4 a = Z4;
    for (int jj=q; jj<63; jj+=32){ float4 xv=xr[jj], wv=wr4[jj]; FMA4(a,xv,wv) }
    float s = hsum4(a);
    s += __shfl_down(s,16,32); s += __shfl_down(s,8,32);
    s += __shfl_down(s,4,32);  s += __shfl_down(s,2,32); s += __shfl_down(s,1,32);
    if (q == 0){
      float cw = s + c2b[0];
      #pragma unroll
      for (int k=0;k<3;k++) ws[OFF_EDGE + (e0b+e)*68 + 64 + k] = cw*srel[e][k];
    }
  }
}

// ---- node MLP (float4, padded weights) + gathers -> smi_pre ----
#define NNB 8
__global__ __launch_bounds__(256) void k_node(
    const float* __restrict__ mnc,
    const float* __restrict__ n1b, const float* __restrict__ n2b,
    float* __restrict__ ws, const int* __restrict__ iw)
{
  __shared__ float xin[NNB][132];
  __shared__ float t1 [NNB][132];
  int tid = threadIdx.x;
  int n0 = blockIdx.x*NNB;
  for (int idx=tid; idx<NNB*128; idx+=256){
    int e = idx>>7, j = idx&127;
    int node = n0 + e;
    float v = 0.f;
    if (j < 63) v = mnc[node*ID + 3 + j];
    else if (j < 126){
      int u = j - 63;
      int cnt = iw[IOFF_ECNT+node]; if (cnt > ECAP) cnt = ECAP;
      for (int q=0;q<cnt;q++) v += ws[OFF_EDGE + iw[IOFF_ELIST+node*ECAP+q]*68 + u];
    }
    xin[e][j] = v;
    t1[e][j] = 0.f;
  }
  __syncthreads();
  {
    int ng = tid&3, ug = tid>>2;
    int u0 = 2*ug, u1 = u0+1;
    const float4* w0 = (const float4*)(ws+OFF_N1P + u0*128);
    const float4* w1 = (const float4*)(ws+OFF_N1P + u1*128);
    float4 a0=Z4,a1=Z4,b0=Z4,b1=Z4;
    for (int jj=0;jj<32;jj++){
      float4 wv0=w0[jj], wv1=w1[jj];
      float4 x0 = *(const float4*)&xin[ng  ][jj*4];
      float4 x1 = *(const float4*)&xin[ng+4][jj*4];
      FMA4(a0,x0,wv0) FMA4(a1,x1,wv0)
      FMA4(b0,x0,wv1) FMA4(b1,x1,wv1)
    }
    if (u0 < 126){ float bv=n1b[u0]; t1[ng][u0]=silu_(bv+hsum4(a0)); t1[ng+4][u0]=silu_(bv+hsum4(a1)); }
    if (u1 < 126){ float bv=n1b[u1]; t1[ng][u1]=silu_(bv+hsum4(b0)); t1[ng+4][u1]=silu_(bv+hsum4(b1)); }
  }
  __syncthreads();
  {
    int ng = tid&7, ug = tid>>3;
    int u0 = 2*ug, u1 = u0+1;
    const float4* w0 = (const float4*)(ws+OFF_N2P + u0*128);
    const float4* w1 = (const float4*)(ws+OFF_N2P + u1*128);
    float4 a0=Z4,b0=Z4;
    if (u0 < 63){
      for (int jj=0;jj<32;jj++){
        float4 x0 = *(const float4*)&t1[ng][jj*4];
        FMA4(a0,x0,w0[jj]) FMA4(b0,x0,w1[jj])
      }
      int node = n0 + ng;
      ws[OFF_SMIP + node*ID + 3 + u0] = nan0(xin[ng][u0] + n2b[u0] + hsum4(a0));
      if (u1 < 63)
        ws[OFF_SMIP + node*ID + 3 + u1] = nan0(xin[ng][u1] + n2b[u1] + hsum4(b0));
    }
  }
  if (tid < NNB*3){
    int e = tid/3, k = tid%3;
    int node = n0 + e;
    int cnt = iw[IOFF_ECNT+node]; if (cnt > ECAP) cnt = ECAP;
    float s = mnc[node*ID + k];
    for (int q=0;q<cnt;q++) s += ws[OFF_EDGE + iw[IOFF_ELIST+node*ECAP+q]*68 + 64 + k];
    ws[OFF_SMIP + node*ID + k] = nan0(s);
  }
}

// ---- batchnorm ----
__global__ __launch_bounds__(256) void k_bn_stats(float* __restrict__ ws){
  __shared__ float scr[8];
  int j = blockIdx.x, tid = threadIdx.x;
  float s=0.f, ss=0.f;
  for (int i=tid; i<NN; i+=256){ float x = ws[OFF_SMIP + i*ID + j]; s+=x; ss+=x*x; }
  for (int o=32;o>0;o>>=1){ s += __shfl_down(s,o,64); ss += __shfl_down(ss,o,64); }
  int w = tid>>6;
  if ((tid&63)==0){ scr[w]=s; scr[4+w]=ss; }
  __syncthreads();
  if (tid==0){
    float S=0,SS=0;
    for (int q=0;q<4;q++){S+=scr[q];SS+=scr[4+q];}
    float mean = S/NN;
    float var  = SS/NN - mean*mean;
    ws[OFF_STATS + j]      = mean;
    ws[OFF_STATS + 66 + j] = 1.0f/sqrtf(var + 1e-5f);
  }
}
__global__ void k_bn_apply(const float* __restrict__ bng, const float* __restrict__ bnb,
                           float* __restrict__ ws){
  int idx = blockIdx.x*256 + threadIdx.x;
  if (idx < NN*ID){
    int j = idx % ID;
    ws[OFF_OUT + idx] = bng[j]*(ws[OFF_SMIP+idx]-ws[OFF_STATS+j])*ws[OFF_STATS+66+j] + bnb[j];
  }
}

// ---- T[n][t*66+o] = sum_i h[n,i]*Qaug[i,t,o]; 192 blocks = 64 node-tiles x 3 passes ----
__global__ __launch_bounds__(256) void k_tbuild(float* __restrict__ ws){
  __shared__ float xs[16][68];
  int tid = threadIdx.x;
  int n0 = (blockIdx.x/3)*16;
  int pass = blockIdx.x%3;
  for (int idx=tid; idx<16*68; idx+=256){ int n=idx/68, j=idx%68;
    xs[n][j] = (j<66)? ws[OFF_OUT + (n0+n)*ID + j] : 0.f; }
  __syncthreads();
  int to = pass*256 + tid;
  if (to < 726){
    float acc[16];
    #pragma unroll
    for (int n=0;n<16;n++) acc[n] = 0.f;
    const float4* qp = (const float4*)(ws + OFF_QAUG + to*68);
    for (int jj=0;jj<17;jj++){
      float4 w = qp[jj];
      #pragma unroll
      for (int n=0;n<16;n++){
        float4 x = *(const float4*)&xs[n][jj*4];
        acc[n] += x.x*w.x + x.y*w.y + x.z*w.z + x.w*w.w;
      }
    }
    #pragma unroll
    for (int n=0;n<16;n++) ws[OFF_T + (n0+n)*726 + to] = acc[n];
  }
}

// ---- m = relu(gathered_msg/deg + h@root + nn_bias); 256 blocks ----
#define MNB 4
__global__ __launch_bounds__(256) void k_mnode(
    const float* __restrict__ root, const float* __restrict__ nnbias,
    const int* __restrict__ eidx, const float* __restrict__ ea,
    float* __restrict__ ws, const int* __restrict__ iw)
{
  __shared__ float rs[66][68];
  __shared__ float xo[MNB][68];
  int tid = threadIdx.x;
  int n0 = blockIdx.x*MNB;
  for (int idx=tid; idx<66*66; idx+=256) rs[idx/66][idx%66] = root[idx];
  for (int idx=tid; idx<MNB*66; idx+=256) xo[idx/66][idx%66] = ws[OFF_OUT + n0*ID + idx];
  __syncthreads();
  for (int idx=tid; idx<MNB*66; idx+=256){
    int n = idx/66, o = idx%66;
    int node = n0 + n;
    int rawcnt = iw[IOFF_ECNT+node];
    int cnt = rawcnt > ECAP ? ECAP : rawcnt;
    float magg = 0.f;
    for (int q=0;q<cnt;q++){
      int e = iw[IOFF_ELIST + node*ECAP + q];
      int s = eidx[e];
      const float* Tp = ws + OFF_T + s*726 + o;
      const float* eap = ea + e*10;
      float av = Tp[660];
      #pragma unroll
      for (int t=0;t<10;t++) av += eap[t]*Tp[t*66];
      magg += av;
    }
    float deg = fmaxf((float)rawcnt, 1.0f);
    float s2 = nnbias[o] + magg/deg;
    for (int j=0;j<66;j++) s2 += xo[n][j]*rs[j][o];
    s2 = fmaxf(s2, 0.0f);
    ws[OFF_M  + node*ID  + o] = s2;
    ws[OFF_CM + node*132 + o] = s2;
  }
}

// ---- fused sparse conv ----
__global__ __launch_bounds__(256) void k_spconv(
    const float* __restrict__ cv1b, const float* __restrict__ cv2w,
    const float* __restrict__ cv2b,
    int it, float* __restrict__ ws, const int* __restrict__ iw)
{
  __shared__ float mid[DD][68];
  __shared__ float mps[32][68];
  __shared__ float w1s[32][192];
  __shared__ float vv[32];
  __shared__ float w2s[204];
  __shared__ float part[4][64];
  int tid = threadIdx.x;
  int a = blockIdx.x;
  for (int idx=tid; idx<DD*68; idx+=256) (&mid[0][0])[idx] = 0.f;
  if (tid < 198) w2s[tid] = cv2w[it*198 + tid];
  int nnz = iw[IOFF_CNT + a]; if (nnz > CAP) nnz = CAP;
  __syncthreads();
  for (int q0=0; q0<nnz; q0+=32){
    int qn = nnz - q0; if (qn > 32) qn = 32;
    for (int idx=tid; idx<qn*68; idx+=256){
      int q=idx/68, cc=idx%68;
      int b = iw[IOFF_CIDX + a*CAP + q0 + q];
      mps[q][cc] = (cc>=1 && cc<=66)? ws[OFF_M + b*ID + cc-1] : 0.f;
    }
    for (int idx=tid; idx<qn*192; idx+=256){
      int q=idx/192, r=idx%192;
      int b = iw[IOFF_CIDX + a*CAP + q0 + q];
      w1s[q][r] = ws[OFF_C1R + (it*1024+b)*192 + r];
    }
    if (tid < qn) vv[tid] = ws[OFF_CVAL + a*CAP + q0 + tid];
    __syncthreads();
    for (int idx=tid; idx<DD*ID; idx+=256){
      int o = idx/ID, cc = idx%ID;
      float acc = mid[o][cc];
      for (int q=0;q<qn;q++){
        acc += vv[q]*(w1s[q][o*3]*mps[q][cc] + w1s[q][o*3+1]*mps[q][cc+1] + w1s[q][o*3+2]*mps[q][cc+2]);
      }
      mid[o][cc] = acc;
    }
    __syncthreads();
  }
  for (int idx=tid; idx<DD*ID; idx+=256){ int o=idx/ID, cc=idx%ID; mid[o][cc] += cv1b[it*DD+o]; }
  __syncthreads();
  {
    int x = tid & 63, qq = tid >> 6;
    int c0 = qq*17, cN = c0+17; if (cN > ID) cN = ID;
    float s = 0.f;
    for (int cc=c0; cc<cN; cc++){
      #pragma unroll
      for (int k=0;k<3;k++){
        int oo = x + k - 1;
        if (oo >= 0 && oo < DD) s += mid[oo][cc]*w2s[cc*3+k];
      }
    }
    part[qq][x] = s;
  }
  __syncthreads();
  if (tid < DD)
    ws[OFF_CM + a*132 + ID + tid] = part[0][tid]+part[1][tid]+part[2][tid]+part[3][tid] + cv2b[it];
}

// ---- gate score + per-mol segment softmax -> av[node] ----
__global__ __launch_bounds__(64) void k_af(
    const int* __restrict__ mb,
    const float* __restrict__ lfw, const float* __restrict__ lfb,
    float* __restrict__ ws)
{
  __shared__ int memb[MAXM]; __shared__ int lcnt;
  int tid = threadIdx.x, m = blockIdx.x;
  if (tid==0) lcnt = 0;
  __syncthreads();
  for (int i=tid; i<NN; i+=64)
    if (mb[i]==m){ int p = atomicAdd(&lcnt,1); if (p<MAXM) memb[p]=i; }
  __syncthreads();
  int M = lcnt; if (M > MAXM) M = MAXM;
  float x = -INFINITY;
  if (tid < M){
    const float4* cr = (const float4*)(ws + OFF_CM + memb[tid]*132);
    const float4* lw = (const float4*)lfw;
    float4 a = Z4;
    for (int jj=0;jj<32;jj++){ float4 cv=cr[jj], wv=lw[jj]; FMA4(a,cv,wv) }
    const float* crow = ws + OFF_CM + memb[tid]*132;
    float s = hsum4(a) + crow[128]*lfw[128] + crow[129]*lfw[129] + lfb[0];
    x = (s > 0.f) ? s : 0.01f*s;
  }
  float mx = x;
  for (int o=32;o>0;o>>=1) mx = fmaxf(mx, __shfl_xor(mx,o,64));
  float ex = (tid<M) ? expf(x-mx) : 0.f;
  float sm = ex;
  for (int o=32;o>0;o>>=1) sm += __shfl_xor(sm,o,64);
  if (tid<M) ws[OFF_AV + memb[tid]] = ex/(sm + 1e-16f);
}

// ---- GRU gate GEMM + blend, node-parallel ----
__global__ __launch_bounds__(256) void k_grug(
    const float* __restrict__ bih, const float* __restrict__ bhh,
    float* __restrict__ ws)
{
  __shared__ float xs[GNB][132];
  __shared__ float hs[GNB][68];
  __shared__ float ggg[GNB][132];
  __shared__ float g1[GNB][68], g2[GNB][68];
  int tid = threadIdx.x;
  int n0 = blockIdx.x*GNB;
  for (int idx=tid; idx<GNB*132; idx+=256){
    int n = idx/132, j = idx%132;
    xs[n][j] = (j<130)? ws[OFF_AV + n0 + n] * ws[OFF_CM + (n0+n)*132 + j] : 0.f;
  }
  for (int idx=tid; idx<GNB*68; idx+=256){
    int n = idx/68, j = idx%68;
    hs[n][j] = (j<66)? ws[OFF_OUT + (n0+n)*ID + j] : 0.f;
  }
  __syncthreads();
  if (tid < 198){
    int u = tid;
    const float4* w1 = (const float4*)(ws+OFF_GIH + u*132);
    const float4* w2 = (const float4*)(ws+OFF_GHH + u*68);
    float4 a0=Z4,a1=Z4,a2=Z4,a3=Z4;
    #pragma unroll 4
    for (int jj=0;jj<33;jj++){
      float4 w = w1[jj];
      FMA4(a0,*(const float4*)&xs[0][jj*4],w)
      FMA4(a1,*(const float4*)&xs[1][jj*4],w)
      FMA4(a2,*(const float4*)&xs[2][jj*4],w)
      FMA4(a3,*(const float4*)&xs[3][jj*4],w)
    }
    float4 b0=Z4,b1=Z4,b2=Z4,b3=Z4;
    #pragma unroll 4
    for (int jj=0;jj<17;jj++){
      float4 w = w2[jj];
      FMA4(b0,*(const float4*)&hs[0][jj*4],w)
      FMA4(b1,*(const float4*)&hs[1][jj*4],w)
      FMA4(b2,*(const float4*)&hs[2][jj*4],w)
      FMA4(b3,*(const float4*)&hs[3][jj*4],w)
    }
    float bv1 = bih[u], bv2 = bhh[u];
    float d1[4] = {hsum4(a0),hsum4(a1),hsum4(a2),hsum4(a3)};
    float d2[4] = {hsum4(b0),hsum4(b1),hsum4(b2),hsum4(b3)};
    #pragma unroll
    for (int n=0;n<4;n++){
      float v1 = bv1 + d1[n];
      float v2 = bv2 + d2[n];
      if (u < 132) ggg[n][u] = sgm(v1+v2);
      else { g1[n][u-132] = v1; g2[n][u-132] = v2; }
    }
  }
  __syncthreads();
  for (int idx=tid; idx<GNB*66; idx+=256){
    int n = idx/66, u = idx%66;
    float r = ggg[n][u], z = ggg[n][66+u];
    float nn_ = tanhf(g1[n][u] + r*g2[n][u]);
    ws[OFF_OUT + (n0+n)*ID + u] = (1.f - z)*nn_ + z*hs[n][u];
  }
}

// ---- Set2Set readout ----
__global__ __launch_bounds__(256) void k_s2s(
    const int* __restrict__ mb,
    const float* __restrict__ wih, const float* __restrict__ whh,
    const float* __restrict__ bih, const float* __restrict__ bhh,
    float* __restrict__ ws)
{
  __shared__ int memb[MAXM]; __shared__ int lcnt;
  __shared__ float orow[MAXM][68];
  __shared__ float hsv[66], csv[66], qsv[132], gv[264];
  __shared__ float av[MAXM];
  int tid = threadIdx.x, m = blockIdx.x;
  if (tid==0) lcnt = 0;
  __syncthreads();
  for (int i=tid; i<NN; i+=256)
    if (mb[i]==m){ int p = atomicAdd(&lcnt,1); if (p<MAXM) memb[p]=i; }
  __syncthreads();
  int M = lcnt; if (M > MAXM) M = MAXM;
  for (int idx=tid; idx<M*ID; idx+=256){ int i=idx/ID, j=idx%ID; orow[i][j]=ws[OFF_OUT+memb[i]*ID+j]; }
  if (tid < 66){ hsv[tid]=0.f; csv[tid]=0.f; }
  if (tid < 132) qsv[tid]=0.f;
  __syncthreads();
  for (int step=0; step<3; step++){
    for (int u=tid; u<264; u+=256){
      float s = bih[u] + bhh[u];
      const float* w1 = wih + u*132;
      for (int j=0;j<132;j++) s += qsv[j]*w1[j];
      const float* w2 = whh + u*ID;
      for (int j=0;j<ID;j++) s += hsv[j]*w2[j];
      gv[u] = s;
    }
    __syncthreads();
    if (tid < 66){
      float ig=gv[tid], fg=gv[66+tid], gg_=gv[132+tid], og=gv[198+tid];
      float c = sgm(fg)*csv[tid] + sgm(ig)*tanhf(gg_);
      csv[tid] = c;
      hsv[tid] = sgm(og)*tanhf(c);
    }
    __syncthreads();
    if (tid < 64){
      float e = -INFINITY;
      if (tid < M){ e = 0.f; for (int j=0;j<ID;j++) e += orow[tid][j]*hsv[j]; }
      float mx = e;
      for (int o=32;o>0;o>>=1) mx = fmaxf(mx, __shfl_xor(mx,o,64));
      float ex = (tid<M) ? expf(e-mx) : 0.f;
      float sm = ex;
      for (int o=32;o>0;o>>=1) sm += __shfl_xor(sm,o,64);
      if (tid<M) av[tid] = ex/(sm + 1e-16f);
    }
    __syncthreads();
    if (tid < 66){
      float r = 0.f;
      for (int i=0;i<M;i++) r += av[i]*orow[i][tid];
      qsv[tid]      = hsv[tid];
      qsv[66+tid]   = r;
    }
    __syncthreads();
  }
  if (tid < 132) ws[OFF_QSTAR + m*132 + tid] = qsv[tid];
}

// ---- fingers MLP ----
__global__ __launch_bounds__(256) void k_fd1(
    const float* __restrict__ fing, const float* __restrict__ d1w, const float* __restrict__ d1b,
    float* __restrict__ ws)
{
  __shared__ __align__(16) float fin[1024];
  int tid = threadIdx.x;
  int b = blockIdx.x >> 4, u0 = (blockIdx.x & 15)*32;
  for (int j=tid; j<1024; j+=256) fin[j] = fing[b*1024+j];
  __syncthreads();
  int u = u0 + (tid>>3), q = tid & 7;
  const float4* w4 = (const float4*)(d1w + u*1024);
  const float4* x4 = (const float4*)fin;
  float4 a = Z4;
  for (int jj=q; jj<256; jj+=8){ float4 wv=w4[jj], xv=x4[jj]; FMA4(a,xv,wv) }
  float s = hsum4(a);
  s += __shfl_xor(s,1,64); s += __shfl_xor(s,2,64); s += __shfl_xor(s,4,64);
  if (q==0) ws[OFF_F1 + b*512 + u] = fmaxf(s + d1b[u], 0.f);
}
__global__ __launch_bounds__(256) void k_fd2(
    const float* __restrict__ d2w, const float* __restrict__ d2b, float* __restrict__ ws)
{
  __shared__ __align__(16) float f1[512];
  int tid = threadIdx.x;
  int b = blockIdx.x >> 3, u0 = (blockIdx.x & 7)*32;
  for (int j=tid; j<512; j+=256) f1[j] = ws[OFF_F1 + b*512 + j];
  __syncthreads();
  int u = u0 + (tid>>3), q = tid & 7;
  const float4* w4 = (const float4*)(d2w + u*512);
  const float4* x4 = (const float4*)f1;
  float4 a = Z4;
  for (int jj=q; jj<128; jj+=8){ float4 wv=w4[jj], xv=x4[jj]; FMA4(a,xv,wv) }
  float s = hsum4(a);
  s += __shfl_xor(s,1,64); s += __shfl_xor(s,2,64); s += __shfl_xor(s,4,64);
  if (q==0) ws[OFF_F2 + b*256 + u] = fmaxf(s + d2b[u], 0.f);
}
__global__ __launch_bounds__(256) void k_fd3p(
    const float* __restrict__ d3w, const float* __restrict__ d3b,
    const float* __restrict__ pw,  const float* __restrict__ pb,
    const float* __restrict__ ws,  float* __restrict__ outp)
{
  __shared__ __align__(16) float f2[256];
  __shared__ float f3[64];
  int tid = threadIdx.x, b = blockIdx.x;
  for (int j=tid; j<256; j+=256) f2[j] = ws[OFF_F2 + b*256 + j];
  __syncthreads();
  {
    int u = tid>>2, q = tid&3;
    const float4* w4 = (const float4*)(d3w + u*256);
    const float4* x4 = (const float4*)f2;
    float4 a = Z4;
    for (int jj=q; jj<64; jj+=4){ float4 wv=w4[jj], xv=x4[jj]; FMA4(a,xv,wv) }
    float s = hsum4(a);
    s += __shfl_xor(s,1,64); s += __shfl_xor(s,2,64);
    if (q==0) f3[u] = s + d3b[u];
  }
  __syncthreads();
  if (tid < 64){
    float s = 0.f;
    for (int j=tid; j<132; j+=64) s += ws[OFF_QSTAR + b*132 + j]*pw[j];
    s += f3[tid]*pw[132 + tid];
    for (int o=32;o>0;o>>=1) s += __shfl_xor(s,o,64);
    if (tid==0) outp[b] = s + pb[0];
  }
}

extern "C" void kernel_launch(void* const* d_in, const int* in_sizes, int n_in,
                              void* d_out, int out_size, void* d_ws, size_t ws_size,
                              hipStream_t stream)
{
  const float* mnc = (const float*)d_in[0];
  const float* ea  = (const float*)d_in[1];
  const float* fing= (const float*)d_in[2];
  const int*   eidx= (const int*)d_in[3];
  const int*   mb  = (const int*)d_in[4];
  const float* adj = (const float*)d_in[5];
  const float* e1w=(const float*)d_in[6],  *e1b=(const float*)d_in[7];
  const float* e2w=(const float*)d_in[8],  *e2b=(const float*)d_in[9];
  const float* c1w=(const float*)d_in[10], *c1b=(const float*)d_in[11];
  const float* c2w=(const float*)d_in[12], *c2b=(const float*)d_in[13];
  const float* n1w=(const float*)d_in[14], *n1b=(const float*)d_in[15];
  const float* n2w=(const float*)d_in[16], *n2b=(const float*)d_in[17];
  const float* bng=(const float*)d_in[18], *bnb=(const float*)d_in[19];
  const float* nnw=(const float*)d_in[20], *nnb=(const float*)d_in[21];
  const float* root=(const float*)d_in[22],*nnbias=(const float*)d_in[23];
  const float* cv1w=(const float*)d_in[24],*cv1b=(const float*)d_in[25];
  const float* cv2w=(const float*)d_in[26],*cv2b=(const float*)d_in[27];
  const float* lfw=(const float*)d_in[28], *lfb=(const float*)d_in[29];
  const float* gwih=(const float*)d_in[30],*gwhh=(const float*)d_in[31];
  const float* gbih=(const float*)d_in[32],*gbhh=(const float*)d_in[33];
  const float* lwih=(const float*)d_in[34],*lwhh=(const float*)d_in[35];
  const float* lbih=(const float*)d_in[36],*lbhh=(const float*)d_in[37];
  const float* d1w=(const float*)d_in[38], *d1b=(const float*)d_in[39];
  const float* d2w=(const float*)d_in[40], *d2b=(const float*)d_in[41];
  const float* d3w=(const float*)d_in[42], *d3b=(const float*)d_in[43];
  const float* pw =(const float*)d_in[44], *pb =(const float*)d_in[45];
  float* ws = (float*)d_ws;
  int*   iw = (int*)(ws + OFF_FEND);
  float* outp = (float*)d_out;

  const long long setup_total = (long long)NN*NN + EE + 16384 + 16384 + 16384
                              + 726*68 + 3*1024*192 + 198*132 + 198*68
                              + 126*128 + 63*128;
  int setup_blocks = (int)((setup_total + 255)/256);

  k_zero0    <<<4, 256, 0, stream>>>(iw);
  k_setup    <<<setup_blocks, 256, 0, stream>>>(adj, eidx, e1w, e2w, c1w, nnw, nnb, cv1w, gwih, gwhh, n1w, n2w, ws, iw);
  k_ab       <<<(NN/32)*4, 256, 0, stream>>>(mnc, e1b, ws);
  k_edge     <<<EE/EB, 256, 0, stream>>>(mnc, eidx, e2b, c1b, c2w, c2b, ws);
  k_node     <<<NN/NNB, 256, 0, stream>>>(mnc, n1b, n2b, ws, iw);
  k_bn_stats <<<ID, 256, 0, stream>>>(ws);
  k_bn_apply <<<(NN*ID+255)/256, 256, 0, stream>>>(bng, bnb, ws);
  for (int it=0; it<3; ++it){
    k_tbuild <<<(NN/16)*3, 256, 0, stream>>>(ws);
    k_mnode  <<<NN/MNB, 256, 0, stream>>>(root, nnbias, eidx, ea, ws, iw);
    k_spconv <<<NN, 256, 0, stream>>>(cv1b, cv2w, cv2b, it, ws, iw);
    k_af     <<<BB, 64, 0, stream>>>(mb, lfw, lfb, ws);
    k_grug   <<<NN/GNB, 256, 0, stream>>>(gbih, gbhh, ws);
  }
  k_s2s      <<<BB, 256, 0, stream>>>(mb, lwih, lwhh, lbih, lbhh, ws);
  k_fd1      <<<BB*16, 256, 0, stream>>>(fing, d1w, d1b, ws);
  k_fd2      <<<BB*8, 256, 0, stream>>>(d2w, d2b, ws);
  k_fd3p     <<<BB, 256, 0, stream>>>(d3w, d3b, pw, pb, ws, outp);
}

// Round 11
// 534.572 us; speedup vs baseline: 2.2759x; 1.0517x over previous
//
#include <hip/hip_runtime.h>
#include <math.h>

// Problem constants (fixed by the reference)
#define NN 1024   // nodes
#define BB 32     // mols
#define EE 8192   // edges
#define DD 64     // DIM
#define ID 66     // IN_DIM
#define FT 63     // feats dim
#define CAP 128   // max nnz per adj column
#define ECAP 64   // max in-edges per node
#define MAXM 64   // max nodes per mol (s2s)
#define GNB 4     // nodes per block in gru gate gemm
#define QCH 16    // spconv neighbor chunk

// ---- workspace layout (float offsets) ----
enum : int {
  OFF_SMIP  = 0,                        // N*66 pre-BN smi
  OFF_OUT   = OFF_SMIP + NN*ID,         // N*66 h
  OFF_STATS = OFF_OUT + NN*ID,          // 144 mean/rstd
  OFF_M     = OFF_STATS + 144,          // N*66 m buffer
  OFF_CM    = OFF_M + NN*ID,            // N*132 cm
  OFF_QSTAR = OFF_CM + NN*132,          // 32*132
  OFF_CVAL  = OFF_QSTAR + BB*132,       // N*CAP csc values
  OFF_A     = OFF_CVAL + NN*CAP,        // 1024*256 A = feats@W1a^T + e1b
  OFF_B     = OFF_A + 1024*256,         // 1024*256 B = feats@W1b^T
  OFF_EDGE  = OFF_B + 1024*256,         // 8192*68: [0..62]=mij, [64..66]=cw*rel
  OFF_T     = OFF_EDGE + EE*68,         // 1024*726 T[n][t*66+o]
  OFF_QAUG  = OFF_T + NN*726,           // 726*68 Qaug[(t*66+o)][i]
  OFF_W1A   = OFF_QAUG + 726*68,        // 256*64
  OFF_W1B   = OFF_W1A + 16384,          // 256*64
  OFF_WR    = OFF_W1B + 16384,          // 256
  OFF_W2P   = OFF_WR + 256,             // 64*256 padded e2w
  OFF_C1P   = OFF_W2P + 16384,          // 256*64 padded c1w
  OFF_C1R   = OFF_C1P + 16384,          // 3*1024*192 conv1_w reorg
  OFF_GIH   = OFF_C1R + 3*1024*192,     // 198*132
  OFF_GHH   = OFF_GIH + 198*132,        // 198*68
  OFF_F1    = OFF_GHH + 198*68,         // 32*512
  OFF_F2    = OFF_F1 + BB*512,          // 32*256
  OFF_AV    = OFF_F2 + BB*256,          // N  softmax gate per node
  OFF_N1P   = OFF_AV + NN,              // 126*128 padded n1w
  OFF_N2P   = OFF_N1P + 126*128,        // 63*128  padded n2w
  OFF_FEND  = OFF_N2P + 63*128
};
enum : int {  // int region at ws + OFF_FEND
  IOFF_CNT   = 0,                 // N   csc col counts
  IOFF_CIDX  = NN,                // N*CAP
  IOFF_ECNT  = NN + NN*CAP,       // N   in-degree
  IOFF_ELIST = NN + NN*CAP + NN,  // N*ECAP edge ids sorted by dst
  IOFF_END   = NN + NN*CAP + NN + NN*ECAP
};

__device__ __forceinline__ float sgm(float x){ return 1.0f/(1.0f+expf(-x)); }
__device__ __forceinline__ float silu_(float x){ return x/(1.0f+expf(-x)); }
__device__ __forceinline__ float nan0(float v){ return (v!=v) ? 0.0f : v; }
__device__ __forceinline__ float hsum4(float4 v){ return v.x+v.y+v.z+v.w; }
#define FMA4(A,X,W) {A.x += (X).x*(W).x; A.y += (X).y*(W).y; A.z += (X).z*(W).z; A.w += (X).w*(W).w;}
#define Z4 {0.f,0.f,0.f,0.f}

// ---- zero the atomic counters ----
__global__ void k_zero0(int* __restrict__ iw){
  int i = blockIdx.x*256 + threadIdx.x;
  if (i < NN){ iw[IOFF_CNT + i] = 0; iw[IOFF_ECNT + i] = 0; }
}

// ---- one-shot setup: csc(adj), edge sort by dst, weight reorg/pad ----
__global__ void k_setup(const float* __restrict__ adj, const int* __restrict__ eidx,
                        const float* __restrict__ e1w, const float* __restrict__ e2w,
                        const float* __restrict__ c1w,
                        const float* __restrict__ nnw, const float* __restrict__ nnb,
                        const float* __restrict__ cv1w,
                        const float* __restrict__ gwih, const float* __restrict__ gwhh,
                        const float* __restrict__ n1w, const float* __restrict__ n2w,
                        float* __restrict__ ws, int* __restrict__ iw){
  long long idx = (long long)blockIdx.x*256 + threadIdx.x;
  if (idx < (long long)NN*NN){
    float v = adj[idx];
    if (v != 0.0f){
      int a = (int)(idx & 1023), b = (int)(idx >> 10);
      int p = atomicAdd(iw + IOFF_CNT + a, 1);
      if (p < CAP){ iw[IOFF_CIDX + a*CAP + p] = b; ws[OFF_CVAL + a*CAP + p] = v; }
    }
    return;
  }
  idx -= (long long)NN*NN;
  if (idx < EE){
    int e = (int)idx, d = eidx[EE + e];
    int p = atomicAdd(iw + IOFF_ECNT + d, 1);
    if (p < ECAP) iw[IOFF_ELIST + d*ECAP + p] = e;
    return;
  }
  idx -= EE;
  if (idx < 16384){ int u=(int)idx>>6, j=(int)idx&63;
    ws[OFF_W1A+idx] = (u<254 && j<63)? e1w[u*127+j]      : 0.f;
    ws[OFF_W1B+idx] = (u<254 && j<63)? e1w[u*127+63+j]   : 0.f;
    if (j==0) ws[OFF_WR+u] = (u<254)? e1w[u*127+126] : 0.f;
    return; }
  idx -= 16384;
  if (idx < 16384){ int u=(int)idx>>8, j=(int)idx&255; ws[OFF_W2P+idx] = (u<63 && j<254)? e2w[u*254+j] : 0.f; return; }
  idx -= 16384;
  if (idx < 16384){ int u=(int)idx>>6, j=(int)idx&63; ws[OFF_C1P+idx] = (u<252 && j<63)? c1w[u*63+j] : 0.f; return; }
  idx -= 16384;
  if (idx < 726*68){ int to=(int)idx/68, i=(int)idx%68; int t=to/66, o=to%66;
    float v = 0.f;
    if (i < 66) v = (t<10)? nnw[(i*66+o)*10+t] : nnb[i*66+o];
    ws[OFF_QAUG+idx] = v; return; }
  idx -= 726*68;
  if (idx < 3*1024*192){ int it=(int)(idx/196608); int r=(int)(idx%196608); int b=r/192; int z=r%192; int o=z/3, k=z%3;
    ws[OFF_C1R+idx] = cv1w[((it*64+o)*1024+b)*3+k]; return; }
  idx -= 3*1024*192;
  if (idx < 198*132){ int u=(int)idx/132, j=(int)idx%132; ws[OFF_GIH+idx] = (j<130)? gwih[u*130+j] : 0.f; return; }
  idx -= 198*132;
  if (idx < 198*68){ int u=(int)idx/68, j=(int)idx%68; ws[OFF_GHH+idx] = (j<66)? gwhh[u*66+j] : 0.f; return; }
  idx -= 198*68;
  if (idx < 126*128){ int u=(int)idx>>7, j=(int)idx&127; ws[OFF_N1P+idx] = (j<126)? n1w[u*126+j] : 0.f; return; }
  idx -= 126*128;
  if (idx < 63*128){ int u=(int)idx>>7, j=(int)idx&127; ws[OFF_N2P+idx] = (j<126)? n2w[u*126+j] : 0.f; return; }
}

// ---- A/B build: 128 blocks = 32 node-tiles x 4 u-tiles ----
__global__ __launch_bounds__(256) void k_ab(const float* __restrict__ mnc,
                                            const float* __restrict__ e1b,
                                            float* __restrict__ ws){
  __shared__ float xf[32][68];
  int tid = threadIdx.x;
  int n0 = (blockIdx.x>>2)*32;
  int ut = blockIdx.x&3;
  for (int idx=tid; idx<32*64; idx+=256){ int n=idx>>6, j=idx&63;
    xf[n][j] = (j<63)? mnc[(n0+n)*ID + 3 + j] : 0.f; }
  __syncthreads();
  int eg = tid&7, ug = tid>>3;
  for (int pass=0; pass<2; pass++){
    int u = ut*64 + pass*32 + ug;
    const float4* wa = (const float4*)(ws + OFF_W1A + u*64);
    const float4* wb = (const float4*)(ws + OFF_W1B + u*64);
    float4 a0=Z4,a1=Z4,a2=Z4,a3=Z4,b0=Z4,b1=Z4,b2=Z4,b3=Z4;
    for (int jj=0;jj<16;jj++){
      float4 w1 = wa[jj], w2 = wb[jj];
      float4 x0 = *(const float4*)&xf[eg   ][jj*4];
      float4 x1 = *(const float4*)&xf[eg+ 8][jj*4];
      float4 x2 = *(const float4*)&xf[eg+16][jj*4];
      float4 x3 = *(const float4*)&xf[eg+24][jj*4];
      FMA4(a0,x0,w1) FMA4(a1,x1,w1) FMA4(a2,x2,w1) FMA4(a3,x3,w1)
      FMA4(b0,x0,w2) FMA4(b1,x1,w2) FMA4(b2,x2,w2) FMA4(b3,x3,w2)
    }
    if (u < 254){
      float bv = e1b[u];
      float va[4]={hsum4(a0),hsum4(a1),hsum4(a2),hsum4(a3)};
      float vb[4]={hsum4(b0),hsum4(b1),hsum4(b2),hsum4(b3)};
      #pragma unroll
      for (int i=0;i<4;i++){
        int n = n0 + eg + 8*i;
        ws[OFF_A + n*256 + u] = bv + va[i];
        ws[OFF_B + n*256 + u] = vb[i];
      }
    }
  }
}

// ---- per-edge chain: EB=8 -> 1024 blocks ----
#define EB 8
__global__ __launch_bounds__(256) void k_edge(
    const float* __restrict__ mnc, const int* __restrict__ eidx,
    const float* __restrict__ e2b, const float* __restrict__ c1b,
    const float* __restrict__ c2w, const float* __restrict__ c2b,
    float* __restrict__ ws)
{
  __shared__ float eh [EB][260];   // L1 out; later ch
  __shared__ float mij[EB][68];
  __shared__ float srel[EB][4];
  __shared__ int ssrc[EB], sdst[EB];
  int tid = threadIdx.x;
  int e0b = blockIdx.x*EB;
  if (tid < EB){
    int e = e0b + tid;
    int s = eidx[e], d = eidx[EE + e];
    ssrc[tid]=s; sdst[tid]=d;
    float rd = 0.f;
    #pragma unroll
    for (int k=0;k<3;k++){ float r = mnc[s*ID+k]-mnc[d*ID+k]; srel[tid][k]=r; rd += r*r; }
    srel[tid][3] = rd;
  }
  if (tid < EB*5) mij[tid/5][63+tid%5] = 0.f;
  __syncthreads();
  // L1: eh = silu(A[dst] + B[src] + wr*rd)
  for (int idx=tid; idx<EB*256; idx+=256){
    int e = idx>>8, u = idx&255;
    float v = 0.f;
    if (u < 254) v = silu_(ws[OFF_A + sdst[e]*256 + u] + ws[OFF_B + ssrc[e]*256 + u]
                           + ws[OFF_WR + u]*srel[e][3]);
    eh[e][u] = v;
  }
  __syncthreads();
  int ug = tid>>2, eg = tid&3;   // u = ug; edges eg, eg+4
  // L2: mij = silu(eh @ W2P^T + e2b), K=256
  {
    const float4* w0 = (const float4*)(ws+OFF_W2P + ug*256);
    float4 a0=Z4,a1=Z4;
    for (int jj=0;jj<64;jj++){
      float4 w = w0[jj];
      FMA4(a0, *(const float4*)&eh[eg  ][jj*4], w)
      FMA4(a1, *(const float4*)&eh[eg+4][jj*4], w)
    }
    if (ug < 63){
      float bv = e2b[ug];
      float v0 = silu_(bv + hsum4(a0));
      float v1 = silu_(bv + hsum4(a1));
      mij[eg  ][ug] = v0; ws[OFF_EDGE + (e0b+eg  )*68 + ug] = v0;
      mij[eg+4][ug] = v1; ws[OFF_EDGE + (e0b+eg+4)*68 + ug] = v1;
    }
  }
  __syncthreads();
  // L3: ch = silu(mij @ C1P^T + c1b) into eh; 4 u-passes
  for (int uc=0; uc<4; uc++){
    int u = uc*64 + ug;
    const float4* w0 = (const float4*)(ws+OFF_C1P + u*64);
    float4 a0=Z4,a1=Z4;
    for (int jj=0;jj<16;jj++){
      float4 w = w0[jj];
      FMA4(a0, *(const float4*)&mij[eg  ][jj*4], w)
      FMA4(a1, *(const float4*)&mij[eg+4][jj*4], w)
    }
    if (u < 252){
      float bv = c1b[u];
      eh[eg  ][u] = silu_(bv + hsum4(a0));
      eh[eg+4][u] = silu_(bv + hsum4(a1));
    }
  }
  __syncthreads();
  // L4: cw = ch·c2w + c2b; 32 lanes per edge
  {
    int e = tid>>5, q = tid&31;
    const float4* xr = (const float4*)&eh[e][0];
    const float4* wr4 = (const float4*)c2w;
    float4 a = Z4;
    for (int jj=q; jj<63; jj+=32){ float4 xv=xr[jj], wv=wr4[jj]; FMA4(a,xv,wv) }
    float s = hsum4(a);
    s += __shfl_down(s,16,32); s += __shfl_down(s,8,32);
    s += __shfl_down(s,4,32);  s += __shfl_down(s,2,32); s += __shfl_down(s,1,32);
    if (q == 0){
      float cw = s + c2b[0];
      #pragma unroll
      for (int k=0;k<3;k++) ws[OFF_EDGE + (e0b+e)*68 + 64 + k] = cw*srel[e][k];
    }
  }
}

// ---- node MLP (float4, padded weights) + gathers -> smi_pre ----
#define NNB 8
__global__ __launch_bounds__(256) void k_node(
    const float* __restrict__ mnc,
    const float* __restrict__ n1b, const float* __restrict__ n2b,
    float* __restrict__ ws, const int* __restrict__ iw)
{
  __shared__ float xin[NNB][132];
  __shared__ float t1 [NNB][132];
  int tid = threadIdx.x;
  int n0 = blockIdx.x*NNB;
  for (int idx=tid; idx<NNB*128; idx+=256){
    int e = idx>>7, j = idx&127;
    int node = n0 + e;
    float v = 0.f;
    if (j < 63) v = mnc[node*ID + 3 + j];
    else if (j < 126){
      int u = j - 63;
      int cnt = iw[IOFF_ECNT+node]; if (cnt > ECAP) cnt = ECAP;
      for (int q=0;q<cnt;q++) v += ws[OFF_EDGE + iw[IOFF_ELIST+node*ECAP+q]*68 + u];
    }
    xin[e][j] = v;
    t1[e][j] = 0.f;
  }
  __syncthreads();
  {
    int ng = tid&3, ug = tid>>2;
    int u0 = 2*ug, u1 = u0+1;
    const float4* w0 = (const float4*)(ws+OFF_N1P + u0*128);
    const float4* w1 = (const float4*)(ws+OFF_N1P + u1*128);
    float4 a0=Z4,a1=Z4,b0=Z4,b1=Z4;
    for (int jj=0;jj<32;jj++){
      float4 wv0=w0[jj], wv1=w1[jj];
      float4 x0 = *(const float4*)&xin[ng  ][jj*4];
      float4 x1 = *(const float4*)&xin[ng+4][jj*4];
      FMA4(a0,x0,wv0) FMA4(a1,x1,wv0)
      FMA4(b0,x0,wv1) FMA4(b1,x1,wv1)
    }
    if (u0 < 126){ float bv=n1b[u0]; t1[ng][u0]=silu_(bv+hsum4(a0)); t1[ng+4][u0]=silu_(bv+hsum4(a1)); }
    if (u1 < 126){ float bv=n1b[u1]; t1[ng][u1]=silu_(bv+hsum4(b0)); t1[ng+4][u1]=silu_(bv+hsum4(b1)); }
  }
  __syncthreads();
  {
    int ng = tid&7, ug = tid>>3;
    int u0 = 2*ug, u1 = u0+1;
    const float4* w0 = (const float4*)(ws+OFF_N2P + u0*128);
    const float4* w1 = (const float4*)(ws+OFF_N2P + u1*128);
    float4 a0=Z4,b0=Z4;
    if (u0 < 63){
      for (int jj=0;jj<32;jj++){
        float4 x0 = *(const float4*)&t1[ng][jj*4];
        FMA4(a0,x0,w0[jj]) FMA4(b0,x0,w1[jj])
      }
      int node = n0 + ng;
      ws[OFF_SMIP + node*ID + 3 + u0] = nan0(xin[ng][u0] + n2b[u0] + hsum4(a0));
      if (u1 < 63)
        ws[OFF_SMIP + node*ID + 3 + u1] = nan0(xin[ng][u1] + n2b[u1] + hsum4(b0));
    }
  }
  if (tid < NNB*3){
    int e = tid/3, k = tid%3;
    int node = n0 + e;
    int cnt = iw[IOFF_ECNT+node]; if (cnt > ECAP) cnt = ECAP;
    float s = mnc[node*ID + k];
    for (int q=0;q<cnt;q++) s += ws[OFF_EDGE + iw[IOFF_ELIST+node*ECAP+q]*68 + 64 + k];
    ws[OFF_SMIP + node*ID + k] = nan0(s);
  }
}

// ---- batchnorm ----
__global__ __launch_bounds__(256) void k_bn_stats(float* __restrict__ ws){
  __shared__ float scr[8];
  int j = blockIdx.x, tid = threadIdx.x;
  float s=0.f, ss=0.f;
  for (int i=tid; i<NN; i+=256){ float x = ws[OFF_SMIP + i*ID + j]; s+=x; ss+=x*x; }
  for (int o=32;o>0;o>>=1){ s += __shfl_down(s,o,64); ss += __shfl_down(ss,o,64); }
  int w = tid>>6;
  if ((tid&63)==0){ scr[w]=s; scr[4+w]=ss; }
  __syncthreads();
  if (tid==0){
    float S=0,SS=0;
    for (int q=0;q<4;q++){S+=scr[q];SS+=scr[4+q];}
    float mean = S/NN;
    float var  = SS/NN - mean*mean;
    ws[OFF_STATS + j]      = mean;
    ws[OFF_STATS + 66 + j] = 1.0f/sqrtf(var + 1e-5f);
  }
}
__global__ void k_bn_apply(const float* __restrict__ bng, const float* __restrict__ bnb,
                           float* __restrict__ ws){
  int idx = blockIdx.x*256 + threadIdx.x;
  if (idx < NN*ID){
    int j = idx % ID;
    ws[OFF_OUT + idx] = bng[j]*(ws[OFF_SMIP+idx]-ws[OFF_STATS+j])*ws[OFF_STATS+66+j] + bnb[j];
  }
}

// ---- T[n][t*66+o] = sum_i h[n,i]*Qaug[i,t,o]; 192 blocks ----
__global__ __launch_bounds__(256) void k_tbuild(float* __restrict__ ws){
  __shared__ float xs[16][68];
  int tid = threadIdx.x;
  int n0 = (blockIdx.x/3)*16;
  int pass = blockIdx.x%3;
  for (int idx=tid; idx<16*68; idx+=256){ int n=idx/68, j=idx%68;
    xs[n][j] = (j<66)? ws[OFF_OUT + (n0+n)*ID + j] : 0.f; }
  __syncthreads();
  int to = pass*256 + tid;
  if (to < 726){
    float acc[16];
    #pragma unroll
    for (int n=0;n<16;n++) acc[n] = 0.f;
    const float4* qp = (const float4*)(ws + OFF_QAUG + to*68);
    for (int jj=0;jj<17;jj++){
      float4 w = qp[jj];
      #pragma unroll
      for (int n=0;n<16;n++){
        float4 x = *(const float4*)&xs[n][jj*4];
        acc[n] += x.x*w.x + x.y*w.y + x.z*w.z + x.w*w.w;
      }
    }
    #pragma unroll
    for (int n=0;n<16;n++) ws[OFF_T + (n0+n)*726 + to] = acc[n];
  }
}

// ---- m = relu(gathered_msg/deg + h@root + nn_bias); 256 blocks ----
#define MNB 4
__global__ __launch_bounds__(256) void k_mnode(
    const float* __restrict__ root, const float* __restrict__ nnbias,
    const int* __restrict__ eidx, const float* __restrict__ ea,
    float* __restrict__ ws, const int* __restrict__ iw)
{
  __shared__ float rs[66][68];
  __shared__ float xo[MNB][68];
  int tid = threadIdx.x;
  int n0 = blockIdx.x*MNB;
  for (int idx=tid; idx<66*66; idx+=256) rs[idx/66][idx%66] = root[idx];
  for (int idx=tid; idx<MNB*66; idx+=256) xo[idx/66][idx%66] = ws[OFF_OUT + n0*ID + idx];
  __syncthreads();
  for (int idx=tid; idx<MNB*66; idx+=256){
    int n = idx/66, o = idx%66;
    int node = n0 + n;
    int rawcnt = iw[IOFF_ECNT+node];
    int cnt = rawcnt > ECAP ? ECAP : rawcnt;
    float magg = 0.f;
    for (int q=0;q<cnt;q++){
      int e = iw[IOFF_ELIST + node*ECAP + q];
      int s = eidx[e];
      const float* Tp = ws + OFF_T + s*726 + o;
      const float* eap = ea + e*10;
      float av = Tp[660];
      #pragma unroll
      for (int t=0;t<10;t++) av += eap[t]*Tp[t*66];
      magg += av;
    }
    float deg = fmaxf((float)rawcnt, 1.0f);
    float s2 = nnbias[o] + magg/deg;
    for (int j=0;j<66;j++) s2 += xo[n][j]*rs[j][o];
    s2 = fmaxf(s2, 0.0f);
    ws[OFF_M  + node*ID  + o] = s2;
    ws[OFF_CM + node*132 + o] = s2;
  }
}

// ---- fused sparse conv: mid stride 69 (R10: stride-68 gave 8-way bank
// conflict in conv2 tail, 2.64M conflict-cycles), QCH=16 (LDS 52.7->36KB) ----
__global__ __launch_bounds__(256) void k_spconv(
    const float* __restrict__ cv1b, const float* __restrict__ cv2w,
    const float* __restrict__ cv2b,
    int it, float* __restrict__ ws, const int* __restrict__ iw)
{
  __shared__ float mid[DD][69];
  __shared__ float mps[QCH][68];
  __shared__ float w1s[QCH][192];
  __shared__ float vv[QCH];
  __shared__ float w2s[204];
  __shared__ float part[4][64];
  int tid = threadIdx.x;
  int a = blockIdx.x;
  for (int idx=tid; idx<DD*69; idx+=256) (&mid[0][0])[idx] = 0.f;
  if (tid < 198) w2s[tid] = cv2w[it*198 + tid];
  int nnz = iw[IOFF_CNT + a]; if (nnz > CAP) nnz = CAP;
  __syncthreads();
  for (int q0=0; q0<nnz; q0+=QCH){
    int qn = nnz - q0; if (qn > QCH) qn = QCH;
    for (int idx=tid; idx<qn*68; idx+=256){
      int q=idx/68, cc=idx%68;
      int b = iw[IOFF_CIDX + a*CAP + q0 + q];
      mps[q][cc] = (cc>=1 && cc<=66)? ws[OFF_M + b*ID + cc-1] : 0.f;
    }
    for (int idx=tid; idx<qn*192; idx+=256){
      int q=idx/192, r=idx%192;
      int b = iw[IOFF_CIDX + a*CAP + q0 + q];
      w1s[q][r] = ws[OFF_C1R + (it*1024+b)*192 + r];
    }
    if (tid < qn) vv[tid] = ws[OFF_CVAL + a*CAP + q0 + tid];
    __syncthreads();
    for (int idx=tid; idx<DD*ID; idx+=256){
      int o = idx/ID, cc = idx%ID;
      float acc = mid[o][cc];
      for (int q=0;q<qn;q++){
        acc += vv[q]*(w1s[q][o*3]*mps[q][cc] + w1s[q][o*3+1]*mps[q][cc+1] + w1s[q][o*3+2]*mps[q][cc+2]);
      }
      mid[o][cc] = acc;
    }
    __syncthreads();
  }
  for (int idx=tid; idx<DD*ID; idx+=256){ int o=idx/ID, cc=idx%ID; mid[o][cc] += cv1b[it*DD+o]; }
  __syncthreads();
  {
    int x = tid & 63, qq = tid >> 6;
    int c0 = qq*17, cN = c0+17; if (cN > ID) cN = ID;
    float s = 0.f;
    for (int cc=c0; cc<cN; cc++){
      #pragma unroll
      for (int k=0;k<3;k++){
        int oo = x + k - 1;
        if (oo >= 0 && oo < DD) s += mid[oo][cc]*w2s[cc*3+k];
      }
    }
    part[qq][x] = s;
  }
  __syncthreads();
  if (tid < DD)
    ws[OFF_CM + a*132 + ID + tid] = part[0][tid]+part[1][tid]+part[2][tid]+part[3][tid] + cv2b[it];
}

// ---- gate score + per-mol segment softmax -> av[node] ----
__global__ __launch_bounds__(64) void k_af(
    const int* __restrict__ mb,
    const float* __restrict__ lfw, const float* __restrict__ lfb,
    float* __restrict__ ws)
{
  __shared__ int memb[MAXM]; __shared__ int lcnt;
  int tid = threadIdx.x, m = blockIdx.x;
  if (tid==0) lcnt = 0;
  __syncthreads();
  for (int i=tid; i<NN; i+=64)
    if (mb[i]==m){ int p = atomicAdd(&lcnt,1); if (p<MAXM) memb[p]=i; }
  __syncthreads();
  int M = lcnt; if (M > MAXM) M = MAXM;
  float x = -INFINITY;
  if (tid < M){
    const float4* cr = (const float4*)(ws + OFF_CM + memb[tid]*132);
    const float4* lw = (const float4*)lfw;
    float4 a = Z4;
    for (int jj=0;jj<32;jj++){ float4 cv=cr[jj], wv=lw[jj]; FMA4(a,cv,wv) }
    const float* crow = ws + OFF_CM + memb[tid]*132;
    float s = hsum4(a) + crow[128]*lfw[128] + crow[129]*lfw[129] + lfb[0];
    x = (s > 0.f) ? s : 0.01f*s;
  }
  float mx = x;
  for (int o=32;o>0;o>>=1) mx = fmaxf(mx, __shfl_xor(mx,o,64));
  float ex = (tid<M) ? expf(x-mx) : 0.f;
  float sm = ex;
  for (int o=32;o>0;o>>=1) sm += __shfl_xor(sm,o,64);
  if (tid<M) ws[OFF_AV + memb[tid]] = ex/(sm + 1e-16f);
}

// ---- GRU gate GEMM + blend, node-parallel ----
__global__ __launch_bounds__(256) void k_grug(
    const float* __restrict__ bih, const float* __restrict__ bhh,
    float* __restrict__ ws)
{
  __shared__ float xs[GNB][132];
  __shared__ float hs[GNB][68];
  __shared__ float ggg[GNB][132];
  __shared__ float g1[GNB][68], g2[GNB][68];
  int tid = threadIdx.x;
  int n0 = blockIdx.x*GNB;
  for (int idx=tid; idx<GNB*132; idx+=256){
    int n = idx/132, j = idx%132;
    xs[n][j] = (j<130)? ws[OFF_AV + n0 + n] * ws[OFF_CM + (n0+n)*132 + j] : 0.f;
  }
  for (int idx=tid; idx<GNB*68; idx+=256){
    int n = idx/68, j = idx%68;
    hs[n][j] = (j<66)? ws[OFF_OUT + (n0+n)*ID + j] : 0.f;
  }
  __syncthreads();
  if (tid < 198){
    int u = tid;
    const float4* w1 = (const float4*)(ws+OFF_GIH + u*132);
    const float4* w2 = (const float4*)(ws+OFF_GHH + u*68);
    float4 a0=Z4,a1=Z4,a2=Z4,a3=Z4;
    #pragma unroll 4
    for (int jj=0;jj<33;jj++){
      float4 w = w1[jj];
      FMA4(a0,*(const float4*)&xs[0][jj*4],w)
      FMA4(a1,*(const float4*)&xs[1][jj*4],w)
      FMA4(a2,*(const float4*)&xs[2][jj*4],w)
      FMA4(a3,*(const float4*)&xs[3][jj*4],w)
    }
    float4 b0=Z4,b1=Z4,b2=Z4,b3=Z4;
    #pragma unroll 4
    for (int jj=0;jj<17;jj++){
      float4 w = w2[jj];
      FMA4(b0,*(const float4*)&hs[0][jj*4],w)
      FMA4(b1,*(const float4*)&hs[1][jj*4],w)
      FMA4(b2,*(const float4*)&hs[2][jj*4],w)
      FMA4(b3,*(const float4*)&hs[3][jj*4],w)
    }
    float bv1 = bih[u], bv2 = bhh[u];
    float d1[4] = {hsum4(a0),hsum4(a1),hsum4(a2),hsum4(a3)};
    float d2[4] = {hsum4(b0),hsum4(b1),hsum4(b2),hsum4(b3)};
    #pragma unroll
    for (int n=0;n<4;n++){
      float v1 = bv1 + d1[n];
      float v2 = bv2 + d2[n];
      if (u < 132) ggg[n][u] = sgm(v1+v2);
      else { g1[n][u-132] = v1; g2[n][u-132] = v2; }
    }
  }
  __syncthreads();
  for (int idx=tid; idx<GNB*66; idx+=256){
    int n = idx/66, u = idx%66;
    float r = ggg[n][u], z = ggg[n][66+u];
    float nn_ = tanhf(g1[n][u] + r*g2[n][u]);
    ws[OFF_OUT + (n0+n)*ID + u] = (1.f - z)*nn_ + z*hs[n][u];
  }
}

// ---- Set2Set readout ----
__global__ __launch_bounds__(256) void k_s2s(
    const int* __restrict__ mb,
    const float* __restrict__ wih, const float* __restrict__ whh,
    const float* __restrict__ bih, const float* __restrict__ bhh,
    float* __restrict__ ws)
{
  __shared__ int memb[MAXM]; __shared__ int lcnt;
  __shared__ float orow[MAXM][68];
  __shared__ float hsv[66], csv[66], qsv[132], gv[264];
  __shared__ float av[MAXM];
  int tid = threadIdx.x, m = blockIdx.x;
  if (tid==0) lcnt = 0;
  __syncthreads();
  for (int i=tid; i<NN; i+=256)
    if (mb[i]==m){ int p = atomicAdd(&lcnt,1); if (p<MAXM) memb[p]=i; }
  __syncthreads();
  int M = lcnt; if (M > MAXM) M = MAXM;
  for (int idx=tid; idx<M*ID; idx+=256){ int i=idx/ID, j=idx%ID; orow[i][j]=ws[OFF_OUT+memb[i]*ID+j]; }
  if (tid < 66){ hsv[tid]=0.f; csv[tid]=0.f; }
  if (tid < 132) qsv[tid]=0.f;
  __syncthreads();
  for (int step=0; step<3; step++){
    for (int u=tid; u<264; u+=256){
      float s = bih[u] + bhh[u];
      const float* w1 = wih + u*132;
      for (int j=0;j<132;j++) s += qsv[j]*w1[j];
      const float* w2 = whh + u*ID;
      for (int j=0;j<ID;j++) s += hsv[j]*w2[j];
      gv[u] = s;
    }
    __syncthreads();
    if (tid < 66){
      float ig=gv[tid], fg=gv[66+tid], gg_=gv[132+tid], og=gv[198+tid];
      float c = sgm(fg)*csv[tid] + sgm(ig)*tanhf(gg_);
      csv[tid] = c;
      hsv[tid] = sgm(og)*tanhf(c);
    }
    __syncthreads();
    if (tid < 64){
      float e = -INFINITY;
      if (tid < M){ e = 0.f; for (int j=0;j<ID;j++) e += orow[tid][j]*hsv[j]; }
      float mx = e;
      for (int o=32;o>0;o>>=1) mx = fmaxf(mx, __shfl_xor(mx,o,64));
      float ex = (tid<M) ? expf(e-mx) : 0.f;
      float sm = ex;
      for (int o=32;o>0;o>>=1) sm += __shfl_xor(sm,o,64);
      if (tid<M) av[tid] = ex/(sm + 1e-16f);
    }
    __syncthreads();
    if (tid < 66){
      float r = 0.f;
      for (int i=0;i<M;i++) r += av[i]*orow[i][tid];
      qsv[tid]      = hsv[tid];
      qsv[66+tid]   = r;
    }
    __syncthreads();
  }
  if (tid < 132) ws[OFF_QSTAR + m*132 + tid] = qsv[tid];
}

// ---- fingers MLP ----
__global__ __launch_bounds__(256) void k_fd1(
    const float* __restrict__ fing, const float* __restrict__ d1w, const float* __restrict__ d1b,
    float* __restrict__ ws)
{
  __shared__ __align__(16) float fin[1024];
  int tid = threadIdx.x;
  int b = blockIdx.x >> 4, u0 = (blockIdx.x & 15)*32;
  for (int j=tid; j<1024; j+=256) fin[j] = fing[b*1024+j];
  __syncthreads();
  int u = u0 + (tid>>3), q = tid & 7;
  const float4* w4 = (const float4*)(d1w + u*1024);
  const float4* x4 = (const float4*)fin;
  float4 a = Z4;
  for (int jj=q; jj<256; jj+=8){ float4 wv=w4[jj], xv=x4[jj]; FMA4(a,xv,wv) }
  float s = hsum4(a);
  s += __shfl_xor(s,1,64); s += __shfl_xor(s,2,64); s += __shfl_xor(s,4,64);
  if (q==0) ws[OFF_F1 + b*512 + u] = fmaxf(s + d1b[u], 0.f);
}
__global__ __launch_bounds__(256) void k_fd2(
    const float* __restrict__ d2w, const float* __restrict__ d2b, float* __restrict__ ws)
{
  __shared__ __align__(16) float f1[512];
  int tid = threadIdx.x;
  int b = blockIdx.x >> 3, u0 = (blockIdx.x & 7)*32;
  for (int j=tid; j<512; j+=256) f1[j] = ws[OFF_F1 + b*512 + j];
  __syncthreads();
  int u = u0 + (tid>>3), q = tid & 7;
  const float4* w4 = (const float4*)(d2w + u*512);
  const float4* x4 = (const float4*)f1;
  float4 a = Z4;
  for (int jj=q; jj<128; jj+=8){ float4 wv=w4[jj], xv=x4[jj]; FMA4(a,xv,wv) }
  float s = hsum4(a);
  s += __shfl_xor(s,1,64); s += __shfl_xor(s,2,64); s += __shfl_xor(s,4,64);
  if (q==0) ws[OFF_F2 + b*256 + u] = fmaxf(s + d2b[u], 0.f);
}
__global__ __launch_bounds__(256) void k_fd3p(
    const float* __restrict__ d3w, const float* __restrict__ d3b,
    const float* __restrict__ pw,  const float* __restrict__ pb,
    const float* __restrict__ ws,  float* __restrict__ outp)
{
  __shared__ __align__(16) float f2[256];
  __shared__ float f3[64];
  int tid = threadIdx.x, b = blockIdx.x;
  for (int j=tid; j<256; j+=256) f2[j] = ws[OFF_F2 + b*256 + j];
  __syncthreads();
  {
    int u = tid>>2, q = tid&3;
    const float4* w4 = (const float4*)(d3w + u*256);
    const float4* x4 = (const float4*)f2;
    float4 a = Z4;
    for (int jj=q; jj<64; jj+=4){ float4 wv=w4[jj], xv=x4[jj]; FMA4(a,xv,wv) }
    float s = hsum4(a);
    s += __shfl_xor(s,1,64); s += __shfl_xor(s,2,64);
    if (q==0) f3[u] = s + d3b[u];
  }
  __syncthreads();
  if (tid < 64){
    float s = 0.f;
    for (int j=tid; j<132; j+=64) s += ws[OFF_QSTAR + b*132 + j]*pw[j];
    s += f3[tid]*pw[132 + tid];
    for (int o=32;o>0;o>>=1) s += __shfl_xor(s,o,64);
    if (tid==0) outp[b] = s + pb[0];
  }
}

extern "C" void kernel_launch(void* const* d_in, const int* in_sizes, int n_in,
                              void* d_out, int out_size, void* d_ws, size_t ws_size,
                              hipStream_t stream)
{
  const float* mnc = (const float*)d_in[0];
  const float* ea  = (const float*)d_in[1];
  const float* fing= (const float*)d_in[2];
  const int*   eidx= (const int*)d_in[3];
  const int*   mb  = (const int*)d_in[4];
  const float* adj = (const float*)d_in[5];
  const float* e1w=(const float*)d_in[6],  *e1b=(const float*)d_in[7];
  const float* e2w=(const float*)d_in[8],  *e2b=(const float*)d_in[9];
  const float* c1w=(const float*)d_in[10], *c1b=(const float*)d_in[11];
  const float* c2w=(const float*)d_in[12], *c2b=(const float*)d_in[13];
  const float* n1w=(const float*)d_in[14], *n1b=(const float*)d_in[15];
  const float* n2w=(const float*)d_in[16], *n2b=(const float*)d_in[17];
  const float* bng=(const float*)d_in[18], *bnb=(const float*)d_in[19];
  const float* nnw=(const float*)d_in[20], *nnb=(const float*)d_in[21];
  const float* root=(const float*)d_in[22],*nnbias=(const float*)d_in[23];
  const float* cv1w=(const float*)d_in[24],*cv1b=(const float*)d_in[25];
  const float* cv2w=(const float*)d_in[26],*cv2b=(const float*)d_in[27];
  const float* lfw=(const float*)d_in[28], *lfb=(const float*)d_in[29];
  const float* gwih=(const float*)d_in[30],*gwhh=(const float*)d_in[31];
  const float* gbih=(const float*)d_in[32],*gbhh=(const float*)d_in[33];
  const float* lwih=(const float*)d_in[34],*lwhh=(const float*)d_in[35];
  const float* lbih=(const float*)d_in[36],*lbhh=(const float*)d_in[37];
  const float* d1w=(const float*)d_in[38], *d1b=(const float*)d_in[39];
  const float* d2w=(const float*)d_in[40], *d2b=(const float*)d_in[41];
  const float* d3w=(const float*)d_in[42], *d3b=(const float*)d_in[43];
  const float* pw =(const float*)d_in[44], *pb =(const float*)d_in[45];
  float* ws = (float*)d_ws;
  int*   iw = (int*)(ws + OFF_FEND);
  float* outp = (float*)d_out;

  const long long setup_total = (long long)NN*NN + EE + 16384 + 16384 + 16384
                              + 726*68 + 3*1024*192 + 198*132 + 198*68
                              + 126*128 + 63*128;
  int setup_blocks = (int)((setup_total + 255)/256);

  k_zero0    <<<4, 256, 0, stream>>>(iw);
  k_setup    <<<setup_blocks, 256, 0, stream>>>(adj, eidx, e1w, e2w, c1w, nnw, nnb, cv1w, gwih, gwhh, n1w, n2w, ws, iw);
  k_ab       <<<(NN/32)*4, 256, 0, stream>>>(mnc, e1b, ws);
  k_edge     <<<EE/EB, 256, 0, stream>>>(mnc, eidx, e2b, c1b, c2w, c2b, ws);
  k_node     <<<NN/NNB, 256, 0, stream>>>(mnc, n1b, n2b, ws, iw);
  k_bn_stats <<<ID, 256, 0, stream>>>(ws);
  k_bn_apply <<<(NN*ID+255)/256, 256, 0, stream>>>(bng, bnb, ws);
  for (int it=0; it<3; ++it){
    k_tbuild <<<(NN/16)*3, 256, 0, stream>>>(ws);
    k_mnode  <<<NN/MNB, 256, 0, stream>>>(root, nnbias, eidx, ea, ws, iw);
    k_spconv <<<NN, 256, 0, stream>>>(cv1b, cv2w, cv2b, it, ws, iw);
    k_af     <<<BB, 64, 0, stream>>>(mb, lfw, lfb, ws);
    k_grug   <<<NN/GNB, 256, 0, stream>>>(gbih, gbhh, ws);
  }
  k_s2s      <<<BB, 256, 0, stream>>>(mb, lwih, lwhh, lbih, lbhh, ws);
  k_fd1      <<<BB*16, 256, 0, stream>>>(fing, d1w, d1b, ws);
  k_fd2      <<<BB*8, 256, 0, stream>>>(d2w, d2b, ws);
  k_fd3p     <<<BB, 256, 0, stream>>>(d3w, d3b, pw, pb, ws, outp);
}

// Round 12
// 509.399 us; speedup vs baseline: 2.3883x; 1.0494x over previous
//
#include <hip/hip_runtime.h>
#include <math.h>

// Problem constants (fixed by the reference)
#define NN 1024   // nodes
#define BB 32     // mols
#define EE 8192   // edges
#define DD 64     // DIM
#define ID 66     // IN_DIM
#define FT 63     // feats dim
#define CAP 128   // max nnz per adj column
#define ECAP 64   // max in-edges per node
#define MAXM 64   // max nodes per mol (s2s)
#define GNB 4     // nodes per block in gru gate gemm
#define QCH 16    // spconv neighbor chunk
#define NTB 8     // tbuild node tile

// ---- workspace layout (float offsets) ----
enum : int {
  OFF_SMIP  = 0,                        // N*66 pre-BN smi
  OFF_OUT   = OFF_SMIP + NN*ID,         // N*66 h
  OFF_STATS = OFF_OUT + NN*ID,          // 144 mean/rstd
  OFF_M     = OFF_STATS + 144,          // N*66 m buffer
  OFF_CM    = OFF_M + NN*ID,            // N*132 cm
  OFF_QSTAR = OFF_CM + NN*132,          // 32*132
  OFF_CVAL  = OFF_QSTAR + BB*132,       // N*CAP csc values
  OFF_A     = OFF_CVAL + NN*CAP,        // 1024*256 A = feats@W1a^T + e1b
  OFF_B     = OFF_A + 1024*256,         // 1024*256 B = feats@W1b^T
  OFF_EDGE  = OFF_B + 1024*256,         // 8192*68: [0..62]=mij, [64..66]=cw*rel
  OFF_T     = OFF_EDGE + EE*68,         // 1024*726 T[n][t*66+o]
  OFF_QAUG  = OFF_T + NN*726,           // 726*68 Qaug[(t*66+o)][i]
  OFF_W1A   = OFF_QAUG + 726*68,        // 256*64
  OFF_W1B   = OFF_W1A + 16384,          // 256*64
  OFF_WR    = OFF_W1B + 16384,          // 256
  OFF_W2P   = OFF_WR + 256,             // 64*256 padded e2w
  OFF_C1P   = OFF_W2P + 16384,          // 256*64 padded c1w
  OFF_C1R   = OFF_C1P + 16384,          // 3*1024*192 conv1_w reorg
  OFF_GIH   = OFF_C1R + 3*1024*192,     // 198*132
  OFF_GHH   = OFF_GIH + 198*132,        // 198*68
  OFF_F1    = OFF_GHH + 198*68,         // 32*512
  OFF_F2    = OFF_F1 + BB*512,          // 32*256
  OFF_AV    = OFF_F2 + BB*256,          // N  softmax gate per node
  OFF_N1P   = OFF_AV + NN,              // 126*128 padded n1w
  OFF_N2P   = OFF_N1P + 126*128,        // 63*128  padded n2w
  OFF_FEND  = OFF_N2P + 63*128
};
enum : int {  // int region at ws + OFF_FEND
  IOFF_CNT   = 0,                 // N   csc col counts
  IOFF_CIDX  = NN,                // N*CAP
  IOFF_ECNT  = NN + NN*CAP,       // N   in-degree
  IOFF_ELIST = NN + NN*CAP + NN,  // N*ECAP edge ids sorted by dst
  IOFF_END   = NN + NN*CAP + NN + NN*ECAP
};

__device__ __forceinline__ float sgm(float x){ return 1.0f/(1.0f+expf(-x)); }
__device__ __forceinline__ float silu_(float x){ return x/(1.0f+expf(-x)); }
__device__ __forceinline__ float nan0(float v){ return (v!=v) ? 0.0f : v; }
__device__ __forceinline__ float hsum4(float4 v){ return v.x+v.y+v.z+v.w; }
#define FMA4(A,X,W) {A.x += (X).x*(W).x; A.y += (X).y*(W).y; A.z += (X).z*(W).z; A.w += (X).w*(W).w;}
#define Z4 {0.f,0.f,0.f,0.f}

// ---- zero the atomic counters ----
__global__ void k_zero0(int* __restrict__ iw){
  int i = blockIdx.x*256 + threadIdx.x;
  if (i < NN){ iw[IOFF_CNT + i] = 0; iw[IOFF_ECNT + i] = 0; }
}

// ---- one-shot setup: csc(adj), edge sort by dst, weight reorg/pad ----
__global__ void k_setup(const float* __restrict__ adj, const int* __restrict__ eidx,
                        const float* __restrict__ e1w, const float* __restrict__ e2w,
                        const float* __restrict__ c1w,
                        const float* __restrict__ nnw, const float* __restrict__ nnb,
                        const float* __restrict__ cv1w,
                        const float* __restrict__ gwih, const float* __restrict__ gwhh,
                        const float* __restrict__ n1w, const float* __restrict__ n2w,
                        float* __restrict__ ws, int* __restrict__ iw){
  long long idx = (long long)blockIdx.x*256 + threadIdx.x;
  if (idx < (long long)NN*NN){
    float v = adj[idx];
    if (v != 0.0f){
      int a = (int)(idx & 1023), b = (int)(idx >> 10);
      int p = atomicAdd(iw + IOFF_CNT + a, 1);
      if (p < CAP){ iw[IOFF_CIDX + a*CAP + p] = b; ws[OFF_CVAL + a*CAP + p] = v; }
    }
    return;
  }
  idx -= (long long)NN*NN;
  if (idx < EE){
    int e = (int)idx, d = eidx[EE + e];
    int p = atomicAdd(iw + IOFF_ECNT + d, 1);
    if (p < ECAP) iw[IOFF_ELIST + d*ECAP + p] = e;
    return;
  }
  idx -= EE;
  if (idx < 16384){ int u=(int)idx>>6, j=(int)idx&63;
    ws[OFF_W1A+idx] = (u<254 && j<63)? e1w[u*127+j]      : 0.f;
    ws[OFF_W1B+idx] = (u<254 && j<63)? e1w[u*127+63+j]   : 0.f;
    if (j==0) ws[OFF_WR+u] = (u<254)? e1w[u*127+126] : 0.f;
    return; }
  idx -= 16384;
  if (idx < 16384){ int u=(int)idx>>8, j=(int)idx&255; ws[OFF_W2P+idx] = (u<63 && j<254)? e2w[u*254+j] : 0.f; return; }
  idx -= 16384;
  if (idx < 16384){ int u=(int)idx>>6, j=(int)idx&63; ws[OFF_C1P+idx] = (u<252 && j<63)? c1w[u*63+j] : 0.f; return; }
  idx -= 16384;
  if (idx < 726*68){ int to=(int)idx/68, i=(int)idx%68; int t=to/66, o=to%66;
    float v = 0.f;
    if (i < 66) v = (t<10)? nnw[(i*66+o)*10+t] : nnb[i*66+o];
    ws[OFF_QAUG+idx] = v; return; }
  idx -= 726*68;
  if (idx < 3*1024*192){ int it=(int)(idx/196608); int r=(int)(idx%196608); int b=r/192; int z=r%192; int o=z/3, k=z%3;
    ws[OFF_C1R+idx] = cv1w[((it*64+o)*1024+b)*3+k]; return; }
  idx -= 3*1024*192;
  if (idx < 198*132){ int u=(int)idx/132, j=(int)idx%132; ws[OFF_GIH+idx] = (j<130)? gwih[u*130+j] : 0.f; return; }
  idx -= 198*132;
  if (idx < 198*68){ int u=(int)idx/68, j=(int)idx%68; ws[OFF_GHH+idx] = (j<66)? gwhh[u*66+j] : 0.f; return; }
  idx -= 198*68;
  if (idx < 126*128){ int u=(int)idx>>7, j=(int)idx&127; ws[OFF_N1P+idx] = (j<126)? n1w[u*126+j] : 0.f; return; }
  idx -= 126*128;
  if (idx < 63*128){ int u=(int)idx>>7, j=(int)idx&127; ws[OFF_N2P+idx] = (j<126)? n2w[u*126+j] : 0.f; return; }
}

// ---- A/B build: 128 blocks = 32 node-tiles x 4 u-tiles ----
__global__ __launch_bounds__(256) void k_ab(const float* __restrict__ mnc,
                                            const float* __restrict__ e1b,
                                            float* __restrict__ ws){
  __shared__ float xf[32][68];
  int tid = threadIdx.x;
  int n0 = (blockIdx.x>>2)*32;
  int ut = blockIdx.x&3;
  for (int idx=tid; idx<32*64; idx+=256){ int n=idx>>6, j=idx&63;
    xf[n][j] = (j<63)? mnc[(n0+n)*ID + 3 + j] : 0.f; }
  __syncthreads();
  int eg = tid&7, ug = tid>>3;
  for (int pass=0; pass<2; pass++){
    int u = ut*64 + pass*32 + ug;
    const float4* wa = (const float4*)(ws + OFF_W1A + u*64);
    const float4* wb = (const float4*)(ws + OFF_W1B + u*64);
    float4 a0=Z4,a1=Z4,a2=Z4,a3=Z4,b0=Z4,b1=Z4,b2=Z4,b3=Z4;
    for (int jj=0;jj<16;jj++){
      float4 w1 = wa[jj], w2 = wb[jj];
      float4 x0 = *(const float4*)&xf[eg   ][jj*4];
      float4 x1 = *(const float4*)&xf[eg+ 8][jj*4];
      float4 x2 = *(const float4*)&xf[eg+16][jj*4];
      float4 x3 = *(const float4*)&xf[eg+24][jj*4];
      FMA4(a0,x0,w1) FMA4(a1,x1,w1) FMA4(a2,x2,w1) FMA4(a3,x3,w1)
      FMA4(b0,x0,w2) FMA4(b1,x1,w2) FMA4(b2,x2,w2) FMA4(b3,x3,w2)
    }
    if (u < 254){
      float bv = e1b[u];
      float va[4]={hsum4(a0),hsum4(a1),hsum4(a2),hsum4(a3)};
      float vb[4]={hsum4(b0),hsum4(b1),hsum4(b2),hsum4(b3)};
      #pragma unroll
      for (int i=0;i<4;i++){
        int n = n0 + eg + 8*i;
        ws[OFF_A + n*256 + u] = bv + va[i];
        ws[OFF_B + n*256 + u] = vb[i];
      }
    }
  }
}

// ---- per-edge chain: EB=8 -> 1024 blocks ----
#define EB 8
__global__ __launch_bounds__(256) void k_edge(
    const float* __restrict__ mnc, const int* __restrict__ eidx,
    const float* __restrict__ e2b, const float* __restrict__ c1b,
    const float* __restrict__ c2w, const float* __restrict__ c2b,
    float* __restrict__ ws)
{
  __shared__ float eh [EB][260];   // L1 out; later ch
  __shared__ float mij[EB][68];
  __shared__ float srel[EB][4];
  __shared__ int ssrc[EB], sdst[EB];
  int tid = threadIdx.x;
  int e0b = blockIdx.x*EB;
  if (tid < EB){
    int e = e0b + tid;
    int s = eidx[e], d = eidx[EE + e];
    ssrc[tid]=s; sdst[tid]=d;
    float rd = 0.f;
    #pragma unroll
    for (int k=0;k<3;k++){ float r = mnc[s*ID+k]-mnc[d*ID+k]; srel[tid][k]=r; rd += r*r; }
    srel[tid][3] = rd;
  }
  if (tid < EB*5) mij[tid/5][63+tid%5] = 0.f;
  __syncthreads();
  // L1: eh = silu(A[dst] + B[src] + wr*rd)
  for (int idx=tid; idx<EB*256; idx+=256){
    int e = idx>>8, u = idx&255;
    float v = 0.f;
    if (u < 254) v = silu_(ws[OFF_A + sdst[e]*256 + u] + ws[OFF_B + ssrc[e]*256 + u]
                           + ws[OFF_WR + u]*srel[e][3]);
    eh[e][u] = v;
  }
  __syncthreads();
  int ug = tid>>2, eg = tid&3;   // u = ug; edges eg, eg+4
  // L2: mij = silu(eh @ W2P^T + e2b), K=256
  {
    const float4* w0 = (const float4*)(ws+OFF_W2P + ug*256);
    float4 a0=Z4,a1=Z4;
    for (int jj=0;jj<64;jj++){
      float4 w = w0[jj];
      FMA4(a0, *(const float4*)&eh[eg  ][jj*4], w)
      FMA4(a1, *(const float4*)&eh[eg+4][jj*4], w)
    }
    if (ug < 63){
      float bv = e2b[ug];
      float v0 = silu_(bv + hsum4(a0));
      float v1 = silu_(bv + hsum4(a1));
      mij[eg  ][ug] = v0; ws[OFF_EDGE + (e0b+eg  )*68 + ug] = v0;
      mij[eg+4][ug] = v1; ws[OFF_EDGE + (e0b+eg+4)*68 + ug] = v1;
    }
  }
  __syncthreads();
  // L3: ch = silu(mij @ C1P^T + c1b) into eh; 4 u-passes
  for (int uc=0; uc<4; uc++){
    int u = uc*64 + ug;
    const float4* w0 = (const float4*)(ws+OFF_C1P + u*64);
    float4 a0=Z4,a1=Z4;
    for (int jj=0;jj<16;jj++){
      float4 w = w0[jj];
      FMA4(a0, *(const float4*)&mij[eg  ][jj*4], w)
      FMA4(a1, *(const float4*)&mij[eg+4][jj*4], w)
    }
    if (u < 252){
      float bv = c1b[u];
      eh[eg  ][u] = silu_(bv + hsum4(a0));
      eh[eg+4][u] = silu_(bv + hsum4(a1));
    }
  }
  __syncthreads();
  // L4: cw = ch·c2w + c2b; 32 lanes per edge
  {
    int e = tid>>5, q = tid&31;
    const float4* xr = (const float4*)&eh[e][0];
    const float4* wr4 = (const float4*)c2w;
    float4 a = Z4;
    for (int jj=q; jj<63; jj+=32){ float4 xv=xr[jj], wv=wr4[jj]; FMA4(a,xv,wv) }
    float s = hsum4(a);
    s += __shfl_down(s,16,32); s += __shfl_down(s,8,32);
    s += __shfl_down(s,4,32);  s += __shfl_down(s,2,32); s += __shfl_down(s,1,32);
    if (q == 0){
      float cw = s + c2b[0];
      #pragma unroll
      for (int k=0;k<3;k++) ws[OFF_EDGE + (e0b+e)*68 + 64 + k] = cw*srel[e][k];
    }
  }
}

// ---- node MLP (float4, padded weights) + gathers -> smi_pre ----
#define NNB 8
__global__ __launch_bounds__(256) void k_node(
    const float* __restrict__ mnc,
    const float* __restrict__ n1b, const float* __restrict__ n2b,
    float* __restrict__ ws, const int* __restrict__ iw)
{
  __shared__ float xin[NNB][132];
  __shared__ float t1 [NNB][132];
  int tid = threadIdx.x;
  int n0 = blockIdx.x*NNB;
  for (int idx=tid; idx<NNB*128; idx+=256){
    int e = idx>>7, j = idx&127;
    int node = n0 + e;
    float v = 0.f;
    if (j < 63) v = mnc[node*ID + 3 + j];
    else if (j < 126){
      int u = j - 63;
      int cnt = iw[IOFF_ECNT+node]; if (cnt > ECAP) cnt = ECAP;
      for (int q=0;q<cnt;q++) v += ws[OFF_EDGE + iw[IOFF_ELIST+node*ECAP+q]*68 + u];
    }
    xin[e][j] = v;
    t1[e][j] = 0.f;
  }
  __syncthreads();
  {
    int ng = tid&3, ug = tid>>2;
    int u0 = 2*ug, u1 = u0+1;
    const float4* w0 = (const float4*)(ws+OFF_N1P + u0*128);
    const float4* w1 = (const float4*)(ws+OFF_N1P + u1*128);
    float4 a0=Z4,a1=Z4,b0=Z4,b1=Z4;
    for (int jj=0;jj<32;jj++){
      float4 wv0=w0[jj], wv1=w1[jj];
      float4 x0 = *(const float4*)&xin[ng  ][jj*4];
      float4 x1 = *(const float4*)&xin[ng+4][jj*4];
      FMA4(a0,x0,wv0) FMA4(a1,x1,wv0)
      FMA4(b0,x0,wv1) FMA4(b1,x1,wv1)
    }
    if (u0 < 126){ float bv=n1b[u0]; t1[ng][u0]=silu_(bv+hsum4(a0)); t1[ng+4][u0]=silu_(bv+hsum4(a1)); }
    if (u1 < 126){ float bv=n1b[u1]; t1[ng][u1]=silu_(bv+hsum4(b0)); t1[ng+4][u1]=silu_(bv+hsum4(b1)); }
  }
  __syncthreads();
  {
    int ng = tid&7, ug = tid>>3;
    int u0 = 2*ug, u1 = u0+1;
    const float4* w0 = (const float4*)(ws+OFF_N2P + u0*128);
    const float4* w1 = (const float4*)(ws+OFF_N2P + u1*128);
    float4 a0=Z4,b0=Z4;
    if (u0 < 63){
      for (int jj=0;jj<32;jj++){
        float4 x0 = *(const float4*)&t1[ng][jj*4];
        FMA4(a0,x0,w0[jj]) FMA4(b0,x0,w1[jj])
      }
      int node = n0 + ng;
      ws[OFF_SMIP + node*ID + 3 + u0] = nan0(xin[ng][u0] + n2b[u0] + hsum4(a0));
      if (u1 < 63)
        ws[OFF_SMIP + node*ID + 3 + u1] = nan0(xin[ng][u1] + n2b[u1] + hsum4(b0));
    }
  }
  if (tid < NNB*3){
    int e = tid/3, k = tid%3;
    int node = n0 + e;
    int cnt = iw[IOFF_ECNT+node]; if (cnt > ECAP) cnt = ECAP;
    float s = mnc[node*ID + k];
    for (int q=0;q<cnt;q++) s += ws[OFF_EDGE + iw[IOFF_ELIST+node*ECAP+q]*68 + 64 + k];
    ws[OFF_SMIP + node*ID + k] = nan0(s);
  }
}

// ---- batchnorm ----
__global__ __launch_bounds__(256) void k_bn_stats(float* __restrict__ ws){
  __shared__ float scr[8];
  int j = blockIdx.x, tid = threadIdx.x;
  float s=0.f, ss=0.f;
  for (int i=tid; i<NN; i+=256){ float x = ws[OFF_SMIP + i*ID + j]; s+=x; ss+=x*x; }
  for (int o=32;o>0;o>>=1){ s += __shfl_down(s,o,64); ss += __shfl_down(ss,o,64); }
  int w = tid>>6;
  if ((tid&63)==0){ scr[w]=s; scr[4+w]=ss; }
  __syncthreads();
  if (tid==0){
    float S=0,SS=0;
    for (int q=0;q<4;q++){S+=scr[q];SS+=scr[4+q];}
    float mean = S/NN;
    float var  = SS/NN - mean*mean;
    ws[OFF_STATS + j]      = mean;
    ws[OFF_STATS + 66 + j] = 1.0f/sqrtf(var + 1e-5f);
  }
}
__global__ void k_bn_apply(const float* __restrict__ bng, const float* __restrict__ bnb,
                           float* __restrict__ ws){
  int idx = blockIdx.x*256 + threadIdx.x;
  if (idx < NN*ID){
    int j = idx % ID;
    ws[OFF_OUT + idx] = bng[j]*(ws[OFF_SMIP+idx]-ws[OFF_STATS+j])*ws[OFF_STATS+66+j] + bnb[j];
  }
}

// ---- T[n][t*66+o] = sum_i h[n,i]*Qaug[i,t,o]; 384 blocks = 128 node-tiles x 3 passes ----
__global__ __launch_bounds__(256) void k_tbuild(float* __restrict__ ws){
  __shared__ float xs[NTB][68];
  int tid = threadIdx.x;
  int n0 = (blockIdx.x/3)*NTB;
  int pass = blockIdx.x%3;
  for (int idx=tid; idx<NTB*68; idx+=256){ int n=idx/68, j=idx%68;
    xs[n][j] = (j<66)? ws[OFF_OUT + (n0+n)*ID + j] : 0.f; }
  __syncthreads();
  int to = pass*256 + tid;
  if (to < 726){
    float acc[NTB];
    #pragma unroll
    for (int n=0;n<NTB;n++) acc[n] = 0.f;
    const float4* qp = (const float4*)(ws + OFF_QAUG + to*68);
    for (int jj=0;jj<17;jj++){
      float4 w = qp[jj];
      #pragma unroll
      for (int n=0;n<NTB;n++){
        float4 x = *(const float4*)&xs[n][jj*4];
        acc[n] += x.x*w.x + x.y*w.y + x.z*w.z + x.w*w.w;
      }
    }
    #pragma unroll
    for (int n=0;n<NTB;n++) ws[OFF_T + (n0+n)*726 + to] = acc[n];
  }
}

// ---- m = relu(gathered_msg/deg + h@root + nn_bias); 256 blocks ----
#define MNB 4
__global__ __launch_bounds__(256) void k_mnode(
    const float* __restrict__ root, const float* __restrict__ nnbias,
    const int* __restrict__ eidx, const float* __restrict__ ea,
    float* __restrict__ ws, const int* __restrict__ iw)
{
  __shared__ float rs[66][68];
  __shared__ float xo[MNB][68];
  int tid = threadIdx.x;
  int n0 = blockIdx.x*MNB;
  for (int idx=tid; idx<66*66; idx+=256) rs[idx/66][idx%66] = root[idx];
  for (int idx=tid; idx<MNB*66; idx+=256) xo[idx/66][idx%66] = ws[OFF_OUT + n0*ID + idx];
  __syncthreads();
  for (int idx=tid; idx<MNB*66; idx+=256){
    int n = idx/66, o = idx%66;
    int node = n0 + n;
    int rawcnt = iw[IOFF_ECNT+node];
    int cnt = rawcnt > ECAP ? ECAP : rawcnt;
    float magg = 0.f;
    for (int q=0;q<cnt;q++){
      int e = iw[IOFF_ELIST + node*ECAP + q];
      int s = eidx[e];
      const float* Tp = ws + OFF_T + s*726 + o;
      const float* eap = ea + e*10;
      float av = Tp[660];
      #pragma unroll
      for (int t=0;t<10;t++) av += eap[t]*Tp[t*66];
      magg += av;
    }
    float deg = fmaxf((float)rawcnt, 1.0f);
    float s2 = nnbias[o] + magg/deg;
    for (int j=0;j<66;j++) s2 += xo[n][j]*rs[j][o];
    s2 = fmaxf(s2, 0.0f);
    ws[OFF_M  + node*ID  + o] = s2;
    ws[OFF_CM + node*132 + o] = s2;
  }
}

// ---- fused sparse conv: vv folded into w1s at staging; register accumulators
// (static unroll, 17/thread); mid written once with bias folded (saves the
// zero-init sweep, per-chunk mid r/w, and the bias sweep). mid stride 69. ----
__global__ __launch_bounds__(256) void k_spconv(
    const float* __restrict__ cv1b, const float* __restrict__ cv2w,
    const float* __restrict__ cv2b,
    int it, float* __restrict__ ws, const int* __restrict__ iw)
{
  __shared__ float mid[DD][69];
  __shared__ float mps[QCH][68];
  __shared__ float w1s[QCH][192];
  __shared__ float w2s[204];
  __shared__ float part[4][64];
  int tid = threadIdx.x;
  int a = blockIdx.x;
  if (tid < 198) w2s[tid] = cv2w[it*198 + tid];
  int nnz = iw[IOFF_CNT + a]; if (nnz > CAP) nnz = CAP;
  float acc[17];
  #pragma unroll
  for (int k=0;k<17;k++) acc[k] = 0.f;
  for (int q0=0; q0<nnz; q0+=QCH){
    int qn = nnz - q0; if (qn > QCH) qn = QCH;
    __syncthreads();   // protect w1s/mps from previous chunk's readers
    for (int idx=tid; idx<qn*68; idx+=256){
      int q=idx/68, cc=idx%68;
      int b = iw[IOFF_CIDX + a*CAP + q0 + q];
      mps[q][cc] = (cc>=1 && cc<=66)? ws[OFF_M + b*ID + cc-1] : 0.f;
    }
    for (int idx=tid; idx<qn*192; idx+=256){
      int q=idx/192, r=idx%192;
      int b = iw[IOFF_CIDX + a*CAP + q0 + q];
      w1s[q][r] = ws[OFF_CVAL + a*CAP + q0 + q] * ws[OFF_C1R + (it*1024+b)*192 + r];
    }
    __syncthreads();
    #pragma unroll
    for (int k=0;k<17;k++){
      int idx = tid + k*256;
      if (idx < DD*ID){
        int o = idx/ID, cc = idx%ID;
        float s = acc[k];
        for (int q=0;q<qn;q++)
          s += w1s[q][o*3]*mps[q][cc] + w1s[q][o*3+1]*mps[q][cc+1] + w1s[q][o*3+2]*mps[q][cc+2];
        acc[k] = s;
      }
    }
  }
  #pragma unroll
  for (int k=0;k<17;k++){
    int idx = tid + k*256;
    if (idx < DD*ID){
      int o = idx/ID, cc = idx%ID;
      mid[o][cc] = acc[k] + cv1b[it*DD+o];
    }
  }
  __syncthreads();
  {
    int x = tid & 63, qq = tid >> 6;
    int c0 = qq*17, cN = c0+17; if (cN > ID) cN = ID;
    float s = 0.f;
    for (int cc=c0; cc<cN; cc++){
      #pragma unroll
      for (int k=0;k<3;k++){
        int oo = x + k - 1;
        if (oo >= 0 && oo < DD) s += mid[oo][cc]*w2s[cc*3+k];
      }
    }
    part[qq][x] = s;
  }
  __syncthreads();
  if (tid < DD)
    ws[OFF_CM + a*132 + ID + tid] = part[0][tid]+part[1][tid]+part[2][tid]+part[3][tid] + cv2b[it];
}

// ---- gate score + per-mol segment softmax -> av[node] ----
__global__ __launch_bounds__(64) void k_af(
    const int* __restrict__ mb,
    const float* __restrict__ lfw, const float* __restrict__ lfb,
    float* __restrict__ ws)
{
  __shared__ int memb[MAXM]; __shared__ int lcnt;
  int tid = threadIdx.x, m = blockIdx.x;
  if (tid==0) lcnt = 0;
  __syncthreads();
  for (int i=tid; i<NN; i+=64)
    if (mb[i]==m){ int p = atomicAdd(&lcnt,1); if (p<MAXM) memb[p]=i; }
  __syncthreads();
  int M = lcnt; if (M > MAXM) M = MAXM;
  float x = -INFINITY;
  if (tid < M){
    const float4* cr = (const float4*)(ws + OFF_CM + memb[tid]*132);
    const float4* lw = (const float4*)lfw;
    float4 a = Z4;
    for (int jj=0;jj<32;jj++){ float4 cv=cr[jj], wv=lw[jj]; FMA4(a,cv,wv) }
    const float* crow = ws + OFF_CM + memb[tid]*132;
    float s = hsum4(a) + crow[128]*lfw[128] + crow[129]*lfw[129] + lfb[0];
    x = (s > 0.f) ? s : 0.01f*s;
  }
  float mx = x;
  for (int o=32;o>0;o>>=1) mx = fmaxf(mx, __shfl_xor(mx,o,64));
  float ex = (tid<M) ? expf(x-mx) : 0.f;
  float sm = ex;
  for (int o=32;o>0;o>>=1) sm += __shfl_xor(sm,o,64);
  if (tid<M) ws[OFF_AV + memb[tid]] = ex/(sm + 1e-16f);
}

// ---- GRU gate GEMM + blend, node-parallel ----
__global__ __launch_bounds__(256) void k_grug(
    const float* __restrict__ bih, const float* __restrict__ bhh,
    float* __restrict__ ws)
{
  __shared__ float xs[GNB][132];
  __shared__ float hs[GNB][68];
  __shared__ float ggg[GNB][132];
  __shared__ float g1[GNB][68], g2[GNB][68];
  int tid = threadIdx.x;
  int n0 = blockIdx.x*GNB;
  for (int idx=tid; idx<GNB*132; idx+=256){
    int n = idx/132, j = idx%132;
    xs[n][j] = (j<130)? ws[OFF_AV + n0 + n] * ws[OFF_CM + (n0+n)*132 + j] : 0.f;
  }
  for (int idx=tid; idx<GNB*68; idx+=256){
    int n = idx/68, j = idx%68;
    hs[n][j] = (j<66)? ws[OFF_OUT + (n0+n)*ID + j] : 0.f;
  }
  __syncthreads();
  if (tid < 198){
    int u = tid;
    const float4* w1 = (const float4*)(ws+OFF_GIH + u*132);
    const float4* w2 = (const float4*)(ws+OFF_GHH + u*68);
    float4 a0=Z4,a1=Z4,a2=Z4,a3=Z4;
    #pragma unroll 4
    for (int jj=0;jj<33;jj++){
      float4 w = w1[jj];
      FMA4(a0,*(const float4*)&xs[0][jj*4],w)
      FMA4(a1,*(const float4*)&xs[1][jj*4],w)
      FMA4(a2,*(const float4*)&xs[2][jj*4],w)
      FMA4(a3,*(const float4*)&xs[3][jj*4],w)
    }
    float4 b0=Z4,b1=Z4,b2=Z4,b3=Z4;
    #pragma unroll 4
    for (int jj=0;jj<17;jj++){
      float4 w = w2[jj];
      FMA4(b0,*(const float4*)&hs[0][jj*4],w)
      FMA4(b1,*(const float4*)&hs[1][jj*4],w)
      FMA4(b2,*(const float4*)&hs[2][jj*4],w)
      FMA4(b3,*(const float4*)&hs[3][jj*4],w)
    }
    float bv1 = bih[u], bv2 = bhh[u];
    float d1[4] = {hsum4(a0),hsum4(a1),hsum4(a2),hsum4(a3)};
    float d2[4] = {hsum4(b0),hsum4(b1),hsum4(b2),hsum4(b3)};
    #pragma unroll
    for (int n=0;n<4;n++){
      float v1 = bv1 + d1[n];
      float v2 = bv2 + d2[n];
      if (u < 132) ggg[n][u] = sgm(v1+v2);
      else { g1[n][u-132] = v1; g2[n][u-132] = v2; }
    }
  }
  __syncthreads();
  for (int idx=tid; idx<GNB*66; idx+=256){
    int n = idx/66, u = idx%66;
    float r = ggg[n][u], z = ggg[n][66+u];
    float nn_ = tanhf(g1[n][u] + r*g2[n][u]);
    ws[OFF_OUT + (n0+n)*ID + u] = (1.f - z)*nn_ + z*hs[n][u];
  }
}

// ---- Set2Set readout ----
__global__ __launch_bounds__(256) void k_s2s(
    const int* __restrict__ mb,
    const float* __restrict__ wih, const float* __restrict__ whh,
    const float* __restrict__ bih, const float* __restrict__ bhh,
    float* __restrict__ ws)
{
  __shared__ int memb[MAXM]; __shared__ int lcnt;
  __shared__ float orow[MAXM][68];
  __shared__ float hsv[66], csv[66], qsv[132], gv[264];
  __shared__ float av[MAXM];
  int tid = threadIdx.x, m = blockIdx.x;
  if (tid==0) lcnt = 0;
  __syncthreads();
  for (int i=tid; i<NN; i+=256)
    if (mb[i]==m){ int p = atomicAdd(&lcnt,1); if (p<MAXM) memb[p]=i; }
  __syncthreads();
  int M = lcnt; if (M > MAXM) M = MAXM;
  for (int idx=tid; idx<M*ID; idx+=256){ int i=idx/ID, j=idx%ID; orow[i][j]=ws[OFF_OUT+memb[i]*ID+j]; }
  if (tid < 66){ hsv[tid]=0.f; csv[tid]=0.f; }
  if (tid < 132) qsv[tid]=0.f;
  __syncthreads();
  for (int step=0; step<3; step++){
    for (int u=tid; u<264; u+=256){
      float s = bih[u] + bhh[u];
      const float* w1 = wih + u*132;
      for (int j=0;j<132;j++) s += qsv[j]*w1[j];
      const float* w2 = whh + u*ID;
      for (int j=0;j<ID;j++) s += hsv[j]*w2[j];
      gv[u] = s;
    }
    __syncthreads();
    if (tid < 66){
      float ig=gv[tid], fg=gv[66+tid], gg_=gv[132+tid], og=gv[198+tid];
      float c = sgm(fg)*csv[tid] + sgm(ig)*tanhf(gg_);
      csv[tid] = c;
      hsv[tid] = sgm(og)*tanhf(c);
    }
    __syncthreads();
    if (tid < 64){
      float e = -INFINITY;
      if (tid < M){ e = 0.f; for (int j=0;j<ID;j++) e += orow[tid][j]*hsv[j]; }
      float mx = e;
      for (int o=32;o>0;o>>=1) mx = fmaxf(mx, __shfl_xor(mx,o,64));
      float ex = (tid<M) ? expf(e-mx) : 0.f;
      float sm = ex;
      for (int o=32;o>0;o>>=1) sm += __shfl_xor(sm,o,64);
      if (tid<M) av[tid] = ex/(sm + 1e-16f);
    }
    __syncthreads();
    if (tid < 66){
      float r = 0.f;
      for (int i=0;i<M;i++) r += av[i]*orow[i][tid];
      qsv[tid]      = hsv[tid];
      qsv[66+tid]   = r;
    }
    __syncthreads();
  }
  if (tid < 132) ws[OFF_QSTAR + m*132 + tid] = qsv[tid];
}

// ---- fingers MLP ----
__global__ __launch_bounds__(256) void k_fd1(
    const float* __restrict__ fing, const float* __restrict__ d1w, const float* __restrict__ d1b,
    float* __restrict__ ws)
{
  __shared__ __align__(16) float fin[1024];
  int tid = threadIdx.x;
  int b = blockIdx.x >> 4, u0 = (blockIdx.x & 15)*32;
  for (int j=tid; j<1024; j+=256) fin[j] = fing[b*1024+j];
  __syncthreads();
  int u = u0 + (tid>>3), q = tid & 7;
  const float4* w4 = (const float4*)(d1w + u*1024);
  const float4* x4 = (const float4*)fin;
  float4 a = Z4;
  for (int jj=q; jj<256; jj+=8){ float4 wv=w4[jj], xv=x4[jj]; FMA4(a,xv,wv) }
  float s = hsum4(a);
  s += __shfl_xor(s,1,64); s += __shfl_xor(s,2,64); s += __shfl_xor(s,4,64);
  if (q==0) ws[OFF_F1 + b*512 + u] = fmaxf(s + d1b[u], 0.f);
}
__global__ __launch_bounds__(256) void k_fd2(
    const float* __restrict__ d2w, const float* __restrict__ d2b, float* __restrict__ ws)
{
  __shared__ __align__(16) float f1[512];
  int tid = threadIdx.x;
  int b = blockIdx.x >> 3, u0 = (blockIdx.x & 7)*32;
  for (int j=tid; j<512; j+=256) f1[j] = ws[OFF_F1 + b*512 + j];
  __syncthreads();
  int u = u0 + (tid>>3), q = tid & 7;
  const float4* w4 = (const float4*)(d2w + u*512);
  const float4* x4 = (const float4*)f1;
  float4 a = Z4;
  for (int jj=q; jj<128; jj+=8){ float4 wv=w4[jj], xv=x4[jj]; FMA4(a,xv,wv) }
  float s = hsum4(a);
  s += __shfl_xor(s,1,64); s += __shfl_xor(s,2,64); s += __shfl_xor(s,4,64);
  if (q==0) ws[OFF_F2 + b*256 + u] = fmaxf(s + d2b[u], 0.f);
}
__global__ __launch_bounds__(256) void k_fd3p(
    const float* __restrict__ d3w, const float* __restrict__ d3b,
    const float* __restrict__ pw,  const float* __restrict__ pb,
    const float* __restrict__ ws,  float* __restrict__ outp)
{
  __shared__ __align__(16) float f2[256];
  __shared__ float f3[64];
  int tid = threadIdx.x, b = blockIdx.x;
  for (int j=tid; j<256; j+=256) f2[j] = ws[OFF_F2 + b*256 + j];
  __syncthreads();
  {
    int u = tid>>2, q = tid&3;
    const float4* w4 = (const float4*)(d3w + u*256);
    const float4* x4 = (const float4*)f2;
    float4 a = Z4;
    for (int jj=q; jj<64; jj+=4){ float4 wv=w4[jj], xv=x4[jj]; FMA4(a,xv,wv) }
    float s = hsum4(a);
    s += __shfl_xor(s,1,64); s += __shfl_xor(s,2,64);
    if (q==0) f3[u] = s + d3b[u];
  }
  __syncthreads();
  if (tid < 64){
    float s = 0.f;
    for (int j=tid; j<132; j+=64) s += ws[OFF_QSTAR + b*132 + j]*pw[j];
    s += f3[tid]*pw[132 + tid];
    for (int o=32;o>0;o>>=1) s += __shfl_xor(s,o,64);
    if (tid==0) outp[b] = s + pb[0];
  }
}

extern "C" void kernel_launch(void* const* d_in, const int* in_sizes, int n_in,
                              void* d_out, int out_size, void* d_ws, size_t ws_size,
                              hipStream_t stream)
{
  const float* mnc = (const float*)d_in[0];
  const float* ea  = (const float*)d_in[1];
  const float* fing= (const float*)d_in[2];
  const int*   eidx= (const int*)d_in[3];
  const int*   mb  = (const int*)d_in[4];
  const float* adj = (const float*)d_in[5];
  const float* e1w=(const float*)d_in[6],  *e1b=(const float*)d_in[7];
  const float* e2w=(const float*)d_in[8],  *e2b=(const float*)d_in[9];
  const float* c1w=(const float*)d_in[10], *c1b=(const float*)d_in[11];
  const float* c2w=(const float*)d_in[12], *c2b=(const float*)d_in[13];
  const float* n1w=(const float*)d_in[14], *n1b=(const float*)d_in[15];
  const float* n2w=(const float*)d_in[16], *n2b=(const float*)d_in[17];
  const float* bng=(const float*)d_in[18], *bnb=(const float*)d_in[19];
  const float* nnw=(const float*)d_in[20], *nnb=(const float*)d_in[21];
  const float* root=(const float*)d_in[22],*nnbias=(const float*)d_in[23];
  const float* cv1w=(const float*)d_in[24],*cv1b=(const float*)d_in[25];
  const float* cv2w=(const float*)d_in[26],*cv2b=(const float*)d_in[27];
  const float* lfw=(const float*)d_in[28], *lfb=(const float*)d_in[29];
  const float* gwih=(const float*)d_in[30],*gwhh=(const float*)d_in[31];
  const float* gbih=(const float*)d_in[32],*gbhh=(const float*)d_in[33];
  const float* lwih=(const float*)d_in[34],*lwhh=(const float*)d_in[35];
  const float* lbih=(const float*)d_in[36],*lbhh=(const float*)d_in[37];
  const float* d1w=(const float*)d_in[38], *d1b=(const float*)d_in[39];
  const float* d2w=(const float*)d_in[40], *d2b=(const float*)d_in[41];
  const float* d3w=(const float*)d_in[42], *d3b=(const float*)d_in[43];
  const float* pw =(const float*)d_in[44], *pb =(const float*)d_in[45];
  float* ws = (float*)d_ws;
  int*   iw = (int*)(ws + OFF_FEND);
  float* outp = (float*)d_out;

  const long long setup_total = (long long)NN*NN + EE + 16384 + 16384 + 16384
                              + 726*68 + 3*1024*192 + 198*132 + 198*68
                              + 126*128 + 63*128;
  int setup_blocks = (int)((setup_total + 255)/256);

  k_zero0    <<<4, 256, 0, stream>>>(iw);
  k_setup    <<<setup_blocks, 256, 0, stream>>>(adj, eidx, e1w, e2w, c1w, nnw, nnb, cv1w, gwih, gwhh, n1w, n2w, ws, iw);
  k_ab       <<<(NN/32)*4, 256, 0, stream>>>(mnc, e1b, ws);
  k_edge     <<<EE/EB, 256, 0, stream>>>(mnc, eidx, e2b, c1b, c2w, c2b, ws);
  k_node     <<<NN/NNB, 256, 0, stream>>>(mnc, n1b, n2b, ws, iw);
  k_bn_stats <<<ID, 256, 0, stream>>>(ws);
  k_bn_apply <<<(NN*ID+255)/256, 256, 0, stream>>>(bng, bnb, ws);
  for (int it=0; it<3; ++it){
    k_tbuild <<<(NN/NTB)*3, 256, 0, stream>>>(ws);
    k_mnode  <<<NN/MNB, 256, 0, stream>>>(root, nnbias, eidx, ea, ws, iw);
    k_spconv <<<NN, 256, 0, stream>>>(cv1b, cv2w, cv2b, it, ws, iw);
    k_af     <<<BB, 64, 0, stream>>>(mb, lfw, lfb, ws);
    k_grug   <<<NN/GNB, 256, 0, stream>>>(gbih, gbhh, ws);
  }
  k_s2s      <<<BB, 256, 0, stream>>>(mb, lwih, lwhh, lbih, lbhh, ws);
  k_fd1      <<<BB*16, 256, 0, stream>>>(fing, d1w, d1b, ws);
  k_fd2      <<<BB*8, 256, 0, stream>>>(d2w, d2b, ws);
  k_fd3p     <<<BB, 256, 0, stream>>>(d3w, d3b, pw, pb, ws, outp);
}